// Round 1
// 8913.297 us; speedup vs baseline: 1.1123x; 1.1123x over previous
//
#include <hip/hip_runtime.h>
#include <math.h>

// ---------------------------------------------------------------------------
// CompactVidTr forward.
//  - Patch-embed conv: im2col (pure permutation, stride==patch) + split-bf16
//    MFMA GEMM (M=25088, N=512, K=768) — replaces the fp32 VALU conv that ran
//    at 9.5% of vector peak / 1.3% of HBM peak (1322 us -> ~150-200 us).
//  - Wt (QKV) GEMM: split-bf16 MFMA (hi/lo decomposition, 3 MFMA terms) ->
//    fp32-class accuracy for the sigma-top-k ranking path. Conv uses the same
//    split scheme since it feeds the residual stream reaching that path.
//  - Ws/Wo/FFN GEMMs: plain bf16 MFMA (incremental-error paths).
//  - Attention/LN: fp32 vector.
// Layout: token matrices row-major [row = l*B + b][C]; l=0 is cls. B=8, C=512.
//
// Workspace (261.9 MB < 268.4 MB):
//   X   : 3137*8 x 512  fp32   (51.4 MB)  residual stream, pooled IN PLACE
//   Ab  : 3137*8 x 512  fp32   (51.4 MB)  LN out / attention out staging
//   QKV : 3137*8 x 1536 fp32  (154.1 MB)  qkv GEMM out; FFN mid; im2col stage
//   CLS : 8x512 fp32, IDX: 8*8*196*16 int (~0.8 MB)
//   WT1 : 2048*512 bf16 (2.1 MB)  weight scratch (conv-hi / Wt-hi / Ws / Wo / W1)
//   WT2 : 2048*512 bf16 (2.1 MB)  weight scratch (conv-lo / Wt-lo / W2)
// ---------------------------------------------------------------------------

#define BB 8
#define CC 512
#define HH 8
#define HD 64
#define WHT 196
#define NCLS 157

typedef short bf16x8 __attribute__((ext_vector_type(8)));
typedef float floatx4 __attribute__((ext_vector_type(4)));

__device__ __forceinline__ unsigned short f2bf(float f) {
  unsigned u = __float_as_uint(f);
  unsigned r = u + 0x7FFFu + ((u >> 16) & 1u);  // RNE
  return (unsigned short)(r >> 16);
}
__device__ __forceinline__ float bf2f(unsigned short h) {
  return __uint_as_float((unsigned)h << 16);
}

__device__ __forceinline__ float wave_reduce_sum(float v) {
#pragma unroll
  for (int o = 32; o > 0; o >>= 1) v += __shfl_down(v, o, 64);
  return v;
}
__device__ __forceinline__ float wave_reduce_max(float v) {
#pragma unroll
  for (int o = 32; o > 0; o >>= 1) v = fmaxf(v, __shfl_down(v, o, 64));
  return v;
}

// ---------------------------------------------------------------------------
// im2col: src [B=8][3][16][224][224] -> IM [25088][768] fp32.
// Stride 16 == patch size -> pure permutation (each src elem read once).
// Row u = (t*196 + ph*14 + pw)*8 + b ; col k = ci*256 + py*16 + px.
// Writes fully coalesced (row-contiguous); reads in 16B granules.
// ---------------------------------------------------------------------------
__global__ __launch_bounds__(256)
void im2col_kernel(const float* __restrict__ src, float* __restrict__ IM) {
  int gid = blockIdx.x * 256 + threadIdx.x;
  int k4 = gid % 192;          // float4 index within the 768-wide row
  int u = gid / 192;           // token index
  if (u >= 25088) return;
  int b = u & 7;
  int s = u >> 3;
  int tt = s / WHT;
  int w2 = s % WHT;
  int ph = w2 / 14, pw = w2 % 14;
  int k = k4 * 4;
  int ci = k >> 8;
  int rem = k & 255;
  int py = rem >> 4, px = rem & 15;
  const float* sp = src + (size_t)b * (3 * 16 * 224 * 224) +
                    (size_t)ci * (16 * 224 * 224) + (size_t)tt * (224 * 224) +
                    (size_t)(ph * 16 + py) * 224 + pw * 16 + px;
  *(float4*)(IM + (size_t)u * 768 + k) = *(const float4*)sp;
}

// ---------------------------------------------------------------------------
// Flat weight split fp32 -> (hi, lo) bf16 (no transpose; conv_w is already
// [out_c][in-elems] = [N][K]).
// ---------------------------------------------------------------------------
__global__ __launch_bounds__(256)
void wsplit_flat_kernel(const float* __restrict__ W,
                        unsigned short* __restrict__ Whi,
                        unsigned short* __restrict__ Wlo, int total) {
  int i = blockIdx.x * 256 + threadIdx.x;
  if (i >= total) return;
  float w = W[i];
  unsigned short hi = f2bf(w);
  Whi[i] = hi;
  Wlo[i] = f2bf(w - bf2f(hi));
}

__global__ void cls_init_kernel(const float* __restrict__ clst, float* __restrict__ X) {
  X[(size_t)blockIdx.x * CC + threadIdx.x] = clst[threadIdx.x];
}

__global__ void copy_cls_kernel(const float* __restrict__ cls, float* __restrict__ A) {
  A[(size_t)blockIdx.x * CC + threadIdx.x] = cls[(size_t)blockIdx.x * CC + threadIdx.x];
}

// ---------------------------------------------------------------------------
// LayerNorm over C=512; one block per row; optional +pos (layer0 q-input)
// ---------------------------------------------------------------------------
__global__ __launch_bounds__(256)
void ln_kernel(const float* __restrict__ X, float* __restrict__ O,
               const float* __restrict__ w, const float* __restrict__ b,
               const float* __restrict__ pos) {
  __shared__ float red[8];
  const int row = blockIdx.x, tid = threadIdx.x;
  const float* x = X + (size_t)row * CC;
  float v0 = x[tid], v1 = x[tid + 256];
  float s = wave_reduce_sum(v0 + v1);
  if ((tid & 63) == 0) red[tid >> 6] = s;
  __syncthreads();
  float mean = (red[0] + red[1] + red[2] + red[3]) * (1.f / 512.f);
  float d0 = v0 - mean, d1 = v1 - mean;
  float vs = wave_reduce_sum(d0 * d0 + d1 * d1);
  if ((tid & 63) == 0) red[4 + (tid >> 6)] = vs;
  __syncthreads();
  float var = (red[4] + red[5] + red[6] + red[7]) * (1.f / 512.f);
  float inv = 1.0f / sqrtf(var + 1e-5f);
  float o0 = d0 * inv * w[tid] + b[tid];
  float o1 = d1 * inv * w[tid + 256] + b[tid + 256];
  if (pos) {
    const float* pr = pos + (size_t)(row >> 3) * CC;
    o0 += pr[tid];
    o1 += pr[tid + 256];
  }
  O[(size_t)row * CC + tid] = o0;
  O[(size_t)row * CC + tid + 256] = o1;
}

// ---------------------------------------------------------------------------
// Weight transpose + fp32->bf16 (plain): W [K][N] -> WT [N][K]
// ---------------------------------------------------------------------------
__global__ __launch_bounds__(256)
void wtrans_kernel(const float* __restrict__ W, unsigned short* __restrict__ WT,
                   int N, int K) {
  __shared__ float tile[32][33];
  const int tid = threadIdx.x;
  const int tx = tid & 31, ty = tid >> 5;
  const int n0 = blockIdx.x * 32, k0 = blockIdx.y * 32;
#pragma unroll
  for (int r = 0; r < 4; r++) {
    int kk = ty + r * 8;
    tile[kk][tx] = W[(size_t)(k0 + kk) * N + n0 + tx];
  }
  __syncthreads();
#pragma unroll
  for (int r = 0; r < 4; r++) {
    int nn = ty + r * 8;
    WT[(size_t)(n0 + nn) * K + k0 + tx] = f2bf(tile[tx][nn]);
  }
}

// ---------------------------------------------------------------------------
// Weight transpose + split fp32 -> (hi, lo) bf16: W [K][N] -> WThi/WTlo [N][K]
// ---------------------------------------------------------------------------
__global__ __launch_bounds__(256)
void wtrans_split_kernel(const float* __restrict__ W,
                         unsigned short* __restrict__ WThi,
                         unsigned short* __restrict__ WTlo, int N, int K) {
  __shared__ float tile[32][33];
  const int tid = threadIdx.x;
  const int tx = tid & 31, ty = tid >> 5;
  const int n0 = blockIdx.x * 32, k0 = blockIdx.y * 32;
#pragma unroll
  for (int r = 0; r < 4; r++) {
    int kk = ty + r * 8;
    tile[kk][tx] = W[(size_t)(k0 + kk) * N + n0 + tx];
  }
  __syncthreads();
#pragma unroll
  for (int r = 0; r < 4; r++) {
    int nn = ty + r * 8;
    float w = tile[tx][nn];
    unsigned short hi = f2bf(w);
    unsigned short lo = f2bf(w - bf2f(hi));
    WThi[(size_t)(n0 + nn) * K + k0 + tx] = hi;
    WTlo[(size_t)(n0 + nn) * K + k0 + tx] = lo;
  }
}

// ---------------------------------------------------------------------------
// Plain bf16 MFMA GEMM: C = A(M,K) @ W(K,N) + bias [+relu] [+residual]
// A fp32 (converted in staging), WT = bf16 [N][K] pre-transposed.
// 128x128 tile, 4 waves, each 64x64 via 4x4 mfma_f32_16x16x32_bf16.
// ---------------------------------------------------------------------------
template <int RELU, int RES>
__global__ __launch_bounds__(256)
void mfma_gemm_kernel(const float* __restrict__ A,
                      const unsigned short* __restrict__ WT,
                      const float* __restrict__ bias, float* __restrict__ Cout,
                      int M, int N, int K, const float* __restrict__ resid) {
  __shared__ unsigned short AsU[128 * 40];
  __shared__ unsigned short BsU[128 * 40];
  const int tid = threadIdx.x;
  const int wave = tid >> 6, lane = tid & 63;
  const int quad = lane >> 4, l16 = lane & 15;
  const int wrow = (wave >> 1) * 64, wcol = (wave & 1) * 64;
  const int m0 = blockIdx.x * 128, n0 = blockIdx.y * 128;

  floatx4 acc[4][4];
#pragma unroll
  for (int i = 0; i < 4; i++)
#pragma unroll
    for (int j = 0; j < 4; j++) acc[i][j] = (floatx4){0.f, 0.f, 0.f, 0.f};

  for (int k0 = 0; k0 < K; k0 += 32) {
#pragma unroll
    for (int r = 0; r < 4; r++) {
      int e = (tid + r * 256) * 4;
      int row = e >> 5, col = e & 31;
      int gm = m0 + row;
      float4 v = make_float4(0.f, 0.f, 0.f, 0.f);
      if (gm < M) v = *(const float4*)(A + (size_t)gm * K + k0 + col);
      ushort4 o;
      o.x = f2bf(v.x); o.y = f2bf(v.y); o.z = f2bf(v.z); o.w = f2bf(v.w);
      *(ushort4*)&AsU[row * 40 + col] = o;
    }
#pragma unroll
    for (int r = 0; r < 4; r++) {
      int e = (tid + r * 256) * 4;
      int n = e >> 5, k = e & 31;
      ushort4 w = *(const ushort4*)(WT + (size_t)(n0 + n) * K + k0 + k);
      *(ushort4*)&BsU[n * 40 + k] = w;
    }
    __syncthreads();
    bf16x8 af[4], bf[4];
#pragma unroll
    for (int i = 0; i < 4; i++)
      af[i] = *(const bf16x8*)&AsU[(wrow + i * 16 + l16) * 40 + quad * 8];
#pragma unroll
    for (int j = 0; j < 4; j++)
      bf[j] = *(const bf16x8*)&BsU[(wcol + j * 16 + l16) * 40 + quad * 8];
#pragma unroll
    for (int i = 0; i < 4; i++)
#pragma unroll
      for (int j = 0; j < 4; j++)
        acc[i][j] = __builtin_amdgcn_mfma_f32_16x16x32_bf16(af[i], bf[j],
                                                            acc[i][j], 0, 0, 0);
    __syncthreads();
  }
#pragma unroll
  for (int i = 0; i < 4; i++) {
#pragma unroll
    for (int p = 0; p < 4; p++) {
      int gm = m0 + wrow + i * 16 + quad * 4 + p;
      if (gm >= M) continue;
#pragma unroll
      for (int j = 0; j < 4; j++) {
        int gn = n0 + wcol + j * 16 + l16;
        float v = acc[i][j][p] + bias[gn];
        if (RELU) v = fmaxf(v, 0.f);
        if (RES == 1) v += resid[(size_t)gm * N + gn];
        Cout[(size_t)gm * N + gn] = v;
      }
    }
  }
}

// ---------------------------------------------------------------------------
// Split-bf16 MFMA GEMM (sigma-safe, ~1e-5 relative error):
// C = Ahi@Bhi + Ahi@Blo + Alo@Bhi + bias.  A fp32 split in staging; B from
// pre-split WThi/WTlo [N][K]. 48 MFMA per 32-wide K-tile; 40 KB LDS.
// ---------------------------------------------------------------------------
__global__ __launch_bounds__(256)
void mfma_gemm3_kernel(const float* __restrict__ A,
                       const unsigned short* __restrict__ WThi,
                       const unsigned short* __restrict__ WTlo,
                       const float* __restrict__ bias, float* __restrict__ Cout,
                       int M, int N, int K) {
  __shared__ unsigned short AsHi[128 * 40];
  __shared__ unsigned short AsLo[128 * 40];
  __shared__ unsigned short BsHi[128 * 40];
  __shared__ unsigned short BsLo[128 * 40];
  const int tid = threadIdx.x;
  const int wave = tid >> 6, lane = tid & 63;
  const int quad = lane >> 4, l16 = lane & 15;
  const int wrow = (wave >> 1) * 64, wcol = (wave & 1) * 64;
  const int m0 = blockIdx.x * 128, n0 = blockIdx.y * 128;

  floatx4 acc[4][4];
#pragma unroll
  for (int i = 0; i < 4; i++)
#pragma unroll
    for (int j = 0; j < 4; j++) acc[i][j] = (floatx4){0.f, 0.f, 0.f, 0.f};

  for (int k0 = 0; k0 < K; k0 += 32) {
#pragma unroll
    for (int r = 0; r < 4; r++) {
      int e = (tid + r * 256) * 4;
      int row = e >> 5, col = e & 31;
      int gm = m0 + row;
      float4 v = make_float4(0.f, 0.f, 0.f, 0.f);
      if (gm < M) v = *(const float4*)(A + (size_t)gm * K + k0 + col);
      ushort4 hi, lo;
      hi.x = f2bf(v.x); lo.x = f2bf(v.x - bf2f(hi.x));
      hi.y = f2bf(v.y); lo.y = f2bf(v.y - bf2f(hi.y));
      hi.z = f2bf(v.z); lo.z = f2bf(v.z - bf2f(hi.z));
      hi.w = f2bf(v.w); lo.w = f2bf(v.w - bf2f(hi.w));
      *(ushort4*)&AsHi[row * 40 + col] = hi;
      *(ushort4*)&AsLo[row * 40 + col] = lo;
    }
#pragma unroll
    for (int r = 0; r < 4; r++) {
      int e = (tid + r * 256) * 4;
      int n = e >> 5, k = e & 31;
      *(ushort4*)&BsHi[n * 40 + k] =
          *(const ushort4*)(WThi + (size_t)(n0 + n) * K + k0 + k);
      *(ushort4*)&BsLo[n * 40 + k] =
          *(const ushort4*)(WTlo + (size_t)(n0 + n) * K + k0 + k);
    }
    __syncthreads();
    bf16x8 ah[4], al[4], bh[4], bl[4];
#pragma unroll
    for (int i = 0; i < 4; i++) {
      ah[i] = *(const bf16x8*)&AsHi[(wrow + i * 16 + l16) * 40 + quad * 8];
      al[i] = *(const bf16x8*)&AsLo[(wrow + i * 16 + l16) * 40 + quad * 8];
    }
#pragma unroll
    for (int j = 0; j < 4; j++) {
      bh[j] = *(const bf16x8*)&BsHi[(wcol + j * 16 + l16) * 40 + quad * 8];
      bl[j] = *(const bf16x8*)&BsLo[(wcol + j * 16 + l16) * 40 + quad * 8];
    }
#pragma unroll
    for (int i = 0; i < 4; i++)
#pragma unroll
      for (int j = 0; j < 4; j++) {
        acc[i][j] = __builtin_amdgcn_mfma_f32_16x16x32_bf16(ah[i], bh[j],
                                                            acc[i][j], 0, 0, 0);
        acc[i][j] = __builtin_amdgcn_mfma_f32_16x16x32_bf16(ah[i], bl[j],
                                                            acc[i][j], 0, 0, 0);
        acc[i][j] = __builtin_amdgcn_mfma_f32_16x16x32_bf16(al[i], bh[j],
                                                            acc[i][j], 0, 0, 0);
      }
    __syncthreads();
  }
#pragma unroll
  for (int i = 0; i < 4; i++) {
#pragma unroll
    for (int p = 0; p < 4; p++) {
      int gm = m0 + wrow + i * 16 + quad * 4 + p;
      if (gm >= M) continue;
#pragma unroll
      for (int j = 0; j < 4; j++) {
        int gn = n0 + wcol + j * 16 + l16;
        Cout[(size_t)gm * N + gn] = acc[i][j][p] + bias[gn];
      }
    }
  }
}

// ---------------------------------------------------------------------------
// Class attention
// ---------------------------------------------------------------------------
__global__ __launch_bounds__(256)
void class_attn_kernel(const float* __restrict__ qkv, float* __restrict__ cls, int L) {
  __shared__ float q[64];
  __shared__ float sc[3200];
  __shared__ float red[8];
  __shared__ float pv[256];
  const int h = blockIdx.x & 7, b = blockIdx.x >> 3;
  const int tid = threadIdx.x;
  if (tid < 64) q[tid] = qkv[(size_t)b * 1536 + h * 64 + tid] * 0.125f;
  __syncthreads();
  float lmax = -3.4e38f;
  for (int l = tid; l < L; l += 256) {
    const float* kr = qkv + (size_t)(l * 8 + b) * 1536 + 512 + h * 64;
    float s = 0;
#pragma unroll 8
    for (int d2 = 0; d2 < 64; d2++) s += q[d2] * kr[d2];
    sc[l] = s;
    lmax = fmaxf(lmax, s);
  }
  lmax = wave_reduce_max(lmax);
  if ((tid & 63) == 0) red[tid >> 6] = lmax;
  __syncthreads();
  float gmax = fmaxf(fmaxf(red[0], red[1]), fmaxf(red[2], red[3]));
  float lsum = 0;
  for (int l = tid; l < L; l += 256) {
    float e = expf(sc[l] - gmax);
    sc[l] = e;
    lsum += e;
  }
  lsum = wave_reduce_sum(lsum);
  if ((tid & 63) == 0) red[4 + (tid >> 6)] = lsum;
  __syncthreads();
  float gsum = red[4] + red[5] + red[6] + red[7];
  const int g = tid >> 6, d = tid & 63;
  float acc = 0;
  for (int l = g; l < L; l += 4)
    acc += sc[l] * qkv[(size_t)(l * 8 + b) * 1536 + 1024 + h * 64 + d];
  pv[g * 64 + d] = acc;
  __syncthreads();
  if (g == 0) {
    float tot = pv[d] + pv[64 + d] + pv[128 + d] + pv[192 + d];
    cls[b * CC + h * 64 + d] = tot / gsum;
  }
}

// ---------------------------------------------------------------------------
// Temporal attention + sigma top-k pooling (fp32 — rank-critical).
// ---------------------------------------------------------------------------
__global__ __launch_bounds__(256)
void temporal_attn_kernel(const float* __restrict__ qkv, float* __restrict__ Y,
                          int* __restrict__ idxbuf, int t, int tp, int pk) {
  __shared__ float qs[16 * 65], ks[16 * 65], vs[16 * 65];
  __shared__ float a[16 * 17];
  __shared__ float sig[16];
  __shared__ int keepf[16];
  __shared__ int klist[16];
  const int g = blockIdx.x;
  const int w = g % WHT;
  const int bb = (g / WHT) & 7;
  const int h = g / (WHT * 8);
  const int tid = threadIdx.x;
  const int td = t * 64;
  for (int e = tid; e < td; e += 256) {
    int tt = e >> 6, d = e & 63;
    size_t rb = (size_t)((1 + tt * WHT + w) * 8 + bb) * 1536 + h * 64 + d;
    qs[tt * 65 + d] = qkv[rb] * 0.125f;
    ks[tt * 65 + d] = qkv[rb + 512];
    vs[tt * 65 + d] = qkv[rb + 1024];
  }
  __syncthreads();
  if (tid < t * t) {
    int qi = tid / t, ki = tid % t;
    const float* qp = &qs[qi * 65];
    const float* kp = &ks[ki * 65];
    float s = 0;
#pragma unroll 8
    for (int d2 = 0; d2 < 64; d2++) s += qp[d2] * kp[d2];
    a[qi * 17 + ki] = s;
  }
  __syncthreads();
  if (tid < t) {
    float* row = &a[tid * 17];
    float m = row[0];
    for (int k2 = 1; k2 < t; k2++) m = fmaxf(m, row[k2]);
    float sum = 0;
    for (int k2 = 0; k2 < t; k2++) {
      float e2 = expf(row[k2] - m);
      row[k2] = e2;
      sum += e2;
    }
    float inv = 1.f / sum;
    for (int k2 = 0; k2 < t; k2++) row[k2] *= inv;
  }
  __syncthreads();
  if (pk > 0) {
    if (tid < t) {
      const float* row = &a[tid * 17];
      float mean = 0;
      for (int k2 = 0; k2 < t; k2++) mean += row[k2];
      mean /= (float)t;
      float var = 0;
      for (int k2 = 0; k2 < t; k2++) {
        float dl = row[k2] - mean;
        var += dl * dl;
      }
      var /= (float)(t - 1);
      sig[tid] = sqrtf(var);
    }
    __syncthreads();
    if (tid < t) {
      float sv = sig[tid];
      int r = 0;
      for (int q2 = 0; q2 < t; q2++) {
        float so = sig[q2];
        if (so > sv || (so == sv && q2 < tid)) r++;
      }
      keepf[tid] = (r < tp) ? 1 : 0;
    }
    __syncthreads();
    if (tid < t && keepf[tid]) {
      int ppos = 0;
      for (int q2 = 0; q2 < tid; q2++) ppos += keepf[q2];
      klist[ppos] = tid;
      idxbuf[((h * 8 + bb) * WHT + w) * 16 + ppos] = tid;
    }
  } else {
    if (tid < t) klist[tid] = tid;
  }
  __syncthreads();
  const int gq = tid >> 6, d = tid & 63;
  for (int qi = gq; qi < tp; qi += 4) {
    int qq = klist[qi];
    const float* arow = &a[qq * 17];
    float acc = 0;
    for (int k2 = 0; k2 < t; k2++) acc += arow[k2] * vs[k2 * 65 + d];
    Y[(size_t)((qi * WHT + w) * 8 + bb) * CC + h * 64 + d] = acc;
  }
}

// ---------------------------------------------------------------------------
// In-place temporal pooling of the residual stream X.
// ---------------------------------------------------------------------------
__global__ __launch_bounds__(256)
void pool_inplace_kernel(float* __restrict__ X, const int* __restrict__ idxbuf,
                         int tp) {
  const int b = blockIdx.x & 7;
  const int w = blockIdx.x >> 3;
  const int tid = threadIdx.x;
  const int c0 = tid, c1 = tid + 256;
  const int h0 = c0 >> 6, h1 = c1 >> 6;
  const int ib0 = ((h0 * 8 + b) * WHT + w) * 16;
  const int ib1 = ((h1 * 8 + b) * WHT + w) * 16;
  for (int q = 0; q < tp; q++) {
    int s0 = idxbuf[ib0 + q];
    int s1 = idxbuf[ib1 + q];
    size_t drow = (size_t)((1 + q * WHT + w) * 8 + b) * CC;
    if (s0 != q) {
      size_t srow = (size_t)((1 + s0 * WHT + w) * 8 + b) * CC;
      X[drow + c0] = X[srow + c0];
    }
    if (s1 != q) {
      size_t srow = (size_t)((1 + s1 * WHT + w) * 8 + b) * CC;
      X[drow + c1] = X[srow + c1];
    }
  }
}

// ---------------------------------------------------------------------------
// Spatial attention v3 (register-bounded)
// ---------------------------------------------------------------------------
__global__ __launch_bounds__(256)
void spatial_attn3_kernel(const float* __restrict__ qkv, float* __restrict__ outA) {
  __shared__ float Qs[16 * 68];
  __shared__ float Ks[64 * 68];
  __shared__ float Vs[64 * 68];
  __shared__ float S[16 * 200];
  const int blk = blockIdx.x;
  const int h = blk & 7;
  const int b = (blk >> 3) & 7;
  const int tq = blk >> 6;
  const int tid = threadIdx.x;
  const size_t base = (size_t)((size_t)tq * WHT * 8 + b) * 1536 + h * 64;

  const int i16 = tid >> 4;
  const int jj = tid & 15;
  const int qg = tid >> 6;
  const int d = tid & 63;

  for (int qt = 0; qt < 13; qt++) {
    __syncthreads();
    {
      int i = tid >> 4, f4 = (tid & 15) * 4;
      int w = qt * 16 + i;
      float4 v = make_float4(0.f, 0.f, 0.f, 0.f);
      if (w < WHT) {
        v = *(const float4*)(qkv + base + (size_t)w * 12288 + f4);
        v.x *= 0.125f; v.y *= 0.125f; v.z *= 0.125f; v.w *= 0.125f;
      }
      *(float4*)&Qs[i * 68 + f4] = v;
    }
    for (int kc = 0; kc < WHT; kc += 64) {
      const int cn = min(64, WHT - kc);
      __syncthreads();
#pragma unroll
      for (int r = 0; r < 4; r++) {
        int e = tid + r * 256;
        int j = e >> 4, f4 = (e & 15) * 4;
        int krow = kc + j;
        float4 v = make_float4(0.f, 0.f, 0.f, 0.f);
        if (krow < WHT)
          v = *(const float4*)(qkv + base + (size_t)krow * 12288 + 512 + f4);
        *(float4*)&Ks[j * 68 + f4] = v;
      }
      __syncthreads();
      float s0 = 0.f, s1 = 0.f, s2 = 0.f, s3 = 0.f;
      const float* qrow = &Qs[i16 * 68];
      const float* k0 = &Ks[jj * 68];
      const float* k1 = &Ks[(jj + 16) * 68];
      const float* k2 = &Ks[(jj + 32) * 68];
      const float* k3 = &Ks[(jj + 48) * 68];
#pragma unroll 2
      for (int d2 = 0; d2 < 64; d2 += 4) {
        float4 q4 = *(const float4*)(qrow + d2);
        float4 a0 = *(const float4*)(k0 + d2);
        float4 a1 = *(const float4*)(k1 + d2);
        float4 a2 = *(const float4*)(k2 + d2);
        float4 a3 = *(const float4*)(k3 + d2);
        s0 += q4.x * a0.x + q4.y * a0.y + q4.z * a0.z + q4.w * a0.w;
        s1 += q4.x * a1.x + q4.y * a1.y + q4.z * a1.z + q4.w * a1.w;
        s2 += q4.x * a2.x + q4.y * a2.y + q4.z * a2.z + q4.w * a2.w;
        s3 += q4.x * a3.x + q4.y * a3.y + q4.z * a3.z + q4.w * a3.w;
      }
      float* srow = &S[i16 * 200 + kc];
      if (jj < cn) srow[jj] = s0;
      if (jj + 16 < cn) srow[jj + 16] = s1;
      if (jj + 32 < cn) srow[jj + 32] = s2;
      if (jj + 48 < cn) srow[jj + 48] = s3;
    }
    __syncthreads();
    {
      const int row = tid >> 4;
      const int lane = tid & 15;
      float* srow = &S[row * 200];
      float m = -3.4e38f;
      for (int j = lane; j < WHT; j += 16) m = fmaxf(m, srow[j]);
#pragma unroll
      for (int msk = 8; msk >= 1; msk >>= 1) m = fmaxf(m, __shfl_xor(m, msk, 16));
      float l = 0.f;
      for (int j = lane; j < WHT; j += 16) {
        float e = expf(srow[j] - m);
        srow[j] = e;
        l += e;
      }
#pragma unroll
      for (int msk = 8; msk >= 1; msk >>= 1) l += __shfl_xor(l, msk, 16);
      float inv = 1.f / l;
      for (int j = lane; j < WHT; j += 16) srow[j] *= inv;
    }
    float acc[4] = {0.f, 0.f, 0.f, 0.f};
    for (int vc = 0; vc < WHT; vc += 64) {
      const int cn = min(64, WHT - vc);
      __syncthreads();
#pragma unroll
      for (int r = 0; r < 4; r++) {
        int e = tid + r * 256;
        int j = e >> 4, f4 = (e & 15) * 4;
        int vrow = vc + j;
        float4 v = make_float4(0.f, 0.f, 0.f, 0.f);
        if (vrow < WHT)
          v = *(const float4*)(qkv + base + (size_t)vrow * 12288 + 1024 + f4);
        *(float4*)&Vs[j * 68 + f4] = v;
      }
      __syncthreads();
#pragma unroll 2
      for (int j4 = 0; j4 < cn; j4 += 4) {
        float v0 = Vs[(j4 + 0) * 68 + d];
        float v1 = Vs[(j4 + 1) * 68 + d];
        float v2 = Vs[(j4 + 2) * 68 + d];
        float v3 = Vs[(j4 + 3) * 68 + d];
#pragma unroll
        for (int u = 0; u < 4; u++) {
          float4 s4 = *(const float4*)&S[(qg + 4 * u) * 200 + vc + j4];
          acc[u] += s4.x * v0 + s4.y * v1 + s4.z * v2 + s4.w * v3;
        }
      }
    }
#pragma unroll
    for (int u = 0; u < 4; u++) {
      int i = qg + 4 * u;
      int w = qt * 16 + i;
      if (w < WHT)
        outA[(size_t)((1 + tq * WHT + w) * 8 + b) * CC + h * 64 + d] = acc[u];
    }
  }
}

// ---------------------------------------------------------------------------
// Final LN (token 0 only) + classifier head
// ---------------------------------------------------------------------------
__global__ __launch_bounds__(256)
void head_kernel(const float* __restrict__ X, const float* __restrict__ enw,
                 const float* __restrict__ enb, const float* __restrict__ fcw,
                 const float* __restrict__ fcb, float* __restrict__ out) {
  __shared__ float nx[512];
  __shared__ float red[8];
  const int b = blockIdx.x, tid = threadIdx.x;
  const float* x = X + (size_t)b * CC;
  float v0 = x[tid], v1 = x[tid + 256];
  float s = wave_reduce_sum(v0 + v1);
  if ((tid & 63) == 0) red[tid >> 6] = s;
  __syncthreads();
  float mean = (red[0] + red[1] + red[2] + red[3]) * (1.f / 512.f);
  float d0 = v0 - mean, d1 = v1 - mean;
  float vs = wave_reduce_sum(d0 * d0 + d1 * d1);
  if ((tid & 63) == 0) red[4 + (tid >> 6)] = vs;
  __syncthreads();
  float var = (red[4] + red[5] + red[6] + red[7]) * (1.f / 512.f);
  float inv = 1.0f / sqrtf(var + 1e-5f);
  nx[tid] = d0 * inv * enw[tid] + enb[tid];
  nx[tid + 256] = d1 * inv * enw[tid + 256] + enb[tid + 256];
  __syncthreads();
  if (tid < NCLS) {
    float acc = fcb[tid];
    for (int c = 0; c < 512; c++) acc += nx[c] * fcw[c * NCLS + tid];
    out[b * NCLS + tid] = acc;
  }
}

// ---------------------------------------------------------------------------
extern "C" void kernel_launch(void* const* d_in, const int* in_sizes, int n_in,
                              void* d_out, int out_size, void* d_ws, size_t ws_size,
                              hipStream_t stream) {
  (void)in_sizes; (void)n_in; (void)out_size; (void)ws_size;
  const float* src  = (const float*)d_in[0];
  const float* cw   = (const float*)d_in[1];
  const float* cb   = (const float*)d_in[2];
  const float* clst = (const float*)d_in[3];
  const float* pos  = (const float*)d_in[4];
  const float* Wt   = (const float*)d_in[5];
  const float* bt   = (const float*)d_in[6];
  const float* Wsp  = (const float*)d_in[7];
  const float* bsp  = (const float*)d_in[8];
  const float* Wo   = (const float*)d_in[9];
  const float* bo   = (const float*)d_in[10];
  const float* n1w  = (const float*)d_in[11];
  const float* n1b  = (const float*)d_in[12];
  const float* n2w  = (const float*)d_in[13];
  const float* n2b  = (const float*)d_in[14];
  const float* W1   = (const float*)d_in[15];
  const float* b1   = (const float*)d_in[16];
  const float* W2   = (const float*)d_in[17];
  const float* b2   = (const float*)d_in[18];
  const float* enw  = (const float*)d_in[19];
  const float* enb  = (const float*)d_in[20];
  const float* fcw  = (const float*)d_in[21];
  const float* fcb  = (const float*)d_in[22];

  float* ws = (float*)d_ws;
  const size_t TOKR = (size_t)3137 * 8;
  float* X0  = ws;                              // TOKR*512
  float* Ab  = X0 + TOKR * 512;                 // TOKR*512
  float* QKV = Ab + TOKR * 512;                 // TOKR*1536 (also FFN mid / im2col)
  float* CLS = QKV + TOKR * 1536;               // 8*512
  int*   IDX = (int*)(CLS + 8 * 512);           // 8*8*196*16 ints
  unsigned short* WT1 = (unsigned short*)(IDX + 8 * 8 * WHT * 16);  // 2048*512
  unsigned short* WT2 = WT1 + 2048 * 512;                           // 2048*512

  // Patch embed as im2col + split-bf16 MFMA GEMM (M=25088, N=512, K=768).
  // conv_w is [512][3*16*16] = [N][K] already -> flat split, no transpose.
  wsplit_flat_kernel<<<(512 * 768 + 255) / 256, 256, 0, stream>>>(
      cw, WT1, WT2, 512 * 768);
  im2col_kernel<<<(25088 * 192) / 256, 256, 0, stream>>>(src, QKV);
  mfma_gemm3_kernel<<<dim3(25088 / 128, 4), 256, 0, stream>>>(
      QKV, WT1, WT2, cb, X0 + 8 * CC, 25088, 512, 768);
  cls_init_kernel<<<8, 512, 0, stream>>>(clst, X0);

  float* Xc = X0;
  int t = 16;
  const int FFN_CHUNK = 16384;
  for (int i = 0; i < 6; i++) {
    const int pk = (i & 1) ? 2 : 0;
    const int tp = t - pk;
    const int L = 1 + t * WHT;
    const int Lo = 1 + tp * WHT;
    const int M = L * 8, Mo = Lo * 8, My = tp * WHT * 8;

    ln_kernel<<<M, 256, 0, stream>>>(Xc, Ab, n1w + (size_t)i * 512, n1b + (size_t)i * 512,
                                     (i == 0) ? pos : nullptr);
    // sigma-critical Wt: split-bf16 MFMA (hi/lo), fp32-class accuracy
    wtrans_split_kernel<<<dim3(1536 / 32, 512 / 32), 256, 0, stream>>>(
        Wt + (size_t)i * 512 * 1536, WT1, WT2, 1536, 512);
    mfma_gemm3_kernel<<<dim3((M + 127) / 128, 12), 256, 0, stream>>>(
        Ab, WT1, WT2, bt + (size_t)i * 1536, QKV, M, 1536, 512);
    class_attn_kernel<<<64, 256, 0, stream>>>(QKV, CLS, L);
    temporal_attn_kernel<<<HH * BB * WHT, 256, 0, stream>>>(QKV, Ab, IDX, t, tp, pk);
    // Ws: plain bf16 MFMA
    wtrans_kernel<<<dim3(1536 / 32, 512 / 32), 256, 0, stream>>>(
        Wsp + (size_t)i * 512 * 1536, WT1, 1536, 512);
    mfma_gemm_kernel<0, 0><<<dim3((My + 127) / 128, 12), 256, 0, stream>>>(
        Ab, WT1, bsp + (size_t)i * 1536, QKV, My, 1536, 512, nullptr);
    copy_cls_kernel<<<8, 512, 0, stream>>>(CLS, Ab);
    spatial_attn3_kernel<<<64 * tp, 256, 0, stream>>>(QKV, Ab);
    if (pk > 0)
      pool_inplace_kernel<<<8 * WHT, 256, 0, stream>>>(Xc, IDX, tp);
    // Wo: plain bf16 MFMA + residual
    wtrans_kernel<<<dim3(512 / 32, 512 / 32), 256, 0, stream>>>(
        Wo + (size_t)i * 512 * 512, WT1, 512, 512);
    mfma_gemm_kernel<0, 1><<<dim3((Mo + 127) / 128, 4), 256, 0, stream>>>(
        Ab, WT1, bo + (size_t)i * 512, Xc, Mo, 512, 512, Xc);
    ln_kernel<<<Mo, 256, 0, stream>>>(Xc, Ab, n2w + (size_t)i * 512, n2b + (size_t)i * 512,
                                      nullptr);
    // FFN: plain bf16 MFMA
    wtrans_kernel<<<dim3(2048 / 32, 512 / 32), 256, 0, stream>>>(
        W1 + (size_t)i * 512 * 2048, WT1, 2048, 512);
    wtrans_kernel<<<dim3(512 / 32, 2048 / 32), 256, 0, stream>>>(
        W2 + (size_t)i * 2048 * 512, WT2, 512, 2048);
    for (int off = 0; off < Mo; off += FFN_CHUNK) {
      int R = Mo - off;
      if (R > FFN_CHUNK) R = FFN_CHUNK;
      mfma_gemm_kernel<1, 0><<<dim3((R + 127) / 128, 16), 256, 0, stream>>>(
          Ab + (size_t)off * 512, WT1, b1 + (size_t)i * 2048, QKV, R, 2048, 512,
          nullptr);
      mfma_gemm_kernel<0, 1><<<dim3((R + 127) / 128, 4), 256, 0, stream>>>(
          QKV, WT2, b2 + (size_t)i * 512, Xc + (size_t)off * 512, R, 512, 2048,
          Xc + (size_t)off * 512);
    }
    t = tp;
  }
  head_kernel<<<8, 256, 0, stream>>>(Xc, enw, enb, fcw, fcb, (float*)d_out);
}

// Round 2
// 7074.438 us; speedup vs baseline: 1.4014x; 1.2599x over previous
//
#include <hip/hip_runtime.h>
#include <math.h>

// ---------------------------------------------------------------------------
// CompactVidTr forward.
//  - Patch-embed conv: im2col + split-bf16 MFMA GEMM (M=25088,N=512,K=768).
//  - Wt (QKV) GEMM: split-bf16 MFMA (hi/lo, 3 terms) -> fp32-class accuracy
//    for the sigma-top-k ranking path.
//  - Spatial attention: split-bf16 MFMA flash kernel (QK^T and PV both 3-term
//    hi/lo split -> fp32-class accuracy; softmax fp32 in-register).
//  - Ws/Wo/FFN GEMMs: plain bf16 MFMA (incremental-error paths).
//  - Temporal/class attention + LN: fp32 vector.
// Layout: token matrices row-major [row = l*B + b][C]; l=0 is cls. B=8, C=512.
//
// Workspace (261.9 MB < 268.4 MB):
//   X   : 3137*8 x 512  fp32   (51.4 MB)  residual stream, pooled IN PLACE
//   Ab  : 3137*8 x 512  fp32   (51.4 MB)  LN out / attention out staging
//   QKV : 3137*8 x 1536 fp32  (154.1 MB)  qkv GEMM out; FFN mid; im2col stage
//   CLS : 8x512 fp32, IDX: 8*8*196*16 int (~0.8 MB)
//   WT1 : 2048*512 bf16 (2.1 MB)  weight scratch
//   WT2 : 2048*512 bf16 (2.1 MB)  weight scratch
// ---------------------------------------------------------------------------

#define BB 8
#define CC 512
#define HH 8
#define HD 64
#define WHT 196
#define NCLS 157

typedef short bf16x8 __attribute__((ext_vector_type(8)));
typedef float floatx4 __attribute__((ext_vector_type(4)));

__device__ __forceinline__ unsigned short f2bf(float f) {
  unsigned u = __float_as_uint(f);
  unsigned r = u + 0x7FFFu + ((u >> 16) & 1u);  // RNE
  return (unsigned short)(r >> 16);
}
__device__ __forceinline__ float bf2f(unsigned short h) {
  return __uint_as_float((unsigned)h << 16);
}
// truncation split: hi = top-16-bits, lo = RNE(residual); reconstruct ~2^-17
__device__ __forceinline__ void splitf(float x, unsigned short& h, unsigned short& l) {
  unsigned u = __float_as_uint(x);
  unsigned hs = u >> 16;
  float rem = x - __uint_as_float(hs << 16);
  h = (unsigned short)hs;
  l = f2bf(rem);
}

__device__ __forceinline__ float wave_reduce_sum(float v) {
#pragma unroll
  for (int o = 32; o > 0; o >>= 1) v += __shfl_down(v, o, 64);
  return v;
}
__device__ __forceinline__ float wave_reduce_max(float v) {
#pragma unroll
  for (int o = 32; o > 0; o >>= 1) v = fmaxf(v, __shfl_down(v, o, 64));
  return v;
}

// ---------------------------------------------------------------------------
// im2col: src [B=8][3][16][224][224] -> IM [25088][768] fp32 (pure permute).
// ---------------------------------------------------------------------------
__global__ __launch_bounds__(256)
void im2col_kernel(const float* __restrict__ src, float* __restrict__ IM) {
  int gid = blockIdx.x * 256 + threadIdx.x;
  int k4 = gid % 192;
  int u = gid / 192;
  if (u >= 25088) return;
  int b = u & 7;
  int s = u >> 3;
  int tt = s / WHT;
  int w2 = s % WHT;
  int ph = w2 / 14, pw = w2 % 14;
  int k = k4 * 4;
  int ci = k >> 8;
  int rem = k & 255;
  int py = rem >> 4, px = rem & 15;
  const float* sp = src + (size_t)b * (3 * 16 * 224 * 224) +
                    (size_t)ci * (16 * 224 * 224) + (size_t)tt * (224 * 224) +
                    (size_t)(ph * 16 + py) * 224 + pw * 16 + px;
  *(float4*)(IM + (size_t)u * 768 + k) = *(const float4*)sp;
}

__global__ __launch_bounds__(256)
void wsplit_flat_kernel(const float* __restrict__ W,
                        unsigned short* __restrict__ Whi,
                        unsigned short* __restrict__ Wlo, int total) {
  int i = blockIdx.x * 256 + threadIdx.x;
  if (i >= total) return;
  float w = W[i];
  unsigned short hi = f2bf(w);
  Whi[i] = hi;
  Wlo[i] = f2bf(w - bf2f(hi));
}

__global__ void cls_init_kernel(const float* __restrict__ clst, float* __restrict__ X) {
  X[(size_t)blockIdx.x * CC + threadIdx.x] = clst[threadIdx.x];
}

__global__ void copy_cls_kernel(const float* __restrict__ cls, float* __restrict__ A) {
  A[(size_t)blockIdx.x * CC + threadIdx.x] = cls[(size_t)blockIdx.x * CC + threadIdx.x];
}

// ---------------------------------------------------------------------------
// LayerNorm over C=512; one block per row; optional +pos (layer0 q-input)
// ---------------------------------------------------------------------------
__global__ __launch_bounds__(256)
void ln_kernel(const float* __restrict__ X, float* __restrict__ O,
               const float* __restrict__ w, const float* __restrict__ b,
               const float* __restrict__ pos) {
  __shared__ float red[8];
  const int row = blockIdx.x, tid = threadIdx.x;
  const float* x = X + (size_t)row * CC;
  float v0 = x[tid], v1 = x[tid + 256];
  float s = wave_reduce_sum(v0 + v1);
  if ((tid & 63) == 0) red[tid >> 6] = s;
  __syncthreads();
  float mean = (red[0] + red[1] + red[2] + red[3]) * (1.f / 512.f);
  float d0 = v0 - mean, d1 = v1 - mean;
  float vs = wave_reduce_sum(d0 * d0 + d1 * d1);
  if ((tid & 63) == 0) red[4 + (tid >> 6)] = vs;
  __syncthreads();
  float var = (red[4] + red[5] + red[6] + red[7]) * (1.f / 512.f);
  float inv = 1.0f / sqrtf(var + 1e-5f);
  float o0 = d0 * inv * w[tid] + b[tid];
  float o1 = d1 * inv * w[tid + 256] + b[tid + 256];
  if (pos) {
    const float* pr = pos + (size_t)(row >> 3) * CC;
    o0 += pr[tid];
    o1 += pr[tid + 256];
  }
  O[(size_t)row * CC + tid] = o0;
  O[(size_t)row * CC + tid + 256] = o1;
}

// ---------------------------------------------------------------------------
// Weight transpose + fp32->bf16 (plain): W [K][N] -> WT [N][K]
// ---------------------------------------------------------------------------
__global__ __launch_bounds__(256)
void wtrans_kernel(const float* __restrict__ W, unsigned short* __restrict__ WT,
                   int N, int K) {
  __shared__ float tile[32][33];
  const int tid = threadIdx.x;
  const int tx = tid & 31, ty = tid >> 5;
  const int n0 = blockIdx.x * 32, k0 = blockIdx.y * 32;
#pragma unroll
  for (int r = 0; r < 4; r++) {
    int kk = ty + r * 8;
    tile[kk][tx] = W[(size_t)(k0 + kk) * N + n0 + tx];
  }
  __syncthreads();
#pragma unroll
  for (int r = 0; r < 4; r++) {
    int nn = ty + r * 8;
    WT[(size_t)(n0 + nn) * K + k0 + tx] = f2bf(tile[tx][nn]);
  }
}

// ---------------------------------------------------------------------------
// Weight transpose + split fp32 -> (hi, lo) bf16: W [K][N] -> WThi/WTlo [N][K]
// ---------------------------------------------------------------------------
__global__ __launch_bounds__(256)
void wtrans_split_kernel(const float* __restrict__ W,
                         unsigned short* __restrict__ WThi,
                         unsigned short* __restrict__ WTlo, int N, int K) {
  __shared__ float tile[32][33];
  const int tid = threadIdx.x;
  const int tx = tid & 31, ty = tid >> 5;
  const int n0 = blockIdx.x * 32, k0 = blockIdx.y * 32;
#pragma unroll
  for (int r = 0; r < 4; r++) {
    int kk = ty + r * 8;
    tile[kk][tx] = W[(size_t)(k0 + kk) * N + n0 + tx];
  }
  __syncthreads();
#pragma unroll
  for (int r = 0; r < 4; r++) {
    int nn = ty + r * 8;
    float w = tile[tx][nn];
    unsigned short hi = f2bf(w);
    unsigned short lo = f2bf(w - bf2f(hi));
    WThi[(size_t)(n0 + nn) * K + k0 + tx] = hi;
    WTlo[(size_t)(n0 + nn) * K + k0 + tx] = lo;
  }
}

// ---------------------------------------------------------------------------
// Plain bf16 MFMA GEMM: C = A(M,K) @ W(K,N) + bias [+relu] [+residual]
// ---------------------------------------------------------------------------
template <int RELU, int RES>
__global__ __launch_bounds__(256)
void mfma_gemm_kernel(const float* __restrict__ A,
                      const unsigned short* __restrict__ WT,
                      const float* __restrict__ bias, float* __restrict__ Cout,
                      int M, int N, int K, const float* __restrict__ resid) {
  __shared__ unsigned short AsU[128 * 40];
  __shared__ unsigned short BsU[128 * 40];
  const int tid = threadIdx.x;
  const int wave = tid >> 6, lane = tid & 63;
  const int quad = lane >> 4, l16 = lane & 15;
  const int wrow = (wave >> 1) * 64, wcol = (wave & 1) * 64;
  const int m0 = blockIdx.x * 128, n0 = blockIdx.y * 128;

  floatx4 acc[4][4];
#pragma unroll
  for (int i = 0; i < 4; i++)
#pragma unroll
    for (int j = 0; j < 4; j++) acc[i][j] = (floatx4){0.f, 0.f, 0.f, 0.f};

  for (int k0 = 0; k0 < K; k0 += 32) {
#pragma unroll
    for (int r = 0; r < 4; r++) {
      int e = (tid + r * 256) * 4;
      int row = e >> 5, col = e & 31;
      int gm = m0 + row;
      float4 v = make_float4(0.f, 0.f, 0.f, 0.f);
      if (gm < M) v = *(const float4*)(A + (size_t)gm * K + k0 + col);
      ushort4 o;
      o.x = f2bf(v.x); o.y = f2bf(v.y); o.z = f2bf(v.z); o.w = f2bf(v.w);
      *(ushort4*)&AsU[row * 40 + col] = o;
    }
#pragma unroll
    for (int r = 0; r < 4; r++) {
      int e = (tid + r * 256) * 4;
      int n = e >> 5, k = e & 31;
      ushort4 w = *(const ushort4*)(WT + (size_t)(n0 + n) * K + k0 + k);
      *(ushort4*)&BsU[n * 40 + k] = w;
    }
    __syncthreads();
    bf16x8 af[4], bf[4];
#pragma unroll
    for (int i = 0; i < 4; i++)
      af[i] = *(const bf16x8*)&AsU[(wrow + i * 16 + l16) * 40 + quad * 8];
#pragma unroll
    for (int j = 0; j < 4; j++)
      bf[j] = *(const bf16x8*)&BsU[(wcol + j * 16 + l16) * 40 + quad * 8];
#pragma unroll
    for (int i = 0; i < 4; i++)
#pragma unroll
      for (int j = 0; j < 4; j++)
        acc[i][j] = __builtin_amdgcn_mfma_f32_16x16x32_bf16(af[i], bf[j],
                                                            acc[i][j], 0, 0, 0);
    __syncthreads();
  }
#pragma unroll
  for (int i = 0; i < 4; i++) {
#pragma unroll
    for (int p = 0; p < 4; p++) {
      int gm = m0 + wrow + i * 16 + quad * 4 + p;
      if (gm >= M) continue;
#pragma unroll
      for (int j = 0; j < 4; j++) {
        int gn = n0 + wcol + j * 16 + l16;
        float v = acc[i][j][p] + bias[gn];
        if (RELU) v = fmaxf(v, 0.f);
        if (RES == 1) v += resid[(size_t)gm * N + gn];
        Cout[(size_t)gm * N + gn] = v;
      }
    }
  }
}

// ---------------------------------------------------------------------------
// Split-bf16 MFMA GEMM (sigma-safe, ~1e-5 relative error)
// ---------------------------------------------------------------------------
__global__ __launch_bounds__(256)
void mfma_gemm3_kernel(const float* __restrict__ A,
                       const unsigned short* __restrict__ WThi,
                       const unsigned short* __restrict__ WTlo,
                       const float* __restrict__ bias, float* __restrict__ Cout,
                       int M, int N, int K) {
  __shared__ unsigned short AsHi[128 * 40];
  __shared__ unsigned short AsLo[128 * 40];
  __shared__ unsigned short BsHi[128 * 40];
  __shared__ unsigned short BsLo[128 * 40];
  const int tid = threadIdx.x;
  const int wave = tid >> 6, lane = tid & 63;
  const int quad = lane >> 4, l16 = lane & 15;
  const int wrow = (wave >> 1) * 64, wcol = (wave & 1) * 64;
  const int m0 = blockIdx.x * 128, n0 = blockIdx.y * 128;

  floatx4 acc[4][4];
#pragma unroll
  for (int i = 0; i < 4; i++)
#pragma unroll
    for (int j = 0; j < 4; j++) acc[i][j] = (floatx4){0.f, 0.f, 0.f, 0.f};

  for (int k0 = 0; k0 < K; k0 += 32) {
#pragma unroll
    for (int r = 0; r < 4; r++) {
      int e = (tid + r * 256) * 4;
      int row = e >> 5, col = e & 31;
      int gm = m0 + row;
      float4 v = make_float4(0.f, 0.f, 0.f, 0.f);
      if (gm < M) v = *(const float4*)(A + (size_t)gm * K + k0 + col);
      ushort4 hi, lo;
      hi.x = f2bf(v.x); lo.x = f2bf(v.x - bf2f(hi.x));
      hi.y = f2bf(v.y); lo.y = f2bf(v.y - bf2f(hi.y));
      hi.z = f2bf(v.z); lo.z = f2bf(v.z - bf2f(hi.z));
      hi.w = f2bf(v.w); lo.w = f2bf(v.w - bf2f(hi.w));
      *(ushort4*)&AsHi[row * 40 + col] = hi;
      *(ushort4*)&AsLo[row * 40 + col] = lo;
    }
#pragma unroll
    for (int r = 0; r < 4; r++) {
      int e = (tid + r * 256) * 4;
      int n = e >> 5, k = e & 31;
      *(ushort4*)&BsHi[n * 40 + k] =
          *(const ushort4*)(WThi + (size_t)(n0 + n) * K + k0 + k);
      *(ushort4*)&BsLo[n * 40 + k] =
          *(const ushort4*)(WTlo + (size_t)(n0 + n) * K + k0 + k);
    }
    __syncthreads();
    bf16x8 ah[4], al[4], bh[4], bl[4];
#pragma unroll
    for (int i = 0; i < 4; i++) {
      ah[i] = *(const bf16x8*)&AsHi[(wrow + i * 16 + l16) * 40 + quad * 8];
      al[i] = *(const bf16x8*)&AsLo[(wrow + i * 16 + l16) * 40 + quad * 8];
    }
#pragma unroll
    for (int j = 0; j < 4; j++) {
      bh[j] = *(const bf16x8*)&BsHi[(wcol + j * 16 + l16) * 40 + quad * 8];
      bl[j] = *(const bf16x8*)&BsLo[(wcol + j * 16 + l16) * 40 + quad * 8];
    }
#pragma unroll
    for (int i = 0; i < 4; i++)
#pragma unroll
      for (int j = 0; j < 4; j++) {
        acc[i][j] = __builtin_amdgcn_mfma_f32_16x16x32_bf16(ah[i], bh[j],
                                                            acc[i][j], 0, 0, 0);
        acc[i][j] = __builtin_amdgcn_mfma_f32_16x16x32_bf16(ah[i], bl[j],
                                                            acc[i][j], 0, 0, 0);
        acc[i][j] = __builtin_amdgcn_mfma_f32_16x16x32_bf16(al[i], bh[j],
                                                            acc[i][j], 0, 0, 0);
      }
    __syncthreads();
  }
#pragma unroll
  for (int i = 0; i < 4; i++) {
#pragma unroll
    for (int p = 0; p < 4; p++) {
      int gm = m0 + wrow + i * 16 + quad * 4 + p;
      if (gm >= M) continue;
#pragma unroll
      for (int j = 0; j < 4; j++) {
        int gn = n0 + wcol + j * 16 + l16;
        Cout[(size_t)gm * N + gn] = acc[i][j][p] + bias[gn];
      }
    }
  }
}

// ---------------------------------------------------------------------------
// Class attention
// ---------------------------------------------------------------------------
__global__ __launch_bounds__(256)
void class_attn_kernel(const float* __restrict__ qkv, float* __restrict__ cls, int L) {
  __shared__ float q[64];
  __shared__ float sc[3200];
  __shared__ float red[8];
  __shared__ float pv[256];
  const int h = blockIdx.x & 7, b = blockIdx.x >> 3;
  const int tid = threadIdx.x;
  if (tid < 64) q[tid] = qkv[(size_t)b * 1536 + h * 64 + tid] * 0.125f;
  __syncthreads();
  float lmax = -3.4e38f;
  for (int l = tid; l < L; l += 256) {
    const float* kr = qkv + (size_t)(l * 8 + b) * 1536 + 512 + h * 64;
    float s = 0;
#pragma unroll 8
    for (int d2 = 0; d2 < 64; d2++) s += q[d2] * kr[d2];
    sc[l] = s;
    lmax = fmaxf(lmax, s);
  }
  lmax = wave_reduce_max(lmax);
  if ((tid & 63) == 0) red[tid >> 6] = lmax;
  __syncthreads();
  float gmax = fmaxf(fmaxf(red[0], red[1]), fmaxf(red[2], red[3]));
  float lsum = 0;
  for (int l = tid; l < L; l += 256) {
    float e = expf(sc[l] - gmax);
    sc[l] = e;
    lsum += e;
  }
  lsum = wave_reduce_sum(lsum);
  if ((tid & 63) == 0) red[4 + (tid >> 6)] = lsum;
  __syncthreads();
  float gsum = red[4] + red[5] + red[6] + red[7];
  const int g = tid >> 6, d = tid & 63;
  float acc = 0;
  for (int l = g; l < L; l += 4)
    acc += sc[l] * qkv[(size_t)(l * 8 + b) * 1536 + 1024 + h * 64 + d];
  pv[g * 64 + d] = acc;
  __syncthreads();
  if (g == 0) {
    float tot = pv[d] + pv[64 + d] + pv[128 + d] + pv[192 + d];
    cls[b * CC + h * 64 + d] = tot / gsum;
  }
}

// ---------------------------------------------------------------------------
// Temporal attention + sigma top-k pooling (fp32 — rank-critical).
// ---------------------------------------------------------------------------
__global__ __launch_bounds__(256)
void temporal_attn_kernel(const float* __restrict__ qkv, float* __restrict__ Y,
                          int* __restrict__ idxbuf, int t, int tp, int pk) {
  __shared__ float qs[16 * 65], ks[16 * 65], vs[16 * 65];
  __shared__ float a[16 * 17];
  __shared__ float sig[16];
  __shared__ int keepf[16];
  __shared__ int klist[16];
  const int g = blockIdx.x;
  const int w = g % WHT;
  const int bb = (g / WHT) & 7;
  const int h = g / (WHT * 8);
  const int tid = threadIdx.x;
  const int td = t * 64;
  for (int e = tid; e < td; e += 256) {
    int tt = e >> 6, d = e & 63;
    size_t rb = (size_t)((1 + tt * WHT + w) * 8 + bb) * 1536 + h * 64 + d;
    qs[tt * 65 + d] = qkv[rb] * 0.125f;
    ks[tt * 65 + d] = qkv[rb + 512];
    vs[tt * 65 + d] = qkv[rb + 1024];
  }
  __syncthreads();
  if (tid < t * t) {
    int qi = tid / t, ki = tid % t;
    const float* qp = &qs[qi * 65];
    const float* kp = &ks[ki * 65];
    float s = 0;
#pragma unroll 8
    for (int d2 = 0; d2 < 64; d2++) s += qp[d2] * kp[d2];
    a[qi * 17 + ki] = s;
  }
  __syncthreads();
  if (tid < t) {
    float* row = &a[tid * 17];
    float m = row[0];
    for (int k2 = 1; k2 < t; k2++) m = fmaxf(m, row[k2]);
    float sum = 0;
    for (int k2 = 0; k2 < t; k2++) {
      float e2 = expf(row[k2] - m);
      row[k2] = e2;
      sum += e2;
    }
    float inv = 1.f / sum;
    for (int k2 = 0; k2 < t; k2++) row[k2] *= inv;
  }
  __syncthreads();
  if (pk > 0) {
    if (tid < t) {
      const float* row = &a[tid * 17];
      float mean = 0;
      for (int k2 = 0; k2 < t; k2++) mean += row[k2];
      mean /= (float)t;
      float var = 0;
      for (int k2 = 0; k2 < t; k2++) {
        float dl = row[k2] - mean;
        var += dl * dl;
      }
      var /= (float)(t - 1);
      sig[tid] = sqrtf(var);
    }
    __syncthreads();
    if (tid < t) {
      float sv = sig[tid];
      int r = 0;
      for (int q2 = 0; q2 < t; q2++) {
        float so = sig[q2];
        if (so > sv || (so == sv && q2 < tid)) r++;
      }
      keepf[tid] = (r < tp) ? 1 : 0;
    }
    __syncthreads();
    if (tid < t && keepf[tid]) {
      int ppos = 0;
      for (int q2 = 0; q2 < tid; q2++) ppos += keepf[q2];
      klist[ppos] = tid;
      idxbuf[((h * 8 + bb) * WHT + w) * 16 + ppos] = tid;
    }
  } else {
    if (tid < t) klist[tid] = tid;
  }
  __syncthreads();
  const int gq = tid >> 6, d = tid & 63;
  for (int qi = gq; qi < tp; qi += 4) {
    int qq = klist[qi];
    const float* arow = &a[qq * 17];
    float acc = 0;
    for (int k2 = 0; k2 < t; k2++) acc += arow[k2] * vs[k2 * 65 + d];
    Y[(size_t)((qi * WHT + w) * 8 + bb) * CC + h * 64 + d] = acc;
  }
}

// ---------------------------------------------------------------------------
// In-place temporal pooling of the residual stream X.
// ---------------------------------------------------------------------------
__global__ __launch_bounds__(256)
void pool_inplace_kernel(float* __restrict__ X, const int* __restrict__ idxbuf,
                         int tp) {
  const int b = blockIdx.x & 7;
  const int w = blockIdx.x >> 3;
  const int tid = threadIdx.x;
  const int c0 = tid, c1 = tid + 256;
  const int h0 = c0 >> 6, h1 = c1 >> 6;
  const int ib0 = ((h0 * 8 + b) * WHT + w) * 16;
  const int ib1 = ((h1 * 8 + b) * WHT + w) * 16;
  for (int q = 0; q < tp; q++) {
    int s0 = idxbuf[ib0 + q];
    int s1 = idxbuf[ib1 + q];
    size_t drow = (size_t)((1 + q * WHT + w) * 8 + b) * CC;
    if (s0 != q) {
      size_t srow = (size_t)((1 + s0 * WHT + w) * 8 + b) * CC;
      X[drow + c0] = X[srow + c0];
    }
    if (s1 != q) {
      size_t srow = (size_t)((1 + s1 * WHT + w) * 8 + b) * CC;
      X[drow + c1] = X[srow + c1];
    }
  }
}

// ---------------------------------------------------------------------------
// Spatial attention, split-bf16 MFMA flash kernel.
// Block = (h, b, tq): full 196x196x64 attention. 4 waves, 13 q-strips of 16.
// K hi/lo LDS [208][72] (16B-aligned rows, 2-way max bank alias);
// V TRANSPOSED hi/lo [64][200]; P per-wave strip [16][196] u32 (hi|lo packed).
// QK^T: 3-term split (qh*kh + ql*kh + qh*kl) -> fp32-class scores.
// Softmax fp32 in-register on MFMA C layout (row=quad*4+p, col=l16+16j);
// normalization deferred to O epilogue. PV: 3-term split over 6 k-steps of 32;
// 4-col tail (keys 192..195) via shfl-broadcast + VALU FMA.
// ---------------------------------------------------------------------------
__global__ __launch_bounds__(256)
void spatial_mfma_kernel(const float* __restrict__ qkv, float* __restrict__ outA) {
  __shared__ unsigned short Khi[208 * 72];
  __shared__ unsigned short Klo[208 * 72];
  __shared__ unsigned short Vthi[64 * 200];
  __shared__ unsigned short Vtlo[64 * 200];
  __shared__ unsigned int Ps[4][16 * 196];
  const int blk = blockIdx.x;
  const int h = blk & 7;
  const int b = (blk >> 3) & 7;
  const int tq = blk >> 6;
  const int tid = threadIdx.x;
  const int wave = tid >> 6, lane = tid & 63;
  const int quad = lane >> 4, l16 = lane & 15;
  const size_t rowbase = (size_t)(tq * WHT) * 8 + b;  // qkv row for w=0

  union BF8 { bf16x8 v; unsigned short s[8]; unsigned int u[4]; };

  // ---- stage K (hi/lo) and V (transposed hi/lo) ----
  for (int r = tid >> 4; r < WHT; r += 16) {
    int c = (tid & 15) * 4;
    const float* gk = qkv + (rowbase + (size_t)r * 8) * 1536 + 512 + h * 64 + c;
    float4 kv = *(const float4*)gk;
    ushort4 khs, kls;
    splitf(kv.x, khs.x, kls.x);
    splitf(kv.y, khs.y, kls.y);
    splitf(kv.z, khs.z, kls.z);
    splitf(kv.w, khs.w, kls.w);
    *(ushort4*)&Khi[r * 72 + c] = khs;
    *(ushort4*)&Klo[r * 72 + c] = kls;
    const float* gv = qkv + (rowbase + (size_t)r * 8) * 1536 + 1024 + h * 64 + c;
    float4 vv = *(const float4*)gv;
    unsigned short vh, vl;
    splitf(vv.x, vh, vl); Vthi[(c + 0) * 200 + r] = vh; Vtlo[(c + 0) * 200 + r] = vl;
    splitf(vv.y, vh, vl); Vthi[(c + 1) * 200 + r] = vh; Vtlo[(c + 1) * 200 + r] = vl;
    splitf(vv.z, vh, vl); Vthi[(c + 2) * 200 + r] = vh; Vtlo[(c + 2) * 200 + r] = vl;
    splitf(vv.w, vh, vl); Vthi[(c + 3) * 200 + r] = vh; Vtlo[(c + 3) * 200 + r] = vl;
  }
  __syncthreads();

  unsigned int* myP = &Ps[wave][0];

  for (int strip = wave; strip < 13; strip += 4) {
    // ---- load Q fragments for rows strip*16 + l16 (A-operand layout) ----
    int qr = strip * 16 + l16;
    int qrc = min(qr, WHT - 1);
    const float* qp = qkv + (rowbase + (size_t)qrc * 8) * 1536 + h * 64 + quad * 8;
    BF8 qh[2], ql[2];
#pragma unroll
    for (int st = 0; st < 2; st++) {
      float4 a = *(const float4*)(qp + st * 32);
      float4 c = *(const float4*)(qp + st * 32 + 4);
      float vals[8] = {a.x, a.y, a.z, a.w, c.x, c.y, c.z, c.w};
#pragma unroll
      for (int i = 0; i < 8; i++) {
        float x = vals[i] * 0.125f;
        splitf(x, qh[st].s[i], ql[st].s[i]);
      }
    }

    // ---- S = Q K^T via split MFMA (13 key tiles x 2 k-steps x 3 terms) ----
    floatx4 acc_s[13];
#pragma unroll
    for (int j = 0; j < 13; j++) {
      floatx4 acc = (floatx4){0.f, 0.f, 0.f, 0.f};
#pragma unroll
      for (int st = 0; st < 2; st++) {
        bf16x8 bh = *(const bf16x8*)&Khi[(j * 16 + l16) * 72 + st * 32 + quad * 8];
        bf16x8 bl = *(const bf16x8*)&Klo[(j * 16 + l16) * 72 + st * 32 + quad * 8];
        acc = __builtin_amdgcn_mfma_f32_16x16x32_bf16(qh[st].v, bh, acc, 0, 0, 0);
        acc = __builtin_amdgcn_mfma_f32_16x16x32_bf16(ql[st].v, bh, acc, 0, 0, 0);
        acc = __builtin_amdgcn_mfma_f32_16x16x32_bf16(qh[st].v, bl, acc, 0, 0, 0);
      }
      acc_s[j] = acc;
    }
    // mask invalid key cols 196..207 (tile 12, l16 >= 4)
    if (l16 >= 4) acc_s[12] = (floatx4){-3.4e38f, -3.4e38f, -3.4e38f, -3.4e38f};

    // ---- softmax rows (row = quad*4+p): 13-reg local + 16-lane shfl reduce ----
    float inv4[4];
#pragma unroll
    for (int p = 0; p < 4; p++) {
      float m = acc_s[0][p];
#pragma unroll
      for (int j = 1; j < 13; j++) m = fmaxf(m, acc_s[j][p]);
#pragma unroll
      for (int o = 8; o >= 1; o >>= 1) m = fmaxf(m, __shfl_xor(m, o, 64));
      float s = 0.f;
#pragma unroll
      for (int j = 0; j < 13; j++) {
        float e = __expf(acc_s[j][p] - m);
        acc_s[j][p] = e;
        s += e;
      }
#pragma unroll
      for (int o = 8; o >= 1; o >>= 1) s += __shfl_xor(s, o, 64);
      inv4[p] = 1.f / s;
    }

    // ---- write P (tiles 0..11) to per-wave strip as packed hi|lo u32 ----
#pragma unroll
    for (int j = 0; j < 12; j++) {
#pragma unroll
      for (int p = 0; p < 4; p++) {
        float e = acc_s[j][p];
        unsigned u = __float_as_uint(e);
        unsigned hs = u >> 16;
        float rem = e - __uint_as_float(hs << 16);
        unsigned ls = f2bf(rem);
        myP[(quad * 4 + p) * 196 + j * 16 + l16] = hs | (ls << 16);
      }
    }

    // ---- O = P V via split MFMA (6 k-steps x 4 d-tiles x 3 terms) ----
    floatx4 acc_o[4];
#pragma unroll
    for (int jn = 0; jn < 4; jn++) acc_o[jn] = (floatx4){0.f, 0.f, 0.f, 0.f};
#pragma unroll
    for (int s = 0; s < 6; s++) {
      const unsigned int* pp = &myP[l16 * 196 + s * 32 + quad * 8];
      uint4 u0 = *(const uint4*)pp;
      uint4 u1 = *(const uint4*)(pp + 4);
      BF8 AH, AL;
      AH.u[0] = (u0.x & 0xffffu) | (u0.y << 16);
      AH.u[1] = (u0.z & 0xffffu) | (u0.w << 16);
      AH.u[2] = (u1.x & 0xffffu) | (u1.y << 16);
      AH.u[3] = (u1.z & 0xffffu) | (u1.w << 16);
      AL.u[0] = (u0.x >> 16) | (u0.y & 0xffff0000u);
      AL.u[1] = (u0.z >> 16) | (u0.w & 0xffff0000u);
      AL.u[2] = (u1.x >> 16) | (u1.y & 0xffff0000u);
      AL.u[3] = (u1.z >> 16) | (u1.w & 0xffff0000u);
#pragma unroll
      for (int jn = 0; jn < 4; jn++) {
        bf16x8 bh = *(const bf16x8*)&Vthi[(jn * 16 + l16) * 200 + s * 32 + quad * 8];
        bf16x8 bl = *(const bf16x8*)&Vtlo[(jn * 16 + l16) * 200 + s * 32 + quad * 8];
        acc_o[jn] = __builtin_amdgcn_mfma_f32_16x16x32_bf16(AH.v, bh, acc_o[jn], 0, 0, 0);
        acc_o[jn] = __builtin_amdgcn_mfma_f32_16x16x32_bf16(AL.v, bh, acc_o[jn], 0, 0, 0);
        acc_o[jn] = __builtin_amdgcn_mfma_f32_16x16x32_bf16(AH.v, bl, acc_o[jn], 0, 0, 0);
      }
    }
    // ---- tail keys 192..195: e still in acc_s[12], broadcast within quad ----
#pragma unroll
    for (int kk = 0; kk < 4; kk++) {
      int srcl = (lane & 48) + kk;
      float e0 = __shfl(acc_s[12][0], srcl, 64);
      float e1 = __shfl(acc_s[12][1], srcl, 64);
      float e2 = __shfl(acc_s[12][2], srcl, 64);
      float e3 = __shfl(acc_s[12][3], srcl, 64);
#pragma unroll
      for (int jn = 0; jn < 4; jn++) {
        int d = jn * 16 + l16;
        float v = bf2f(Vthi[d * 200 + 192 + kk]) + bf2f(Vtlo[d * 200 + 192 + kk]);
        acc_o[jn][0] += e0 * v;
        acc_o[jn][1] += e1 * v;
        acc_o[jn][2] += e2 * v;
        acc_o[jn][3] += e3 * v;
      }
    }

    // ---- store O (normalized) ----
#pragma unroll
    for (int jn = 0; jn < 4; jn++) {
#pragma unroll
      for (int p = 0; p < 4; p++) {
        int qrow = strip * 16 + quad * 4 + p;
        if (qrow < WHT)
          outA[((size_t)(1 + tq * WHT + qrow) * 8 + b) * CC + h * 64 + jn * 16 + l16] =
              acc_o[jn][p] * inv4[p];
      }
    }
  }
}

// ---------------------------------------------------------------------------
// Final LN (token 0 only) + classifier head
// ---------------------------------------------------------------------------
__global__ __launch_bounds__(256)
void head_kernel(const float* __restrict__ X, const float* __restrict__ enw,
                 const float* __restrict__ enb, const float* __restrict__ fcw,
                 const float* __restrict__ fcb, float* __restrict__ out) {
  __shared__ float nx[512];
  __shared__ float red[8];
  const int b = blockIdx.x, tid = threadIdx.x;
  const float* x = X + (size_t)b * CC;
  float v0 = x[tid], v1 = x[tid + 256];
  float s = wave_reduce_sum(v0 + v1);
  if ((tid & 63) == 0) red[tid >> 6] = s;
  __syncthreads();
  float mean = (red[0] + red[1] + red[2] + red[3]) * (1.f / 512.f);
  float d0 = v0 - mean, d1 = v1 - mean;
  float vs = wave_reduce_sum(d0 * d0 + d1 * d1);
  if ((tid & 63) == 0) red[4 + (tid >> 6)] = vs;
  __syncthreads();
  float var = (red[4] + red[5] + red[6] + red[7]) * (1.f / 512.f);
  float inv = 1.0f / sqrtf(var + 1e-5f);
  nx[tid] = d0 * inv * enw[tid] + enb[tid];
  nx[tid + 256] = d1 * inv * enw[tid + 256] + enb[tid + 256];
  __syncthreads();
  if (tid < NCLS) {
    float acc = fcb[tid];
    for (int c = 0; c < 512; c++) acc += nx[c] * fcw[c * NCLS + tid];
    out[b * NCLS + tid] = acc;
  }
}

// ---------------------------------------------------------------------------
extern "C" void kernel_launch(void* const* d_in, const int* in_sizes, int n_in,
                              void* d_out, int out_size, void* d_ws, size_t ws_size,
                              hipStream_t stream) {
  (void)in_sizes; (void)n_in; (void)out_size; (void)ws_size;
  const float* src  = (const float*)d_in[0];
  const float* cw   = (const float*)d_in[1];
  const float* cb   = (const float*)d_in[2];
  const float* clst = (const float*)d_in[3];
  const float* pos  = (const float*)d_in[4];
  const float* Wt   = (const float*)d_in[5];
  const float* bt   = (const float*)d_in[6];
  const float* Wsp  = (const float*)d_in[7];
  const float* bsp  = (const float*)d_in[8];
  const float* Wo   = (const float*)d_in[9];
  const float* bo   = (const float*)d_in[10];
  const float* n1w  = (const float*)d_in[11];
  const float* n1b  = (const float*)d_in[12];
  const float* n2w  = (const float*)d_in[13];
  const float* n2b  = (const float*)d_in[14];
  const float* W1   = (const float*)d_in[15];
  const float* b1   = (const float*)d_in[16];
  const float* W2   = (const float*)d_in[17];
  const float* b2   = (const float*)d_in[18];
  const float* enw  = (const float*)d_in[19];
  const float* enb  = (const float*)d_in[20];
  const float* fcw  = (const float*)d_in[21];
  const float* fcb  = (const float*)d_in[22];

  float* ws = (float*)d_ws;
  const size_t TOKR = (size_t)3137 * 8;
  float* X0  = ws;                              // TOKR*512
  float* Ab  = X0 + TOKR * 512;                 // TOKR*512
  float* QKV = Ab + TOKR * 512;                 // TOKR*1536 (also FFN mid / im2col)
  float* CLS = QKV + TOKR * 1536;               // 8*512
  int*   IDX = (int*)(CLS + 8 * 512);           // 8*8*196*16 ints
  unsigned short* WT1 = (unsigned short*)(IDX + 8 * 8 * WHT * 16);  // 2048*512
  unsigned short* WT2 = WT1 + 2048 * 512;                           // 2048*512

  // Patch embed as im2col + split-bf16 MFMA GEMM (M=25088, N=512, K=768).
  wsplit_flat_kernel<<<(512 * 768 + 255) / 256, 256, 0, stream>>>(
      cw, WT1, WT2, 512 * 768);
  im2col_kernel<<<(25088 * 192) / 256, 256, 0, stream>>>(src, QKV);
  mfma_gemm3_kernel<<<dim3(25088 / 128, 4), 256, 0, stream>>>(
      QKV, WT1, WT2, cb, X0 + 8 * CC, 25088, 512, 768);
  cls_init_kernel<<<8, 512, 0, stream>>>(clst, X0);

  float* Xc = X0;
  int t = 16;
  const int FFN_CHUNK = 16384;
  for (int i = 0; i < 6; i++) {
    const int pk = (i & 1) ? 2 : 0;
    const int tp = t - pk;
    const int L = 1 + t * WHT;
    const int Lo = 1 + tp * WHT;
    const int M = L * 8, Mo = Lo * 8, My = tp * WHT * 8;

    ln_kernel<<<M, 256, 0, stream>>>(Xc, Ab, n1w + (size_t)i * 512, n1b + (size_t)i * 512,
                                     (i == 0) ? pos : nullptr);
    // sigma-critical Wt: split-bf16 MFMA (hi/lo), fp32-class accuracy
    wtrans_split_kernel<<<dim3(1536 / 32, 512 / 32), 256, 0, stream>>>(
        Wt + (size_t)i * 512 * 1536, WT1, WT2, 1536, 512);
    mfma_gemm3_kernel<<<dim3((M + 127) / 128, 12), 256, 0, stream>>>(
        Ab, WT1, WT2, bt + (size_t)i * 1536, QKV, M, 1536, 512);
    class_attn_kernel<<<64, 256, 0, stream>>>(QKV, CLS, L);
    temporal_attn_kernel<<<HH * BB * WHT, 256, 0, stream>>>(QKV, Ab, IDX, t, tp, pk);
    // Ws: plain bf16 MFMA
    wtrans_kernel<<<dim3(1536 / 32, 512 / 32), 256, 0, stream>>>(
        Wsp + (size_t)i * 512 * 1536, WT1, 1536, 512);
    mfma_gemm_kernel<0, 0><<<dim3((My + 127) / 128, 12), 256, 0, stream>>>(
        Ab, WT1, bsp + (size_t)i * 1536, QKV, My, 1536, 512, nullptr);
    copy_cls_kernel<<<8, 512, 0, stream>>>(CLS, Ab);
    spatial_mfma_kernel<<<64 * tp, 256, 0, stream>>>(QKV, Ab);
    if (pk > 0)
      pool_inplace_kernel<<<8 * WHT, 256, 0, stream>>>(Xc, IDX, tp);
    // Wo: plain bf16 MFMA + residual
    wtrans_kernel<<<dim3(512 / 32, 512 / 32), 256, 0, stream>>>(
        Wo + (size_t)i * 512 * 512, WT1, 512, 512);
    mfma_gemm_kernel<0, 1><<<dim3((Mo + 127) / 128, 4), 256, 0, stream>>>(
        Ab, WT1, bo + (size_t)i * 512, Xc, Mo, 512, 512, Xc);
    ln_kernel<<<Mo, 256, 0, stream>>>(Xc, Ab, n2w + (size_t)i * 512, n2b + (size_t)i * 512,
                                      nullptr);
    // FFN: plain bf16 MFMA
    wtrans_kernel<<<dim3(2048 / 32, 512 / 32), 256, 0, stream>>>(
        W1 + (size_t)i * 512 * 2048, WT1, 2048, 512);
    wtrans_kernel<<<dim3(512 / 32, 2048 / 32), 256, 0, stream>>>(
        W2 + (size_t)i * 2048 * 512, WT2, 512, 2048);
    for (int off = 0; off < Mo; off += FFN_CHUNK) {
      int R = Mo - off;
      if (R > FFN_CHUNK) R = FFN_CHUNK;
      mfma_gemm_kernel<1, 0><<<dim3((R + 127) / 128, 16), 256, 0, stream>>>(
          Ab + (size_t)off * 512, WT1, b1 + (size_t)i * 2048, QKV, R, 2048, 512,
          nullptr);
      mfma_gemm_kernel<0, 1><<<dim3((R + 127) / 128, 4), 256, 0, stream>>>(
          QKV, WT2, b2 + (size_t)i * 512, Xc + (size_t)off * 512, R, 512, 2048,
          Xc + (size_t)off * 512);
    }
    t = tp;
  }
  head_kernel<<<8, 256, 0, stream>>>(Xc, enw, enb, fcw, fcb, (float*)d_out);
}

// Round 3
// 6096.930 us; speedup vs baseline: 1.6261x; 1.1603x over previous
//
#include <hip/hip_runtime.h>
#include <math.h>

// ---------------------------------------------------------------------------
// CompactVidTr forward.
//  - Patch-embed conv: im2col + split-bf16 MFMA GEMM (M=25088,N=512,K=768).
//  - Wt (QKV) GEMM: split-bf16 MFMA (hi/lo, 3 terms) -> fp32-class accuracy
//    for the sigma-top-k ranking path.
//  - Spatial attention: split-bf16 MFMA flash kernel.
//  - Class attention: two-phase flash split over L (grid 64x32 -> 64) — the
//    monolithic 64-block version was latency-bound at 2.8% occupancy (221 us).
//  - Ws/Wo/FFN GEMMs: plain bf16 MFMA (incremental-error paths).
//  - Temporal attention + LN: fp32 vector.
// Layout: token matrices row-major [row = l*B + b][C]; l=0 is cls. B=8, C=512.
//
// Workspace (262.5 MB < 268.4 MB):
//   X   : 3137*8 x 512  fp32   (51.4 MB)  residual stream, pooled IN PLACE
//   Ab  : 3137*8 x 512  fp32   (51.4 MB)  LN out / attention out staging
//   QKV : 3137*8 x 1536 fp32  (154.1 MB)  qkv GEMM out; FFN mid; im2col stage
//   CLS : 8x512 fp32, IDX: 8*8*196*16 int (~0.8 MB)
//   WT1 : 2048*512 bf16 (2.1 MB)  weight scratch
//   WT2 : 2048*512 bf16 (2.1 MB)  weight scratch
//   PART: 64*32*68 fp32 (0.56 MB) class-attn partials
// ---------------------------------------------------------------------------

#define BB 8
#define CC 512
#define HH 8
#define HD 64
#define WHT 196
#define NCLS 157
#define CA_NCH 32

typedef short bf16x8 __attribute__((ext_vector_type(8)));
typedef float floatx4 __attribute__((ext_vector_type(4)));

__device__ __forceinline__ unsigned short f2bf(float f) {
  unsigned u = __float_as_uint(f);
  unsigned r = u + 0x7FFFu + ((u >> 16) & 1u);  // RNE
  return (unsigned short)(r >> 16);
}
__device__ __forceinline__ float bf2f(unsigned short h) {
  return __uint_as_float((unsigned)h << 16);
}
// truncation split: hi = top-16-bits, lo = RNE(residual); reconstruct ~2^-17
__device__ __forceinline__ void splitf(float x, unsigned short& h, unsigned short& l) {
  unsigned u = __float_as_uint(x);
  unsigned hs = u >> 16;
  float rem = x - __uint_as_float(hs << 16);
  h = (unsigned short)hs;
  l = f2bf(rem);
}

__device__ __forceinline__ float wave_reduce_sum(float v) {
#pragma unroll
  for (int o = 32; o > 0; o >>= 1) v += __shfl_down(v, o, 64);
  return v;
}
__device__ __forceinline__ float wave_reduce_max(float v) {
#pragma unroll
  for (int o = 32; o > 0; o >>= 1) v = fmaxf(v, __shfl_down(v, o, 64));
  return v;
}

// ---------------------------------------------------------------------------
// im2col: src [B=8][3][16][224][224] -> IM [25088][768] fp32 (pure permute).
// ---------------------------------------------------------------------------
__global__ __launch_bounds__(256)
void im2col_kernel(const float* __restrict__ src, float* __restrict__ IM) {
  int gid = blockIdx.x * 256 + threadIdx.x;
  int k4 = gid % 192;
  int u = gid / 192;
  if (u >= 25088) return;
  int b = u & 7;
  int s = u >> 3;
  int tt = s / WHT;
  int w2 = s % WHT;
  int ph = w2 / 14, pw = w2 % 14;
  int k = k4 * 4;
  int ci = k >> 8;
  int rem = k & 255;
  int py = rem >> 4, px = rem & 15;
  const float* sp = src + (size_t)b * (3 * 16 * 224 * 224) +
                    (size_t)ci * (16 * 224 * 224) + (size_t)tt * (224 * 224) +
                    (size_t)(ph * 16 + py) * 224 + pw * 16 + px;
  *(float4*)(IM + (size_t)u * 768 + k) = *(const float4*)sp;
}

__global__ __launch_bounds__(256)
void wsplit_flat_kernel(const float* __restrict__ W,
                        unsigned short* __restrict__ Whi,
                        unsigned short* __restrict__ Wlo, int total) {
  int i = blockIdx.x * 256 + threadIdx.x;
  if (i >= total) return;
  float w = W[i];
  unsigned short hi = f2bf(w);
  Whi[i] = hi;
  Wlo[i] = f2bf(w - bf2f(hi));
}

__global__ void cls_init_kernel(const float* __restrict__ clst, float* __restrict__ X) {
  X[(size_t)blockIdx.x * CC + threadIdx.x] = clst[threadIdx.x];
}

__global__ void copy_cls_kernel(const float* __restrict__ cls, float* __restrict__ A) {
  A[(size_t)blockIdx.x * CC + threadIdx.x] = cls[(size_t)blockIdx.x * CC + threadIdx.x];
}

// ---------------------------------------------------------------------------
// LayerNorm over C=512; one block per row; optional +pos (layer0 q-input)
// ---------------------------------------------------------------------------
__global__ __launch_bounds__(256)
void ln_kernel(const float* __restrict__ X, float* __restrict__ O,
               const float* __restrict__ w, const float* __restrict__ b,
               const float* __restrict__ pos) {
  __shared__ float red[8];
  const int row = blockIdx.x, tid = threadIdx.x;
  const float* x = X + (size_t)row * CC;
  float v0 = x[tid], v1 = x[tid + 256];
  float s = wave_reduce_sum(v0 + v1);
  if ((tid & 63) == 0) red[tid >> 6] = s;
  __syncthreads();
  float mean = (red[0] + red[1] + red[2] + red[3]) * (1.f / 512.f);
  float d0 = v0 - mean, d1 = v1 - mean;
  float vs = wave_reduce_sum(d0 * d0 + d1 * d1);
  if ((tid & 63) == 0) red[4 + (tid >> 6)] = vs;
  __syncthreads();
  float var = (red[4] + red[5] + red[6] + red[7]) * (1.f / 512.f);
  float inv = 1.0f / sqrtf(var + 1e-5f);
  float o0 = d0 * inv * w[tid] + b[tid];
  float o1 = d1 * inv * w[tid + 256] + b[tid + 256];
  if (pos) {
    const float* pr = pos + (size_t)(row >> 3) * CC;
    o0 += pr[tid];
    o1 += pr[tid + 256];
  }
  O[(size_t)row * CC + tid] = o0;
  O[(size_t)row * CC + tid + 256] = o1;
}

// ---------------------------------------------------------------------------
// Weight transpose + fp32->bf16 (plain): W [K][N] -> WT [N][K]
// ---------------------------------------------------------------------------
__global__ __launch_bounds__(256)
void wtrans_kernel(const float* __restrict__ W, unsigned short* __restrict__ WT,
                   int N, int K) {
  __shared__ float tile[32][33];
  const int tid = threadIdx.x;
  const int tx = tid & 31, ty = tid >> 5;
  const int n0 = blockIdx.x * 32, k0 = blockIdx.y * 32;
#pragma unroll
  for (int r = 0; r < 4; r++) {
    int kk = ty + r * 8;
    tile[kk][tx] = W[(size_t)(k0 + kk) * N + n0 + tx];
  }
  __syncthreads();
#pragma unroll
  for (int r = 0; r < 4; r++) {
    int nn = ty + r * 8;
    WT[(size_t)(n0 + nn) * K + k0 + tx] = f2bf(tile[tx][nn]);
  }
}

// ---------------------------------------------------------------------------
// Weight transpose + split fp32 -> (hi, lo) bf16: W [K][N] -> WThi/WTlo [N][K]
// ---------------------------------------------------------------------------
__global__ __launch_bounds__(256)
void wtrans_split_kernel(const float* __restrict__ W,
                         unsigned short* __restrict__ WThi,
                         unsigned short* __restrict__ WTlo, int N, int K) {
  __shared__ float tile[32][33];
  const int tid = threadIdx.x;
  const int tx = tid & 31, ty = tid >> 5;
  const int n0 = blockIdx.x * 32, k0 = blockIdx.y * 32;
#pragma unroll
  for (int r = 0; r < 4; r++) {
    int kk = ty + r * 8;
    tile[kk][tx] = W[(size_t)(k0 + kk) * N + n0 + tx];
  }
  __syncthreads();
#pragma unroll
  for (int r = 0; r < 4; r++) {
    int nn = ty + r * 8;
    float w = tile[tx][nn];
    unsigned short hi = f2bf(w);
    unsigned short lo = f2bf(w - bf2f(hi));
    WThi[(size_t)(n0 + nn) * K + k0 + tx] = hi;
    WTlo[(size_t)(n0 + nn) * K + k0 + tx] = lo;
  }
}

// ---------------------------------------------------------------------------
// Plain bf16 MFMA GEMM: C = A(M,K) @ W(K,N) + bias [+relu] [+residual]
// ---------------------------------------------------------------------------
template <int RELU, int RES>
__global__ __launch_bounds__(256)
void mfma_gemm_kernel(const float* __restrict__ A,
                      const unsigned short* __restrict__ WT,
                      const float* __restrict__ bias, float* __restrict__ Cout,
                      int M, int N, int K, const float* __restrict__ resid) {
  __shared__ unsigned short AsU[128 * 40];
  __shared__ unsigned short BsU[128 * 40];
  const int tid = threadIdx.x;
  const int wave = tid >> 6, lane = tid & 63;
  const int quad = lane >> 4, l16 = lane & 15;
  const int wrow = (wave >> 1) * 64, wcol = (wave & 1) * 64;
  const int m0 = blockIdx.x * 128, n0 = blockIdx.y * 128;

  floatx4 acc[4][4];
#pragma unroll
  for (int i = 0; i < 4; i++)
#pragma unroll
    for (int j = 0; j < 4; j++) acc[i][j] = (floatx4){0.f, 0.f, 0.f, 0.f};

  for (int k0 = 0; k0 < K; k0 += 32) {
#pragma unroll
    for (int r = 0; r < 4; r++) {
      int e = (tid + r * 256) * 4;
      int row = e >> 5, col = e & 31;
      int gm = m0 + row;
      float4 v = make_float4(0.f, 0.f, 0.f, 0.f);
      if (gm < M) v = *(const float4*)(A + (size_t)gm * K + k0 + col);
      ushort4 o;
      o.x = f2bf(v.x); o.y = f2bf(v.y); o.z = f2bf(v.z); o.w = f2bf(v.w);
      *(ushort4*)&AsU[row * 40 + col] = o;
    }
#pragma unroll
    for (int r = 0; r < 4; r++) {
      int e = (tid + r * 256) * 4;
      int n = e >> 5, k = e & 31;
      ushort4 w = *(const ushort4*)(WT + (size_t)(n0 + n) * K + k0 + k);
      *(ushort4*)&BsU[n * 40 + k] = w;
    }
    __syncthreads();
    bf16x8 af[4], bf[4];
#pragma unroll
    for (int i = 0; i < 4; i++)
      af[i] = *(const bf16x8*)&AsU[(wrow + i * 16 + l16) * 40 + quad * 8];
#pragma unroll
    for (int j = 0; j < 4; j++)
      bf[j] = *(const bf16x8*)&BsU[(wcol + j * 16 + l16) * 40 + quad * 8];
#pragma unroll
    for (int i = 0; i < 4; i++)
#pragma unroll
      for (int j = 0; j < 4; j++)
        acc[i][j] = __builtin_amdgcn_mfma_f32_16x16x32_bf16(af[i], bf[j],
                                                            acc[i][j], 0, 0, 0);
    __syncthreads();
  }
#pragma unroll
  for (int i = 0; i < 4; i++) {
#pragma unroll
    for (int p = 0; p < 4; p++) {
      int gm = m0 + wrow + i * 16 + quad * 4 + p;
      if (gm >= M) continue;
#pragma unroll
      for (int j = 0; j < 4; j++) {
        int gn = n0 + wcol + j * 16 + l16;
        float v = acc[i][j][p] + bias[gn];
        if (RELU) v = fmaxf(v, 0.f);
        if (RES == 1) v += resid[(size_t)gm * N + gn];
        Cout[(size_t)gm * N + gn] = v;
      }
    }
  }
}

// ---------------------------------------------------------------------------
// Split-bf16 MFMA GEMM (sigma-safe, ~1e-5 relative error)
// ---------------------------------------------------------------------------
__global__ __launch_bounds__(256)
void mfma_gemm3_kernel(const float* __restrict__ A,
                       const unsigned short* __restrict__ WThi,
                       const unsigned short* __restrict__ WTlo,
                       const float* __restrict__ bias, float* __restrict__ Cout,
                       int M, int N, int K) {
  __shared__ unsigned short AsHi[128 * 40];
  __shared__ unsigned short AsLo[128 * 40];
  __shared__ unsigned short BsHi[128 * 40];
  __shared__ unsigned short BsLo[128 * 40];
  const int tid = threadIdx.x;
  const int wave = tid >> 6, lane = tid & 63;
  const int quad = lane >> 4, l16 = lane & 15;
  const int wrow = (wave >> 1) * 64, wcol = (wave & 1) * 64;
  const int m0 = blockIdx.x * 128, n0 = blockIdx.y * 128;

  floatx4 acc[4][4];
#pragma unroll
  for (int i = 0; i < 4; i++)
#pragma unroll
    for (int j = 0; j < 4; j++) acc[i][j] = (floatx4){0.f, 0.f, 0.f, 0.f};

  for (int k0 = 0; k0 < K; k0 += 32) {
#pragma unroll
    for (int r = 0; r < 4; r++) {
      int e = (tid + r * 256) * 4;
      int row = e >> 5, col = e & 31;
      int gm = m0 + row;
      float4 v = make_float4(0.f, 0.f, 0.f, 0.f);
      if (gm < M) v = *(const float4*)(A + (size_t)gm * K + k0 + col);
      ushort4 hi, lo;
      hi.x = f2bf(v.x); lo.x = f2bf(v.x - bf2f(hi.x));
      hi.y = f2bf(v.y); lo.y = f2bf(v.y - bf2f(hi.y));
      hi.z = f2bf(v.z); lo.z = f2bf(v.z - bf2f(hi.z));
      hi.w = f2bf(v.w); lo.w = f2bf(v.w - bf2f(hi.w));
      *(ushort4*)&AsHi[row * 40 + col] = hi;
      *(ushort4*)&AsLo[row * 40 + col] = lo;
    }
#pragma unroll
    for (int r = 0; r < 4; r++) {
      int e = (tid + r * 256) * 4;
      int n = e >> 5, k = e & 31;
      *(ushort4*)&BsHi[n * 40 + k] =
          *(const ushort4*)(WThi + (size_t)(n0 + n) * K + k0 + k);
      *(ushort4*)&BsLo[n * 40 + k] =
          *(const ushort4*)(WTlo + (size_t)(n0 + n) * K + k0 + k);
    }
    __syncthreads();
    bf16x8 ah[4], al[4], bh[4], bl[4];
#pragma unroll
    for (int i = 0; i < 4; i++) {
      ah[i] = *(const bf16x8*)&AsHi[(wrow + i * 16 + l16) * 40 + quad * 8];
      al[i] = *(const bf16x8*)&AsLo[(wrow + i * 16 + l16) * 40 + quad * 8];
    }
#pragma unroll
    for (int j = 0; j < 4; j++) {
      bh[j] = *(const bf16x8*)&BsHi[(wcol + j * 16 + l16) * 40 + quad * 8];
      bl[j] = *(const bf16x8*)&BsLo[(wcol + j * 16 + l16) * 40 + quad * 8];
    }
#pragma unroll
    for (int i = 0; i < 4; i++)
#pragma unroll
      for (int j = 0; j < 4; j++) {
        acc[i][j] = __builtin_amdgcn_mfma_f32_16x16x32_bf16(ah[i], bh[j],
                                                            acc[i][j], 0, 0, 0);
        acc[i][j] = __builtin_amdgcn_mfma_f32_16x16x32_bf16(ah[i], bl[j],
                                                            acc[i][j], 0, 0, 0);
        acc[i][j] = __builtin_amdgcn_mfma_f32_16x16x32_bf16(al[i], bh[j],
                                                            acc[i][j], 0, 0, 0);
      }
    __syncthreads();
  }
#pragma unroll
  for (int i = 0; i < 4; i++) {
#pragma unroll
    for (int p = 0; p < 4; p++) {
      int gm = m0 + wrow + i * 16 + quad * 4 + p;
      if (gm >= M) continue;
#pragma unroll
      for (int j = 0; j < 4; j++) {
        int gn = n0 + wcol + j * 16 + l16;
        Cout[(size_t)gm * N + gn] = acc[i][j][p] + bias[gn];
      }
    }
  }
}

// ---------------------------------------------------------------------------
// Class attention, phase 1: per-(h,b) x per-chunk partial flash softmax.
// part record [68]: [0]=local max, [1]=local expsum, [2..65]=pv[64].
// ---------------------------------------------------------------------------
__global__ __launch_bounds__(256)
void class_attn_part_kernel(const float* __restrict__ qkv,
                            float* __restrict__ part, int L) {
  __shared__ float q[64];
  __shared__ float sc[128];
  __shared__ float red[8];
  __shared__ float pv[256];
  const int h = blockIdx.x & 7, b = blockIdx.x >> 3;
  const int chunk = blockIdx.y;
  const int tid = threadIdx.x;
  const int per = (L + CA_NCH - 1) / CA_NCH;
  const int l0 = chunk * per;
  const int nl = min(L - l0, per);
  if (tid < 64) q[tid] = qkv[(size_t)b * 1536 + h * 64 + tid] * 0.125f;
  __syncthreads();
  float lmax = -3.4e38f;
  for (int i = tid; i < nl; i += 256) {
    const float* kr = qkv + (size_t)((l0 + i) * 8 + b) * 1536 + 512 + h * 64;
    float s = 0;
#pragma unroll
    for (int d2 = 0; d2 < 64; d2 += 4) {
      float4 k4 = *(const float4*)(kr + d2);
      s += q[d2] * k4.x + q[d2 + 1] * k4.y + q[d2 + 2] * k4.z + q[d2 + 3] * k4.w;
    }
    sc[i] = s;
    lmax = fmaxf(lmax, s);
  }
  lmax = wave_reduce_max(lmax);
  if ((tid & 63) == 0) red[tid >> 6] = lmax;
  __syncthreads();
  float gmax = fmaxf(fmaxf(red[0], red[1]), fmaxf(red[2], red[3]));
  float lsum = 0;
  for (int i = tid; i < nl; i += 256) {
    float e = expf(sc[i] - gmax);
    sc[i] = e;
    lsum += e;
  }
  lsum = wave_reduce_sum(lsum);
  if ((tid & 63) == 0) red[4 + (tid >> 6)] = lsum;
  __syncthreads();
  float gsum = red[4] + red[5] + red[6] + red[7];
  const int g = tid >> 6, d = tid & 63;
  float acc = 0;
  for (int i = g; i < nl; i += 4)
    acc += sc[i] * qkv[(size_t)((l0 + i) * 8 + b) * 1536 + 1024 + h * 64 + d];
  pv[g * 64 + d] = acc;
  __syncthreads();
  float* rec = part + ((size_t)blockIdx.x * CA_NCH + chunk) * 68;
  if (tid == 0) {
    rec[0] = gmax;
    rec[1] = gsum;
  }
  if (g == 0) rec[2 + d] = pv[d] + pv[64 + d] + pv[128 + d] + pv[192 + d];
}

// ---------------------------------------------------------------------------
// Class attention, phase 2: combine CA_NCH partials per (h,b).
// ---------------------------------------------------------------------------
__global__ __launch_bounds__(64)
void class_attn_reduce_kernel(const float* __restrict__ part,
                              float* __restrict__ cls) {
  const int hb = blockIdx.x;  // (b<<3)|h
  const int tid = threadIdx.x;
  const float* prec = part + (size_t)hb * CA_NCH * 68;
  float M = -3.4e38f;
#pragma unroll
  for (int c = 0; c < CA_NCH; c++) M = fmaxf(M, prec[c * 68]);
  float total = 0.f, acc = 0.f;
#pragma unroll
  for (int c = 0; c < CA_NCH; c++) {
    float w = expf(prec[c * 68] - M);
    total += prec[c * 68 + 1] * w;
    acc += prec[c * 68 + 2 + tid] * w;
  }
  int h = hb & 7, b = hb >> 3;
  cls[b * CC + h * 64 + tid] = acc / total;
}

// ---------------------------------------------------------------------------
// Temporal attention + sigma top-k pooling (fp32 — rank-critical).
// ---------------------------------------------------------------------------
__global__ __launch_bounds__(256)
void temporal_attn_kernel(const float* __restrict__ qkv, float* __restrict__ Y,
                          int* __restrict__ idxbuf, int t, int tp, int pk) {
  __shared__ float qs[16 * 65], ks[16 * 65], vs[16 * 65];
  __shared__ float a[16 * 17];
  __shared__ float sig[16];
  __shared__ int keepf[16];
  __shared__ int klist[16];
  const int g = blockIdx.x;
  const int w = g % WHT;
  const int bb = (g / WHT) & 7;
  const int h = g / (WHT * 8);
  const int tid = threadIdx.x;
  const int td = t * 64;
  for (int e = tid; e < td; e += 256) {
    int tt = e >> 6, d = e & 63;
    size_t rb = (size_t)((1 + tt * WHT + w) * 8 + bb) * 1536 + h * 64 + d;
    qs[tt * 65 + d] = qkv[rb] * 0.125f;
    ks[tt * 65 + d] = qkv[rb + 512];
    vs[tt * 65 + d] = qkv[rb + 1024];
  }
  __syncthreads();
  if (tid < t * t) {
    int qi = tid / t, ki = tid % t;
    const float* qp = &qs[qi * 65];
    const float* kp = &ks[ki * 65];
    float s = 0;
#pragma unroll 8
    for (int d2 = 0; d2 < 64; d2++) s += qp[d2] * kp[d2];
    a[qi * 17 + ki] = s;
  }
  __syncthreads();
  if (tid < t) {
    float* row = &a[tid * 17];
    float m = row[0];
    for (int k2 = 1; k2 < t; k2++) m = fmaxf(m, row[k2]);
    float sum = 0;
    for (int k2 = 0; k2 < t; k2++) {
      float e2 = expf(row[k2] - m);
      row[k2] = e2;
      sum += e2;
    }
    float inv = 1.f / sum;
    for (int k2 = 0; k2 < t; k2++) row[k2] *= inv;
  }
  __syncthreads();
  if (pk > 0) {
    if (tid < t) {
      const float* row = &a[tid * 17];
      float mean = 0;
      for (int k2 = 0; k2 < t; k2++) mean += row[k2];
      mean /= (float)t;
      float var = 0;
      for (int k2 = 0; k2 < t; k2++) {
        float dl = row[k2] - mean;
        var += dl * dl;
      }
      var /= (float)(t - 1);
      sig[tid] = sqrtf(var);
    }
    __syncthreads();
    if (tid < t) {
      float sv = sig[tid];
      int r = 0;
      for (int q2 = 0; q2 < t; q2++) {
        float so = sig[q2];
        if (so > sv || (so == sv && q2 < tid)) r++;
      }
      keepf[tid] = (r < tp) ? 1 : 0;
    }
    __syncthreads();
    if (tid < t && keepf[tid]) {
      int ppos = 0;
      for (int q2 = 0; q2 < tid; q2++) ppos += keepf[q2];
      klist[ppos] = tid;
      idxbuf[((h * 8 + bb) * WHT + w) * 16 + ppos] = tid;
    }
  } else {
    if (tid < t) klist[tid] = tid;
  }
  __syncthreads();
  const int gq = tid >> 6, d = tid & 63;
  for (int qi = gq; qi < tp; qi += 4) {
    int qq = klist[qi];
    const float* arow = &a[qq * 17];
    float acc = 0;
    for (int k2 = 0; k2 < t; k2++) acc += arow[k2] * vs[k2 * 65 + d];
    Y[(size_t)((qi * WHT + w) * 8 + bb) * CC + h * 64 + d] = acc;
  }
}

// ---------------------------------------------------------------------------
// In-place temporal pooling of the residual stream X.
// ---------------------------------------------------------------------------
__global__ __launch_bounds__(256)
void pool_inplace_kernel(float* __restrict__ X, const int* __restrict__ idxbuf,
                         int tp) {
  const int b = blockIdx.x & 7;
  const int w = blockIdx.x >> 3;
  const int tid = threadIdx.x;
  const int c0 = tid, c1 = tid + 256;
  const int h0 = c0 >> 6, h1 = c1 >> 6;
  const int ib0 = ((h0 * 8 + b) * WHT + w) * 16;
  const int ib1 = ((h1 * 8 + b) * WHT + w) * 16;
  for (int q = 0; q < tp; q++) {
    int s0 = idxbuf[ib0 + q];
    int s1 = idxbuf[ib1 + q];
    size_t drow = (size_t)((1 + q * WHT + w) * 8 + b) * CC;
    if (s0 != q) {
      size_t srow = (size_t)((1 + s0 * WHT + w) * 8 + b) * CC;
      X[drow + c0] = X[srow + c0];
    }
    if (s1 != q) {
      size_t srow = (size_t)((1 + s1 * WHT + w) * 8 + b) * CC;
      X[drow + c1] = X[srow + c1];
    }
  }
}

// ---------------------------------------------------------------------------
// Spatial attention, split-bf16 MFMA flash kernel.
// Block = (h, b, tq): full 196x196x64 attention. 4 waves, 13 q-strips of 16.
// ---------------------------------------------------------------------------
__global__ __launch_bounds__(256)
void spatial_mfma_kernel(const float* __restrict__ qkv, float* __restrict__ outA) {
  __shared__ unsigned short Khi[208 * 72];
  __shared__ unsigned short Klo[208 * 72];
  __shared__ unsigned short Vthi[64 * 200];
  __shared__ unsigned short Vtlo[64 * 200];
  __shared__ unsigned int Ps[4][16 * 196];
  const int blk = blockIdx.x;
  const int h = blk & 7;
  const int b = (blk >> 3) & 7;
  const int tq = blk >> 6;
  const int tid = threadIdx.x;
  const int wave = tid >> 6, lane = tid & 63;
  const int quad = lane >> 4, l16 = lane & 15;
  const size_t rowbase = (size_t)(tq * WHT) * 8 + b;  // qkv row for w=0

  union BF8 { bf16x8 v; unsigned short s[8]; unsigned int u[4]; };

  // ---- stage K (hi/lo) and V (transposed hi/lo) ----
  for (int r = tid >> 4; r < WHT; r += 16) {
    int c = (tid & 15) * 4;
    const float* gk = qkv + (rowbase + (size_t)r * 8) * 1536 + 512 + h * 64 + c;
    float4 kv = *(const float4*)gk;
    ushort4 khs, kls;
    splitf(kv.x, khs.x, kls.x);
    splitf(kv.y, khs.y, kls.y);
    splitf(kv.z, khs.z, kls.z);
    splitf(kv.w, khs.w, kls.w);
    *(ushort4*)&Khi[r * 72 + c] = khs;
    *(ushort4*)&Klo[r * 72 + c] = kls;
    const float* gv = qkv + (rowbase + (size_t)r * 8) * 1536 + 1024 + h * 64 + c;
    float4 vv = *(const float4*)gv;
    unsigned short vh, vl;
    splitf(vv.x, vh, vl); Vthi[(c + 0) * 200 + r] = vh; Vtlo[(c + 0) * 200 + r] = vl;
    splitf(vv.y, vh, vl); Vthi[(c + 1) * 200 + r] = vh; Vtlo[(c + 1) * 200 + r] = vl;
    splitf(vv.z, vh, vl); Vthi[(c + 2) * 200 + r] = vh; Vtlo[(c + 2) * 200 + r] = vl;
    splitf(vv.w, vh, vl); Vthi[(c + 3) * 200 + r] = vh; Vtlo[(c + 3) * 200 + r] = vl;
  }
  __syncthreads();

  unsigned int* myP = &Ps[wave][0];

  for (int strip = wave; strip < 13; strip += 4) {
    // ---- load Q fragments for rows strip*16 + l16 (A-operand layout) ----
    int qr = strip * 16 + l16;
    int qrc = min(qr, WHT - 1);
    const float* qp = qkv + (rowbase + (size_t)qrc * 8) * 1536 + h * 64 + quad * 8;
    BF8 qh[2], ql[2];
#pragma unroll
    for (int st = 0; st < 2; st++) {
      float4 a = *(const float4*)(qp + st * 32);
      float4 c = *(const float4*)(qp + st * 32 + 4);
      float vals[8] = {a.x, a.y, a.z, a.w, c.x, c.y, c.z, c.w};
#pragma unroll
      for (int i = 0; i < 8; i++) {
        float x = vals[i] * 0.125f;
        splitf(x, qh[st].s[i], ql[st].s[i]);
      }
    }

    // ---- S = Q K^T via split MFMA (13 key tiles x 2 k-steps x 3 terms) ----
    floatx4 acc_s[13];
#pragma unroll
    for (int j = 0; j < 13; j++) {
      floatx4 acc = (floatx4){0.f, 0.f, 0.f, 0.f};
#pragma unroll
      for (int st = 0; st < 2; st++) {
        bf16x8 bh = *(const bf16x8*)&Khi[(j * 16 + l16) * 72 + st * 32 + quad * 8];
        bf16x8 bl = *(const bf16x8*)&Klo[(j * 16 + l16) * 72 + st * 32 + quad * 8];
        acc = __builtin_amdgcn_mfma_f32_16x16x32_bf16(qh[st].v, bh, acc, 0, 0, 0);
        acc = __builtin_amdgcn_mfma_f32_16x16x32_bf16(ql[st].v, bh, acc, 0, 0, 0);
        acc = __builtin_amdgcn_mfma_f32_16x16x32_bf16(qh[st].v, bl, acc, 0, 0, 0);
      }
      acc_s[j] = acc;
    }
    // mask invalid key cols 196..207 (tile 12, l16 >= 4)
    if (l16 >= 4) acc_s[12] = (floatx4){-3.4e38f, -3.4e38f, -3.4e38f, -3.4e38f};

    // ---- softmax rows (row = quad*4+p): 13-reg local + 16-lane shfl reduce ----
    float inv4[4];
#pragma unroll
    for (int p = 0; p < 4; p++) {
      float m = acc_s[0][p];
#pragma unroll
      for (int j = 1; j < 13; j++) m = fmaxf(m, acc_s[j][p]);
#pragma unroll
      for (int o = 8; o >= 1; o >>= 1) m = fmaxf(m, __shfl_xor(m, o, 64));
      float s = 0.f;
#pragma unroll
      for (int j = 0; j < 13; j++) {
        float e = __expf(acc_s[j][p] - m);
        acc_s[j][p] = e;
        s += e;
      }
#pragma unroll
      for (int o = 8; o >= 1; o >>= 1) s += __shfl_xor(s, o, 64);
      inv4[p] = 1.f / s;
    }

    // ---- write P (tiles 0..11) to per-wave strip as packed hi|lo u32 ----
#pragma unroll
    for (int j = 0; j < 12; j++) {
#pragma unroll
      for (int p = 0; p < 4; p++) {
        float e = acc_s[j][p];
        unsigned u = __float_as_uint(e);
        unsigned hs = u >> 16;
        float rem = e - __uint_as_float(hs << 16);
        unsigned ls = f2bf(rem);
        myP[(quad * 4 + p) * 196 + j * 16 + l16] = hs | (ls << 16);
      }
    }

    // ---- O = P V via split MFMA (6 k-steps x 4 d-tiles x 3 terms) ----
    floatx4 acc_o[4];
#pragma unroll
    for (int jn = 0; jn < 4; jn++) acc_o[jn] = (floatx4){0.f, 0.f, 0.f, 0.f};
#pragma unroll
    for (int s = 0; s < 6; s++) {
      const unsigned int* pp = &myP[l16 * 196 + s * 32 + quad * 8];
      uint4 u0 = *(const uint4*)pp;
      uint4 u1 = *(const uint4*)(pp + 4);
      BF8 AH, AL;
      AH.u[0] = (u0.x & 0xffffu) | (u0.y << 16);
      AH.u[1] = (u0.z & 0xffffu) | (u0.w << 16);
      AH.u[2] = (u1.x & 0xffffu) | (u1.y << 16);
      AH.u[3] = (u1.z & 0xffffu) | (u1.w << 16);
      AL.u[0] = (u0.x >> 16) | (u0.y & 0xffff0000u);
      AL.u[1] = (u0.z >> 16) | (u0.w & 0xffff0000u);
      AL.u[2] = (u1.x >> 16) | (u1.y & 0xffff0000u);
      AL.u[3] = (u1.z >> 16) | (u1.w & 0xffff0000u);
#pragma unroll
      for (int jn = 0; jn < 4; jn++) {
        bf16x8 bh = *(const bf16x8*)&Vthi[(jn * 16 + l16) * 200 + s * 32 + quad * 8];
        bf16x8 bl = *(const bf16x8*)&Vtlo[(jn * 16 + l16) * 200 + s * 32 + quad * 8];
        acc_o[jn] = __builtin_amdgcn_mfma_f32_16x16x32_bf16(AH.v, bh, acc_o[jn], 0, 0, 0);
        acc_o[jn] = __builtin_amdgcn_mfma_f32_16x16x32_bf16(AL.v, bh, acc_o[jn], 0, 0, 0);
        acc_o[jn] = __builtin_amdgcn_mfma_f32_16x16x32_bf16(AH.v, bl, acc_o[jn], 0, 0, 0);
      }
    }
    // ---- tail keys 192..195: e still in acc_s[12], broadcast within quad ----
#pragma unroll
    for (int kk = 0; kk < 4; kk++) {
      int srcl = (lane & 48) + kk;
      float e0 = __shfl(acc_s[12][0], srcl, 64);
      float e1 = __shfl(acc_s[12][1], srcl, 64);
      float e2 = __shfl(acc_s[12][2], srcl, 64);
      float e3 = __shfl(acc_s[12][3], srcl, 64);
#pragma unroll
      for (int jn = 0; jn < 4; jn++) {
        int d = jn * 16 + l16;
        float v = bf2f(Vthi[d * 200 + 192 + kk]) + bf2f(Vtlo[d * 200 + 192 + kk]);
        acc_o[jn][0] += e0 * v;
        acc_o[jn][1] += e1 * v;
        acc_o[jn][2] += e2 * v;
        acc_o[jn][3] += e3 * v;
      }
    }

    // ---- store O (normalized) ----
#pragma unroll
    for (int jn = 0; jn < 4; jn++) {
#pragma unroll
      for (int p = 0; p < 4; p++) {
        int qrow = strip * 16 + quad * 4 + p;
        if (qrow < WHT)
          outA[((size_t)(1 + tq * WHT + qrow) * 8 + b) * CC + h * 64 + jn * 16 + l16] =
              acc_o[jn][p] * inv4[p];
      }
    }
  }
}

// ---------------------------------------------------------------------------
// Final LN (token 0 only) + classifier head
// ---------------------------------------------------------------------------
__global__ __launch_bounds__(256)
void head_kernel(const float* __restrict__ X, const float* __restrict__ enw,
                 const float* __restrict__ enb, const float* __restrict__ fcw,
                 const float* __restrict__ fcb, float* __restrict__ out) {
  __shared__ float nx[512];
  __shared__ float red[8];
  const int b = blockIdx.x, tid = threadIdx.x;
  const float* x = X + (size_t)b * CC;
  float v0 = x[tid], v1 = x[tid + 256];
  float s = wave_reduce_sum(v0 + v1);
  if ((tid & 63) == 0) red[tid >> 6] = s;
  __syncthreads();
  float mean = (red[0] + red[1] + red[2] + red[3]) * (1.f / 512.f);
  float d0 = v0 - mean, d1 = v1 - mean;
  float vs = wave_reduce_sum(d0 * d0 + d1 * d1);
  if ((tid & 63) == 0) red[4 + (tid >> 6)] = vs;
  __syncthreads();
  float var = (red[4] + red[5] + red[6] + red[7]) * (1.f / 512.f);
  float inv = 1.0f / sqrtf(var + 1e-5f);
  nx[tid] = d0 * inv * enw[tid] + enb[tid];
  nx[tid + 256] = d1 * inv * enw[tid + 256] + enb[tid + 256];
  __syncthreads();
  if (tid < NCLS) {
    float acc = fcb[tid];
    for (int c = 0; c < 512; c++) acc += nx[c] * fcw[c * NCLS + tid];
    out[b * NCLS + tid] = acc;
  }
}

// ---------------------------------------------------------------------------
extern "C" void kernel_launch(void* const* d_in, const int* in_sizes, int n_in,
                              void* d_out, int out_size, void* d_ws, size_t ws_size,
                              hipStream_t stream) {
  (void)in_sizes; (void)n_in; (void)out_size; (void)ws_size;
  const float* src  = (const float*)d_in[0];
  const float* cw   = (const float*)d_in[1];
  const float* cb   = (const float*)d_in[2];
  const float* clst = (const float*)d_in[3];
  const float* pos  = (const float*)d_in[4];
  const float* Wt   = (const float*)d_in[5];
  const float* bt   = (const float*)d_in[6];
  const float* Wsp  = (const float*)d_in[7];
  const float* bsp  = (const float*)d_in[8];
  const float* Wo   = (const float*)d_in[9];
  const float* bo   = (const float*)d_in[10];
  const float* n1w  = (const float*)d_in[11];
  const float* n1b  = (const float*)d_in[12];
  const float* n2w  = (const float*)d_in[13];
  const float* n2b  = (const float*)d_in[14];
  const float* W1   = (const float*)d_in[15];
  const float* b1   = (const float*)d_in[16];
  const float* W2   = (const float*)d_in[17];
  const float* b2   = (const float*)d_in[18];
  const float* enw  = (const float*)d_in[19];
  const float* enb  = (const float*)d_in[20];
  const float* fcw  = (const float*)d_in[21];
  const float* fcb  = (const float*)d_in[22];

  float* ws = (float*)d_ws;
  const size_t TOKR = (size_t)3137 * 8;
  float* X0  = ws;                              // TOKR*512
  float* Ab  = X0 + TOKR * 512;                 // TOKR*512
  float* QKV = Ab + TOKR * 512;                 // TOKR*1536 (also FFN mid / im2col)
  float* CLS = QKV + TOKR * 1536;               // 8*512
  int*   IDX = (int*)(CLS + 8 * 512);           // 8*8*196*16 ints
  unsigned short* WT1 = (unsigned short*)(IDX + 8 * 8 * WHT * 16);  // 2048*512
  unsigned short* WT2 = WT1 + 2048 * 512;                           // 2048*512
  float* PART = (float*)(WT2 + 2048 * 512);     // 64*CA_NCH*68

  // Patch embed as im2col + split-bf16 MFMA GEMM (M=25088, N=512, K=768).
  wsplit_flat_kernel<<<(512 * 768 + 255) / 256, 256, 0, stream>>>(
      cw, WT1, WT2, 512 * 768);
  im2col_kernel<<<(25088 * 192) / 256, 256, 0, stream>>>(src, QKV);
  mfma_gemm3_kernel<<<dim3(25088 / 128, 4), 256, 0, stream>>>(
      QKV, WT1, WT2, cb, X0 + 8 * CC, 25088, 512, 768);
  cls_init_kernel<<<8, 512, 0, stream>>>(clst, X0);

  float* Xc = X0;
  int t = 16;
  const int FFN_CHUNK = 16384;
  for (int i = 0; i < 6; i++) {
    const int pk = (i & 1) ? 2 : 0;
    const int tp = t - pk;
    const int L = 1 + t * WHT;
    const int Lo = 1 + tp * WHT;
    const int M = L * 8, Mo = Lo * 8, My = tp * WHT * 8;

    ln_kernel<<<M, 256, 0, stream>>>(Xc, Ab, n1w + (size_t)i * 512, n1b + (size_t)i * 512,
                                     (i == 0) ? pos : nullptr);
    // sigma-critical Wt: split-bf16 MFMA (hi/lo), fp32-class accuracy
    wtrans_split_kernel<<<dim3(1536 / 32, 512 / 32), 256, 0, stream>>>(
        Wt + (size_t)i * 512 * 1536, WT1, WT2, 1536, 512);
    mfma_gemm3_kernel<<<dim3((M + 127) / 128, 12), 256, 0, stream>>>(
        Ab, WT1, WT2, bt + (size_t)i * 1536, QKV, M, 1536, 512);
    class_attn_part_kernel<<<dim3(64, CA_NCH), 256, 0, stream>>>(QKV, PART, L);
    class_attn_reduce_kernel<<<64, 64, 0, stream>>>(PART, CLS);
    temporal_attn_kernel<<<HH * BB * WHT, 256, 0, stream>>>(QKV, Ab, IDX, t, tp, pk);
    // Ws: plain bf16 MFMA
    wtrans_kernel<<<dim3(1536 / 32, 512 / 32), 256, 0, stream>>>(
        Wsp + (size_t)i * 512 * 1536, WT1, 1536, 512);
    mfma_gemm_kernel<0, 0><<<dim3((My + 127) / 128, 12), 256, 0, stream>>>(
        Ab, WT1, bsp + (size_t)i * 1536, QKV, My, 1536, 512, nullptr);
    copy_cls_kernel<<<8, 512, 0, stream>>>(CLS, Ab);
    spatial_mfma_kernel<<<64 * tp, 256, 0, stream>>>(QKV, Ab);
    if (pk > 0)
      pool_inplace_kernel<<<8 * WHT, 256, 0, stream>>>(Xc, IDX, tp);
    // Wo: plain bf16 MFMA + residual
    wtrans_kernel<<<dim3(512 / 32, 512 / 32), 256, 0, stream>>>(
        Wo + (size_t)i * 512 * 512, WT1, 512, 512);
    mfma_gemm_kernel<0, 1><<<dim3((Mo + 127) / 128, 4), 256, 0, stream>>>(
        Ab, WT1, bo + (size_t)i * 512, Xc, Mo, 512, 512, Xc);
    ln_kernel<<<Mo, 256, 0, stream>>>(Xc, Ab, n2w + (size_t)i * 512, n2b + (size_t)i * 512,
                                      nullptr);
    // FFN: plain bf16 MFMA
    wtrans_kernel<<<dim3(2048 / 32, 512 / 32), 256, 0, stream>>>(
        W1 + (size_t)i * 512 * 2048, WT1, 2048, 512);
    wtrans_kernel<<<dim3(512 / 32, 2048 / 32), 256, 0, stream>>>(
        W2 + (size_t)i * 2048 * 512, WT2, 512, 2048);
    for (int off = 0; off < Mo; off += FFN_CHUNK) {
      int R = Mo - off;
      if (R > FFN_CHUNK) R = FFN_CHUNK;
      mfma_gemm_kernel<1, 0><<<dim3((R + 127) / 128, 16), 256, 0, stream>>>(
          Ab + (size_t)off * 512, WT1, b1 + (size_t)i * 2048, QKV, R, 2048, 512,
          nullptr);
      mfma_gemm_kernel<0, 1><<<dim3((R + 127) / 128, 4), 256, 0, stream>>>(
          QKV, WT2, b2 + (size_t)i * 512, Xc + (size_t)off * 512, R, 512, 2048,
          Xc + (size_t)off * 512);
    }
    t = tp;
  }
  head_kernel<<<8, 256, 0, stream>>>(Xc, enw, enb, fcw, fcb, (float*)d_out);
}

// Round 4
// 6010.170 us; speedup vs baseline: 1.6496x; 1.0144x over previous
//
#include <hip/hip_runtime.h>
#include <math.h>

// ---------------------------------------------------------------------------
// CompactVidTr forward.
//  - Patch-embed conv: im2col (split bf16 hi/lo planes) + split-bf16 MFMA GEMM.
//  - Wt (QKV) GEMM: A pre-split by ln_split_kernel (hi/lo bf16 planes in Ab);
//    3-term split MFMA -> fp32-class accuracy for the sigma-top-k path.
//  - ALL GEMM grids are (n-tiles, m-tiles) with n FASTEST: blocks sharing an
//    A-tile are temporally adjacent -> A stays hot in L2/L3 (the old m-fastest
//    order re-streamed A once per n-sweep: 317 MB fetch vs 54 MB ideal).
//  - Spatial attention: split-bf16 MFMA flash kernel.
//  - Class attention: two-phase flash split over L.
//  - Ws/Wo/FFN GEMMs: plain bf16 MFMA (incremental-error paths).
//  - Temporal attention + LN: fp32 vector.
// Layout: token matrices row-major [row = l*B + b][C]; l=0 is cls. B=8, C=512.
//
// Workspace (262.5 MB < 268.4 MB):
//   X   : 3137*8 x 512  fp32   (51.4 MB)  residual stream, pooled IN PLACE
//   Ab  : 3137*8 x 512  fp32   (51.4 MB)  LN-split bf16 planes / attn staging
//   QKV : 3137*8 x 1536 fp32  (154.1 MB)  qkv GEMM out; FFN mid; im2col planes
//   CLS : 8x512 fp32, IDX: 8*8*196*16 int (~0.8 MB)
//   WT1 : 2048*512 bf16 (2.1 MB)  weight scratch
//   WT2 : 2048*512 bf16 (2.1 MB)  weight scratch
//   PART: 64*32*68 fp32 (0.56 MB) class-attn partials
// ---------------------------------------------------------------------------

#define BB 8
#define CC 512
#define HH 8
#define HD 64
#define WHT 196
#define NCLS 157
#define CA_NCH 32

typedef short bf16x8 __attribute__((ext_vector_type(8)));
typedef float floatx4 __attribute__((ext_vector_type(4)));

__device__ __forceinline__ unsigned short f2bf(float f) {
  unsigned u = __float_as_uint(f);
  unsigned r = u + 0x7FFFu + ((u >> 16) & 1u);  // RNE
  return (unsigned short)(r >> 16);
}
__device__ __forceinline__ float bf2f(unsigned short h) {
  return __uint_as_float((unsigned)h << 16);
}
// truncation split: hi = top-16-bits, lo = RNE(residual); reconstruct ~2^-17
__device__ __forceinline__ void splitf(float x, unsigned short& h, unsigned short& l) {
  unsigned u = __float_as_uint(x);
  unsigned hs = u >> 16;
  float rem = x - __uint_as_float(hs << 16);
  h = (unsigned short)hs;
  l = f2bf(rem);
}

__device__ __forceinline__ float wave_reduce_sum(float v) {
#pragma unroll
  for (int o = 32; o > 0; o >>= 1) v += __shfl_down(v, o, 64);
  return v;
}
__device__ __forceinline__ float wave_reduce_max(float v) {
#pragma unroll
  for (int o = 32; o > 0; o >>= 1) v = fmaxf(v, __shfl_down(v, o, 64));
  return v;
}

// ---------------------------------------------------------------------------
// im2col + split: src [8][3][16][224][224] -> IMhi/IMlo [25088][768] bf16.
// ---------------------------------------------------------------------------
__global__ __launch_bounds__(256)
void im2col_split_kernel(const float* __restrict__ src,
                         unsigned short* __restrict__ IMhi,
                         unsigned short* __restrict__ IMlo) {
  int gid = blockIdx.x * 256 + threadIdx.x;
  int k4 = gid % 192;
  int u = gid / 192;
  if (u >= 25088) return;
  int b = u & 7;
  int s = u >> 3;
  int tt = s / WHT;
  int w2 = s % WHT;
  int ph = w2 / 14, pw = w2 % 14;
  int k = k4 * 4;
  int ci = k >> 8;
  int rem = k & 255;
  int py = rem >> 4, px = rem & 15;
  const float* sp = src + (size_t)b * (3 * 16 * 224 * 224) +
                    (size_t)ci * (16 * 224 * 224) + (size_t)tt * (224 * 224) +
                    (size_t)(ph * 16 + py) * 224 + pw * 16 + px;
  float4 v = *(const float4*)sp;
  ushort4 h, l;
  splitf(v.x, h.x, l.x);
  splitf(v.y, h.y, l.y);
  splitf(v.z, h.z, l.z);
  splitf(v.w, h.w, l.w);
  *(ushort4*)(IMhi + (size_t)u * 768 + k) = h;
  *(ushort4*)(IMlo + (size_t)u * 768 + k) = l;
}

__global__ __launch_bounds__(256)
void wsplit_flat_kernel(const float* __restrict__ W,
                        unsigned short* __restrict__ Whi,
                        unsigned short* __restrict__ Wlo, int total) {
  int i = blockIdx.x * 256 + threadIdx.x;
  if (i >= total) return;
  float w = W[i];
  unsigned short hi = f2bf(w);
  Whi[i] = hi;
  Wlo[i] = f2bf(w - bf2f(hi));
}

__global__ void cls_init_kernel(const float* __restrict__ clst, float* __restrict__ X) {
  X[(size_t)blockIdx.x * CC + threadIdx.x] = clst[threadIdx.x];
}

__global__ void copy_cls_kernel(const float* __restrict__ cls, float* __restrict__ A) {
  A[(size_t)blockIdx.x * CC + threadIdx.x] = cls[(size_t)blockIdx.x * CC + threadIdx.x];
}

// ---------------------------------------------------------------------------
// LayerNorm over C=512 (fp32 out); one block per row
// ---------------------------------------------------------------------------
__global__ __launch_bounds__(256)
void ln_kernel(const float* __restrict__ X, float* __restrict__ O,
               const float* __restrict__ w, const float* __restrict__ b,
               const float* __restrict__ pos) {
  __shared__ float red[8];
  const int row = blockIdx.x, tid = threadIdx.x;
  const float* x = X + (size_t)row * CC;
  float v0 = x[tid], v1 = x[tid + 256];
  float s = wave_reduce_sum(v0 + v1);
  if ((tid & 63) == 0) red[tid >> 6] = s;
  __syncthreads();
  float mean = (red[0] + red[1] + red[2] + red[3]) * (1.f / 512.f);
  float d0 = v0 - mean, d1 = v1 - mean;
  float vs = wave_reduce_sum(d0 * d0 + d1 * d1);
  if ((tid & 63) == 0) red[4 + (tid >> 6)] = vs;
  __syncthreads();
  float var = (red[4] + red[5] + red[6] + red[7]) * (1.f / 512.f);
  float inv = 1.0f / sqrtf(var + 1e-5f);
  float o0 = d0 * inv * w[tid] + b[tid];
  float o1 = d1 * inv * w[tid + 256] + b[tid + 256];
  if (pos) {
    const float* pr = pos + (size_t)(row >> 3) * CC;
    o0 += pr[tid];
    o1 += pr[tid + 256];
  }
  O[(size_t)row * CC + tid] = o0;
  O[(size_t)row * CC + tid + 256] = o1;
}

// ---------------------------------------------------------------------------
// LayerNorm + split-bf16 output (hi/lo planes) — feeds the Wt split GEMM.
// ---------------------------------------------------------------------------
__global__ __launch_bounds__(256)
void ln_split_kernel(const float* __restrict__ X,
                     unsigned short* __restrict__ Ahi,
                     unsigned short* __restrict__ Alo,
                     const float* __restrict__ w, const float* __restrict__ b,
                     const float* __restrict__ pos) {
  __shared__ float red[8];
  const int row = blockIdx.x, tid = threadIdx.x;
  const float* x = X + (size_t)row * CC;
  float v0 = x[tid], v1 = x[tid + 256];
  float s = wave_reduce_sum(v0 + v1);
  if ((tid & 63) == 0) red[tid >> 6] = s;
  __syncthreads();
  float mean = (red[0] + red[1] + red[2] + red[3]) * (1.f / 512.f);
  float d0 = v0 - mean, d1 = v1 - mean;
  float vs = wave_reduce_sum(d0 * d0 + d1 * d1);
  if ((tid & 63) == 0) red[4 + (tid >> 6)] = vs;
  __syncthreads();
  float var = (red[4] + red[5] + red[6] + red[7]) * (1.f / 512.f);
  float inv = 1.0f / sqrtf(var + 1e-5f);
  float o0 = d0 * inv * w[tid] + b[tid];
  float o1 = d1 * inv * w[tid + 256] + b[tid + 256];
  if (pos) {
    const float* pr = pos + (size_t)(row >> 3) * CC;
    o0 += pr[tid];
    o1 += pr[tid + 256];
  }
  unsigned short h, l;
  splitf(o0, h, l);
  Ahi[(size_t)row * CC + tid] = h;
  Alo[(size_t)row * CC + tid] = l;
  splitf(o1, h, l);
  Ahi[(size_t)row * CC + tid + 256] = h;
  Alo[(size_t)row * CC + tid + 256] = l;
}

// ---------------------------------------------------------------------------
// Weight transpose + fp32->bf16 (plain): W [K][N] -> WT [N][K]
// ---------------------------------------------------------------------------
__global__ __launch_bounds__(256)
void wtrans_kernel(const float* __restrict__ W, unsigned short* __restrict__ WT,
                   int N, int K) {
  __shared__ float tile[32][33];
  const int tid = threadIdx.x;
  const int tx = tid & 31, ty = tid >> 5;
  const int n0 = blockIdx.x * 32, k0 = blockIdx.y * 32;
#pragma unroll
  for (int r = 0; r < 4; r++) {
    int kk = ty + r * 8;
    tile[kk][tx] = W[(size_t)(k0 + kk) * N + n0 + tx];
  }
  __syncthreads();
#pragma unroll
  for (int r = 0; r < 4; r++) {
    int nn = ty + r * 8;
    WT[(size_t)(n0 + nn) * K + k0 + tx] = f2bf(tile[tx][nn]);
  }
}

// ---------------------------------------------------------------------------
// Weight transpose + split fp32 -> (hi, lo) bf16: W [K][N] -> WThi/WTlo [N][K]
// ---------------------------------------------------------------------------
__global__ __launch_bounds__(256)
void wtrans_split_kernel(const float* __restrict__ W,
                         unsigned short* __restrict__ WThi,
                         unsigned short* __restrict__ WTlo, int N, int K) {
  __shared__ float tile[32][33];
  const int tid = threadIdx.x;
  const int tx = tid & 31, ty = tid >> 5;
  const int n0 = blockIdx.x * 32, k0 = blockIdx.y * 32;
#pragma unroll
  for (int r = 0; r < 4; r++) {
    int kk = ty + r * 8;
    tile[kk][tx] = W[(size_t)(k0 + kk) * N + n0 + tx];
  }
  __syncthreads();
#pragma unroll
  for (int r = 0; r < 4; r++) {
    int nn = ty + r * 8;
    float w = tile[tx][nn];
    unsigned short hi = f2bf(w);
    unsigned short lo = f2bf(w - bf2f(hi));
    WThi[(size_t)(n0 + nn) * K + k0 + tx] = hi;
    WTlo[(size_t)(n0 + nn) * K + k0 + tx] = lo;
  }
}

// ---------------------------------------------------------------------------
// Plain bf16 MFMA GEMM: C = A(M,K) @ W(K,N) + bias [+relu] [+residual]
// grid = (n-tiles, m-tiles): n fastest for A-tile L2 locality.
// ---------------------------------------------------------------------------
template <int RELU, int RES>
__global__ __launch_bounds__(256)
void mfma_gemm_kernel(const float* __restrict__ A,
                      const unsigned short* __restrict__ WT,
                      const float* __restrict__ bias, float* __restrict__ Cout,
                      int M, int N, int K, const float* __restrict__ resid) {
  __shared__ unsigned short AsU[128 * 40];
  __shared__ unsigned short BsU[128 * 40];
  const int tid = threadIdx.x;
  const int wave = tid >> 6, lane = tid & 63;
  const int quad = lane >> 4, l16 = lane & 15;
  const int wrow = (wave >> 1) * 64, wcol = (wave & 1) * 64;
  const int m0 = blockIdx.y * 128, n0 = blockIdx.x * 128;

  floatx4 acc[4][4];
#pragma unroll
  for (int i = 0; i < 4; i++)
#pragma unroll
    for (int j = 0; j < 4; j++) acc[i][j] = (floatx4){0.f, 0.f, 0.f, 0.f};

  for (int k0 = 0; k0 < K; k0 += 32) {
#pragma unroll
    for (int r = 0; r < 4; r++) {
      int e = (tid + r * 256) * 4;
      int row = e >> 5, col = e & 31;
      int gm = m0 + row;
      float4 v = make_float4(0.f, 0.f, 0.f, 0.f);
      if (gm < M) v = *(const float4*)(A + (size_t)gm * K + k0 + col);
      ushort4 o;
      o.x = f2bf(v.x); o.y = f2bf(v.y); o.z = f2bf(v.z); o.w = f2bf(v.w);
      *(ushort4*)&AsU[row * 40 + col] = o;
    }
#pragma unroll
    for (int r = 0; r < 4; r++) {
      int e = (tid + r * 256) * 4;
      int n = e >> 5, k = e & 31;
      ushort4 w = *(const ushort4*)(WT + (size_t)(n0 + n) * K + k0 + k);
      *(ushort4*)&BsU[n * 40 + k] = w;
    }
    __syncthreads();
    bf16x8 af[4], bf[4];
#pragma unroll
    for (int i = 0; i < 4; i++)
      af[i] = *(const bf16x8*)&AsU[(wrow + i * 16 + l16) * 40 + quad * 8];
#pragma unroll
    for (int j = 0; j < 4; j++)
      bf[j] = *(const bf16x8*)&BsU[(wcol + j * 16 + l16) * 40 + quad * 8];
#pragma unroll
    for (int i = 0; i < 4; i++)
#pragma unroll
      for (int j = 0; j < 4; j++)
        acc[i][j] = __builtin_amdgcn_mfma_f32_16x16x32_bf16(af[i], bf[j],
                                                            acc[i][j], 0, 0, 0);
    __syncthreads();
  }
#pragma unroll
  for (int i = 0; i < 4; i++) {
#pragma unroll
    for (int p = 0; p < 4; p++) {
      int gm = m0 + wrow + i * 16 + quad * 4 + p;
      if (gm >= M) continue;
#pragma unroll
      for (int j = 0; j < 4; j++) {
        int gn = n0 + wcol + j * 16 + l16;
        float v = acc[i][j][p] + bias[gn];
        if (RELU) v = fmaxf(v, 0.f);
        if (RES == 1) v += resid[(size_t)gm * N + gn];
        Cout[(size_t)gm * N + gn] = v;
      }
    }
  }
}

// ---------------------------------------------------------------------------
// Split-bf16 MFMA GEMM, pre-split A (hi/lo bf16 planes — no staging VALU):
// C = Ahi@Bhi + Ahi@Blo + Alo@Bhi + bias.  grid = (n-tiles, m-tiles).
// ---------------------------------------------------------------------------
__global__ __launch_bounds__(256)
void mfma_gemm3s_kernel(const unsigned short* __restrict__ Ahi,
                        const unsigned short* __restrict__ Alo,
                        const unsigned short* __restrict__ WThi,
                        const unsigned short* __restrict__ WTlo,
                        const float* __restrict__ bias, float* __restrict__ Cout,
                        int M, int N, int K) {
  __shared__ unsigned short AsHi[128 * 40];
  __shared__ unsigned short AsLo[128 * 40];
  __shared__ unsigned short BsHi[128 * 40];
  __shared__ unsigned short BsLo[128 * 40];
  const int tid = threadIdx.x;
  const int wave = tid >> 6, lane = tid & 63;
  const int quad = lane >> 4, l16 = lane & 15;
  const int wrow = (wave >> 1) * 64, wcol = (wave & 1) * 64;
  const int m0 = blockIdx.y * 128, n0 = blockIdx.x * 128;

  floatx4 acc[4][4];
#pragma unroll
  for (int i = 0; i < 4; i++)
#pragma unroll
    for (int j = 0; j < 4; j++) acc[i][j] = (floatx4){0.f, 0.f, 0.f, 0.f};

  for (int k0 = 0; k0 < K; k0 += 32) {
#pragma unroll
    for (int r = 0; r < 2; r++) {
      int e = (tid + r * 256) * 8;
      int row = e >> 5, col = e & 31;
      int gm = m0 + row;
      uint4 vh = make_uint4(0u, 0u, 0u, 0u), vl = make_uint4(0u, 0u, 0u, 0u);
      if (gm < M) {
        vh = *(const uint4*)(Ahi + (size_t)gm * K + k0 + col);
        vl = *(const uint4*)(Alo + (size_t)gm * K + k0 + col);
      }
      *(uint4*)&AsHi[row * 40 + col] = vh;
      *(uint4*)&AsLo[row * 40 + col] = vl;
    }
#pragma unroll
    for (int r = 0; r < 4; r++) {
      int e = (tid + r * 256) * 4;
      int n = e >> 5, k = e & 31;
      *(ushort4*)&BsHi[n * 40 + k] =
          *(const ushort4*)(WThi + (size_t)(n0 + n) * K + k0 + k);
      *(ushort4*)&BsLo[n * 40 + k] =
          *(const ushort4*)(WTlo + (size_t)(n0 + n) * K + k0 + k);
    }
    __syncthreads();
    bf16x8 ah[4], al[4], bh[4], bl[4];
#pragma unroll
    for (int i = 0; i < 4; i++) {
      ah[i] = *(const bf16x8*)&AsHi[(wrow + i * 16 + l16) * 40 + quad * 8];
      al[i] = *(const bf16x8*)&AsLo[(wrow + i * 16 + l16) * 40 + quad * 8];
    }
#pragma unroll
    for (int j = 0; j < 4; j++) {
      bh[j] = *(const bf16x8*)&BsHi[(wcol + j * 16 + l16) * 40 + quad * 8];
      bl[j] = *(const bf16x8*)&BsLo[(wcol + j * 16 + l16) * 40 + quad * 8];
    }
#pragma unroll
    for (int i = 0; i < 4; i++)
#pragma unroll
      for (int j = 0; j < 4; j++) {
        acc[i][j] = __builtin_amdgcn_mfma_f32_16x16x32_bf16(ah[i], bh[j],
                                                            acc[i][j], 0, 0, 0);
        acc[i][j] = __builtin_amdgcn_mfma_f32_16x16x32_bf16(ah[i], bl[j],
                                                            acc[i][j], 0, 0, 0);
        acc[i][j] = __builtin_amdgcn_mfma_f32_16x16x32_bf16(al[i], bh[j],
                                                            acc[i][j], 0, 0, 0);
      }
    __syncthreads();
  }
#pragma unroll
  for (int i = 0; i < 4; i++) {
#pragma unroll
    for (int p = 0; p < 4; p++) {
      int gm = m0 + wrow + i * 16 + quad * 4 + p;
      if (gm >= M) continue;
#pragma unroll
      for (int j = 0; j < 4; j++) {
        int gn = n0 + wcol + j * 16 + l16;
        Cout[(size_t)gm * N + gn] = acc[i][j][p] + bias[gn];
      }
    }
  }
}

// ---------------------------------------------------------------------------
// Class attention, phase 1: per-(h,b) x per-chunk partial flash softmax.
// part record [68]: [0]=local max, [1]=local expsum, [2..65]=pv[64].
// ---------------------------------------------------------------------------
__global__ __launch_bounds__(256)
void class_attn_part_kernel(const float* __restrict__ qkv,
                            float* __restrict__ part, int L) {
  __shared__ float q[64];
  __shared__ float sc[128];
  __shared__ float red[8];
  __shared__ float pv[256];
  const int h = blockIdx.x & 7, b = blockIdx.x >> 3;
  const int chunk = blockIdx.y;
  const int tid = threadIdx.x;
  const int per = (L + CA_NCH - 1) / CA_NCH;
  const int l0 = chunk * per;
  const int nl = min(L - l0, per);
  if (tid < 64) q[tid] = qkv[(size_t)b * 1536 + h * 64 + tid] * 0.125f;
  __syncthreads();
  float lmax = -3.4e38f;
  for (int i = tid; i < nl; i += 256) {
    const float* kr = qkv + (size_t)((l0 + i) * 8 + b) * 1536 + 512 + h * 64;
    float s = 0;
#pragma unroll
    for (int d2 = 0; d2 < 64; d2 += 4) {
      float4 k4 = *(const float4*)(kr + d2);
      s += q[d2] * k4.x + q[d2 + 1] * k4.y + q[d2 + 2] * k4.z + q[d2 + 3] * k4.w;
    }
    sc[i] = s;
    lmax = fmaxf(lmax, s);
  }
  lmax = wave_reduce_max(lmax);
  if ((tid & 63) == 0) red[tid >> 6] = lmax;
  __syncthreads();
  float gmax = fmaxf(fmaxf(red[0], red[1]), fmaxf(red[2], red[3]));
  float lsum = 0;
  for (int i = tid; i < nl; i += 256) {
    float e = expf(sc[i] - gmax);
    sc[i] = e;
    lsum += e;
  }
  lsum = wave_reduce_sum(lsum);
  if ((tid & 63) == 0) red[4 + (tid >> 6)] = lsum;
  __syncthreads();
  float gsum = red[4] + red[5] + red[6] + red[7];
  const int g = tid >> 6, d = tid & 63;
  float acc = 0;
  for (int i = g; i < nl; i += 4)
    acc += sc[i] * qkv[(size_t)((l0 + i) * 8 + b) * 1536 + 1024 + h * 64 + d];
  pv[g * 64 + d] = acc;
  __syncthreads();
  float* rec = part + ((size_t)blockIdx.x * CA_NCH + chunk) * 68;
  if (tid == 0) {
    rec[0] = gmax;
    rec[1] = gsum;
  }
  if (g == 0) rec[2 + d] = pv[d] + pv[64 + d] + pv[128 + d] + pv[192 + d];
}

// ---------------------------------------------------------------------------
// Class attention, phase 2: combine CA_NCH partials per (h,b).
// ---------------------------------------------------------------------------
__global__ __launch_bounds__(64)
void class_attn_reduce_kernel(const float* __restrict__ part,
                              float* __restrict__ cls) {
  const int hb = blockIdx.x;  // (b<<3)|h
  const int tid = threadIdx.x;
  const float* prec = part + (size_t)hb * CA_NCH * 68;
  float M = -3.4e38f;
#pragma unroll
  for (int c = 0; c < CA_NCH; c++) M = fmaxf(M, prec[c * 68]);
  float total = 0.f, acc = 0.f;
#pragma unroll
  for (int c = 0; c < CA_NCH; c++) {
    float w = expf(prec[c * 68] - M);
    total += prec[c * 68 + 1] * w;
    acc += prec[c * 68 + 2 + tid] * w;
  }
  int h = hb & 7, b = hb >> 3;
  cls[b * CC + h * 64 + tid] = acc / total;
}

// ---------------------------------------------------------------------------
// Temporal attention + sigma top-k pooling (fp32 — rank-critical).
// ---------------------------------------------------------------------------
__global__ __launch_bounds__(256)
void temporal_attn_kernel(const float* __restrict__ qkv, float* __restrict__ Y,
                          int* __restrict__ idxbuf, int t, int tp, int pk) {
  __shared__ float qs[16 * 65], ks[16 * 65], vs[16 * 65];
  __shared__ float a[16 * 17];
  __shared__ float sig[16];
  __shared__ int keepf[16];
  __shared__ int klist[16];
  const int g = blockIdx.x;
  const int w = g % WHT;
  const int bb = (g / WHT) & 7;
  const int h = g / (WHT * 8);
  const int tid = threadIdx.x;
  const int td = t * 64;
  for (int e = tid; e < td; e += 256) {
    int tt = e >> 6, d = e & 63;
    size_t rb = (size_t)((1 + tt * WHT + w) * 8 + bb) * 1536 + h * 64 + d;
    qs[tt * 65 + d] = qkv[rb] * 0.125f;
    ks[tt * 65 + d] = qkv[rb + 512];
    vs[tt * 65 + d] = qkv[rb + 1024];
  }
  __syncthreads();
  if (tid < t * t) {
    int qi = tid / t, ki = tid % t;
    const float* qp = &qs[qi * 65];
    const float* kp = &ks[ki * 65];
    float s = 0;
#pragma unroll 8
    for (int d2 = 0; d2 < 64; d2++) s += qp[d2] * kp[d2];
    a[qi * 17 + ki] = s;
  }
  __syncthreads();
  if (tid < t) {
    float* row = &a[tid * 17];
    float m = row[0];
    for (int k2 = 1; k2 < t; k2++) m = fmaxf(m, row[k2]);
    float sum = 0;
    for (int k2 = 0; k2 < t; k2++) {
      float e2 = expf(row[k2] - m);
      row[k2] = e2;
      sum += e2;
    }
    float inv = 1.f / sum;
    for (int k2 = 0; k2 < t; k2++) row[k2] *= inv;
  }
  __syncthreads();
  if (pk > 0) {
    if (tid < t) {
      const float* row = &a[tid * 17];
      float mean = 0;
      for (int k2 = 0; k2 < t; k2++) mean += row[k2];
      mean /= (float)t;
      float var = 0;
      for (int k2 = 0; k2 < t; k2++) {
        float dl = row[k2] - mean;
        var += dl * dl;
      }
      var /= (float)(t - 1);
      sig[tid] = sqrtf(var);
    }
    __syncthreads();
    if (tid < t) {
      float sv = sig[tid];
      int r = 0;
      for (int q2 = 0; q2 < t; q2++) {
        float so = sig[q2];
        if (so > sv || (so == sv && q2 < tid)) r++;
      }
      keepf[tid] = (r < tp) ? 1 : 0;
    }
    __syncthreads();
    if (tid < t && keepf[tid]) {
      int ppos = 0;
      for (int q2 = 0; q2 < tid; q2++) ppos += keepf[q2];
      klist[ppos] = tid;
      idxbuf[((h * 8 + bb) * WHT + w) * 16 + ppos] = tid;
    }
  } else {
    if (tid < t) klist[tid] = tid;
  }
  __syncthreads();
  const int gq = tid >> 6, d = tid & 63;
  for (int qi = gq; qi < tp; qi += 4) {
    int qq = klist[qi];
    const float* arow = &a[qq * 17];
    float acc = 0;
    for (int k2 = 0; k2 < t; k2++) acc += arow[k2] * vs[k2 * 65 + d];
    Y[(size_t)((qi * WHT + w) * 8 + bb) * CC + h * 64 + d] = acc;
  }
}

// ---------------------------------------------------------------------------
// In-place temporal pooling of the residual stream X.
// ---------------------------------------------------------------------------
__global__ __launch_bounds__(256)
void pool_inplace_kernel(float* __restrict__ X, const int* __restrict__ idxbuf,
                         int tp) {
  const int b = blockIdx.x & 7;
  const int w = blockIdx.x >> 3;
  const int tid = threadIdx.x;
  const int c0 = tid, c1 = tid + 256;
  const int h0 = c0 >> 6, h1 = c1 >> 6;
  const int ib0 = ((h0 * 8 + b) * WHT + w) * 16;
  const int ib1 = ((h1 * 8 + b) * WHT + w) * 16;
  for (int q = 0; q < tp; q++) {
    int s0 = idxbuf[ib0 + q];
    int s1 = idxbuf[ib1 + q];
    size_t drow = (size_t)((1 + q * WHT + w) * 8 + b) * CC;
    if (s0 != q) {
      size_t srow = (size_t)((1 + s0 * WHT + w) * 8 + b) * CC;
      X[drow + c0] = X[srow + c0];
    }
    if (s1 != q) {
      size_t srow = (size_t)((1 + s1 * WHT + w) * 8 + b) * CC;
      X[drow + c1] = X[srow + c1];
    }
  }
}

// ---------------------------------------------------------------------------
// Spatial attention, split-bf16 MFMA flash kernel.
// Block = (h, b, tq): full 196x196x64 attention. 4 waves, 13 q-strips of 16.
// ---------------------------------------------------------------------------
__global__ __launch_bounds__(256)
void spatial_mfma_kernel(const float* __restrict__ qkv, float* __restrict__ outA) {
  __shared__ unsigned short Khi[208 * 72];
  __shared__ unsigned short Klo[208 * 72];
  __shared__ unsigned short Vthi[64 * 200];
  __shared__ unsigned short Vtlo[64 * 200];
  __shared__ unsigned int Ps[4][16 * 196];
  const int blk = blockIdx.x;
  const int h = blk & 7;
  const int b = (blk >> 3) & 7;
  const int tq = blk >> 6;
  const int tid = threadIdx.x;
  const int wave = tid >> 6, lane = tid & 63;
  const int quad = lane >> 4, l16 = lane & 15;
  const size_t rowbase = (size_t)(tq * WHT) * 8 + b;  // qkv row for w=0

  union BF8 { bf16x8 v; unsigned short s[8]; unsigned int u[4]; };

  // ---- stage K (hi/lo) and V (transposed hi/lo) ----
  for (int r = tid >> 4; r < WHT; r += 16) {
    int c = (tid & 15) * 4;
    const float* gk = qkv + (rowbase + (size_t)r * 8) * 1536 + 512 + h * 64 + c;
    float4 kv = *(const float4*)gk;
    ushort4 khs, kls;
    splitf(kv.x, khs.x, kls.x);
    splitf(kv.y, khs.y, kls.y);
    splitf(kv.z, khs.z, kls.z);
    splitf(kv.w, khs.w, kls.w);
    *(ushort4*)&Khi[r * 72 + c] = khs;
    *(ushort4*)&Klo[r * 72 + c] = kls;
    const float* gv = qkv + (rowbase + (size_t)r * 8) * 1536 + 1024 + h * 64 + c;
    float4 vv = *(const float4*)gv;
    unsigned short vh, vl;
    splitf(vv.x, vh, vl); Vthi[(c + 0) * 200 + r] = vh; Vtlo[(c + 0) * 200 + r] = vl;
    splitf(vv.y, vh, vl); Vthi[(c + 1) * 200 + r] = vh; Vtlo[(c + 1) * 200 + r] = vl;
    splitf(vv.z, vh, vl); Vthi[(c + 2) * 200 + r] = vh; Vtlo[(c + 2) * 200 + r] = vl;
    splitf(vv.w, vh, vl); Vthi[(c + 3) * 200 + r] = vh; Vtlo[(c + 3) * 200 + r] = vl;
  }
  __syncthreads();

  unsigned int* myP = &Ps[wave][0];

  for (int strip = wave; strip < 13; strip += 4) {
    // ---- load Q fragments for rows strip*16 + l16 (A-operand layout) ----
    int qr = strip * 16 + l16;
    int qrc = min(qr, WHT - 1);
    const float* qp = qkv + (rowbase + (size_t)qrc * 8) * 1536 + h * 64 + quad * 8;
    BF8 qh[2], ql[2];
#pragma unroll
    for (int st = 0; st < 2; st++) {
      float4 a = *(const float4*)(qp + st * 32);
      float4 c = *(const float4*)(qp + st * 32 + 4);
      float vals[8] = {a.x, a.y, a.z, a.w, c.x, c.y, c.z, c.w};
#pragma unroll
      for (int i = 0; i < 8; i++) {
        float x = vals[i] * 0.125f;
        splitf(x, qh[st].s[i], ql[st].s[i]);
      }
    }

    // ---- S = Q K^T via split MFMA (13 key tiles x 2 k-steps x 3 terms) ----
    floatx4 acc_s[13];
#pragma unroll
    for (int j = 0; j < 13; j++) {
      floatx4 acc = (floatx4){0.f, 0.f, 0.f, 0.f};
#pragma unroll
      for (int st = 0; st < 2; st++) {
        bf16x8 bh = *(const bf16x8*)&Khi[(j * 16 + l16) * 72 + st * 32 + quad * 8];
        bf16x8 bl = *(const bf16x8*)&Klo[(j * 16 + l16) * 72 + st * 32 + quad * 8];
        acc = __builtin_amdgcn_mfma_f32_16x16x32_bf16(qh[st].v, bh, acc, 0, 0, 0);
        acc = __builtin_amdgcn_mfma_f32_16x16x32_bf16(ql[st].v, bh, acc, 0, 0, 0);
        acc = __builtin_amdgcn_mfma_f32_16x16x32_bf16(qh[st].v, bl, acc, 0, 0, 0);
      }
      acc_s[j] = acc;
    }
    // mask invalid key cols 196..207 (tile 12, l16 >= 4)
    if (l16 >= 4) acc_s[12] = (floatx4){-3.4e38f, -3.4e38f, -3.4e38f, -3.4e38f};

    // ---- softmax rows (row = quad*4+p): 13-reg local + 16-lane shfl reduce ----
    float inv4[4];
#pragma unroll
    for (int p = 0; p < 4; p++) {
      float m = acc_s[0][p];
#pragma unroll
      for (int j = 1; j < 13; j++) m = fmaxf(m, acc_s[j][p]);
#pragma unroll
      for (int o = 8; o >= 1; o >>= 1) m = fmaxf(m, __shfl_xor(m, o, 64));
      float s = 0.f;
#pragma unroll
      for (int j = 0; j < 13; j++) {
        float e = __expf(acc_s[j][p] - m);
        acc_s[j][p] = e;
        s += e;
      }
#pragma unroll
      for (int o = 8; o >= 1; o >>= 1) s += __shfl_xor(s, o, 64);
      inv4[p] = 1.f / s;
    }

    // ---- write P (tiles 0..11) to per-wave strip as packed hi|lo u32 ----
#pragma unroll
    for (int j = 0; j < 12; j++) {
#pragma unroll
      for (int p = 0; p < 4; p++) {
        float e = acc_s[j][p];
        unsigned u = __float_as_uint(e);
        unsigned hs = u >> 16;
        float rem = e - __uint_as_float(hs << 16);
        unsigned ls = f2bf(rem);
        myP[(quad * 4 + p) * 196 + j * 16 + l16] = hs | (ls << 16);
      }
    }

    // ---- O = P V via split MFMA (6 k-steps x 4 d-tiles x 3 terms) ----
    floatx4 acc_o[4];
#pragma unroll
    for (int jn = 0; jn < 4; jn++) acc_o[jn] = (floatx4){0.f, 0.f, 0.f, 0.f};
#pragma unroll
    for (int s = 0; s < 6; s++) {
      const unsigned int* pp = &myP[l16 * 196 + s * 32 + quad * 8];
      uint4 u0 = *(const uint4*)pp;
      uint4 u1 = *(const uint4*)(pp + 4);
      BF8 AH, AL;
      AH.u[0] = (u0.x & 0xffffu) | (u0.y << 16);
      AH.u[1] = (u0.z & 0xffffu) | (u0.w << 16);
      AH.u[2] = (u1.x & 0xffffu) | (u1.y << 16);
      AH.u[3] = (u1.z & 0xffffu) | (u1.w << 16);
      AL.u[0] = (u0.x >> 16) | (u0.y & 0xffff0000u);
      AL.u[1] = (u0.z >> 16) | (u0.w & 0xffff0000u);
      AL.u[2] = (u1.x >> 16) | (u1.y & 0xffff0000u);
      AL.u[3] = (u1.z >> 16) | (u1.w & 0xffff0000u);
#pragma unroll
      for (int jn = 0; jn < 4; jn++) {
        bf16x8 bh = *(const bf16x8*)&Vthi[(jn * 16 + l16) * 200 + s * 32 + quad * 8];
        bf16x8 bl = *(const bf16x8*)&Vtlo[(jn * 16 + l16) * 200 + s * 32 + quad * 8];
        acc_o[jn] = __builtin_amdgcn_mfma_f32_16x16x32_bf16(AH.v, bh, acc_o[jn], 0, 0, 0);
        acc_o[jn] = __builtin_amdgcn_mfma_f32_16x16x32_bf16(AL.v, bh, acc_o[jn], 0, 0, 0);
        acc_o[jn] = __builtin_amdgcn_mfma_f32_16x16x32_bf16(AH.v, bl, acc_o[jn], 0, 0, 0);
      }
    }
    // ---- tail keys 192..195: e still in acc_s[12], broadcast within quad ----
#pragma unroll
    for (int kk = 0; kk < 4; kk++) {
      int srcl = (lane & 48) + kk;
      float e0 = __shfl(acc_s[12][0], srcl, 64);
      float e1 = __shfl(acc_s[12][1], srcl, 64);
      float e2 = __shfl(acc_s[12][2], srcl, 64);
      float e3 = __shfl(acc_s[12][3], srcl, 64);
#pragma unroll
      for (int jn = 0; jn < 4; jn++) {
        int d = jn * 16 + l16;
        float v = bf2f(Vthi[d * 200 + 192 + kk]) + bf2f(Vtlo[d * 200 + 192 + kk]);
        acc_o[jn][0] += e0 * v;
        acc_o[jn][1] += e1 * v;
        acc_o[jn][2] += e2 * v;
        acc_o[jn][3] += e3 * v;
      }
    }

    // ---- store O (normalized) ----
#pragma unroll
    for (int jn = 0; jn < 4; jn++) {
#pragma unroll
      for (int p = 0; p < 4; p++) {
        int qrow = strip * 16 + quad * 4 + p;
        if (qrow < WHT)
          outA[((size_t)(1 + tq * WHT + qrow) * 8 + b) * CC + h * 64 + jn * 16 + l16] =
              acc_o[jn][p] * inv4[p];
      }
    }
  }
}

// ---------------------------------------------------------------------------
// Final LN (token 0 only) + classifier head
// ---------------------------------------------------------------------------
__global__ __launch_bounds__(256)
void head_kernel(const float* __restrict__ X, const float* __restrict__ enw,
                 const float* __restrict__ enb, const float* __restrict__ fcw,
                 const float* __restrict__ fcb, float* __restrict__ out) {
  __shared__ float nx[512];
  __shared__ float red[8];
  const int b = blockIdx.x, tid = threadIdx.x;
  const float* x = X + (size_t)b * CC;
  float v0 = x[tid], v1 = x[tid + 256];
  float s = wave_reduce_sum(v0 + v1);
  if ((tid & 63) == 0) red[tid >> 6] = s;
  __syncthreads();
  float mean = (red[0] + red[1] + red[2] + red[3]) * (1.f / 512.f);
  float d0 = v0 - mean, d1 = v1 - mean;
  float vs = wave_reduce_sum(d0 * d0 + d1 * d1);
  if ((tid & 63) == 0) red[4 + (tid >> 6)] = vs;
  __syncthreads();
  float var = (red[4] + red[5] + red[6] + red[7]) * (1.f / 512.f);
  float inv = 1.0f / sqrtf(var + 1e-5f);
  nx[tid] = d0 * inv * enw[tid] + enb[tid];
  nx[tid + 256] = d1 * inv * enw[tid + 256] + enb[tid + 256];
  __syncthreads();
  if (tid < NCLS) {
    float acc = fcb[tid];
    for (int c = 0; c < 512; c++) acc += nx[c] * fcw[c * NCLS + tid];
    out[b * NCLS + tid] = acc;
  }
}

// ---------------------------------------------------------------------------
extern "C" void kernel_launch(void* const* d_in, const int* in_sizes, int n_in,
                              void* d_out, int out_size, void* d_ws, size_t ws_size,
                              hipStream_t stream) {
  (void)in_sizes; (void)n_in; (void)out_size; (void)ws_size;
  const float* src  = (const float*)d_in[0];
  const float* cw   = (const float*)d_in[1];
  const float* cb   = (const float*)d_in[2];
  const float* clst = (const float*)d_in[3];
  const float* pos  = (const float*)d_in[4];
  const float* Wt   = (const float*)d_in[5];
  const float* bt   = (const float*)d_in[6];
  const float* Wsp  = (const float*)d_in[7];
  const float* bsp  = (const float*)d_in[8];
  const float* Wo   = (const float*)d_in[9];
  const float* bo   = (const float*)d_in[10];
  const float* n1w  = (const float*)d_in[11];
  const float* n1b  = (const float*)d_in[12];
  const float* n2w  = (const float*)d_in[13];
  const float* n2b  = (const float*)d_in[14];
  const float* W1   = (const float*)d_in[15];
  const float* b1   = (const float*)d_in[16];
  const float* W2   = (const float*)d_in[17];
  const float* b2   = (const float*)d_in[18];
  const float* enw  = (const float*)d_in[19];
  const float* enb  = (const float*)d_in[20];
  const float* fcw  = (const float*)d_in[21];
  const float* fcb  = (const float*)d_in[22];

  float* ws = (float*)d_ws;
  const size_t TOKR = (size_t)3137 * 8;
  float* X0  = ws;                              // TOKR*512
  float* Ab  = X0 + TOKR * 512;                 // TOKR*512
  float* QKV = Ab + TOKR * 512;                 // TOKR*1536 (also FFN mid / im2col)
  float* CLS = QKV + TOKR * 1536;               // 8*512
  int*   IDX = (int*)(CLS + 8 * 512);           // 8*8*196*16 ints
  unsigned short* WT1 = (unsigned short*)(IDX + 8 * 8 * WHT * 16);  // 2048*512
  unsigned short* WT2 = WT1 + 2048 * 512;                           // 2048*512
  float* PART = (float*)(WT2 + 2048 * 512);     // 64*CA_NCH*68

  // A-planes for split GEMMs (aliased into Ab / QKV; same total bytes).
  unsigned short* Ahi = (unsigned short*)Ab;
  unsigned short* Alo = Ahi + TOKR * 512;
  unsigned short* IMhi = (unsigned short*)QKV;
  unsigned short* IMlo = IMhi + (size_t)25088 * 768;

  // Patch embed as im2col(split) + split-bf16 MFMA GEMM (M=25088,N=512,K=768).
  wsplit_flat_kernel<<<(512 * 768 + 255) / 256, 256, 0, stream>>>(
      cw, WT1, WT2, 512 * 768);
  im2col_split_kernel<<<(25088 * 192) / 256, 256, 0, stream>>>(src, IMhi, IMlo);
  mfma_gemm3s_kernel<<<dim3(4, 25088 / 128), 256, 0, stream>>>(
      IMhi, IMlo, WT1, WT2, cb, X0 + 8 * CC, 25088, 512, 768);
  cls_init_kernel<<<8, 512, 0, stream>>>(clst, X0);

  float* Xc = X0;
  int t = 16;
  const int FFN_CHUNK = 16384;
  for (int i = 0; i < 6; i++) {
    const int pk = (i & 1) ? 2 : 0;
    const int tp = t - pk;
    const int L = 1 + t * WHT;
    const int Lo = 1 + tp * WHT;
    const int M = L * 8, Mo = Lo * 8, My = tp * WHT * 8;

    // LN1 with direct bf16 hi/lo split output (feeds only the Wt GEMM)
    ln_split_kernel<<<M, 256, 0, stream>>>(Xc, Ahi, Alo,
                                           n1w + (size_t)i * 512, n1b + (size_t)i * 512,
                                           (i == 0) ? pos : nullptr);
    // sigma-critical Wt: split-bf16 MFMA (hi/lo), fp32-class accuracy
    wtrans_split_kernel<<<dim3(1536 / 32, 512 / 32), 256, 0, stream>>>(
        Wt + (size_t)i * 512 * 1536, WT1, WT2, 1536, 512);
    mfma_gemm3s_kernel<<<dim3(12, (M + 127) / 128), 256, 0, stream>>>(
        Ahi, Alo, WT1, WT2, bt + (size_t)i * 1536, QKV, M, 1536, 512);
    class_attn_part_kernel<<<dim3(64, CA_NCH), 256, 0, stream>>>(QKV, PART, L);
    class_attn_reduce_kernel<<<64, 64, 0, stream>>>(PART, CLS);
    temporal_attn_kernel<<<HH * BB * WHT, 256, 0, stream>>>(QKV, Ab, IDX, t, tp, pk);
    // Ws: plain bf16 MFMA
    wtrans_kernel<<<dim3(1536 / 32, 512 / 32), 256, 0, stream>>>(
        Wsp + (size_t)i * 512 * 1536, WT1, 1536, 512);
    mfma_gemm_kernel<0, 0><<<dim3(12, (My + 127) / 128), 256, 0, stream>>>(
        Ab, WT1, bsp + (size_t)i * 1536, QKV, My, 1536, 512, nullptr);
    copy_cls_kernel<<<8, 512, 0, stream>>>(CLS, Ab);
    spatial_mfma_kernel<<<64 * tp, 256, 0, stream>>>(QKV, Ab);
    if (pk > 0)
      pool_inplace_kernel<<<8 * WHT, 256, 0, stream>>>(Xc, IDX, tp);
    // Wo: plain bf16 MFMA + residual
    wtrans_kernel<<<dim3(512 / 32, 512 / 32), 256, 0, stream>>>(
        Wo + (size_t)i * 512 * 512, WT1, 512, 512);
    mfma_gemm_kernel<0, 1><<<dim3(4, (Mo + 127) / 128), 256, 0, stream>>>(
        Ab, WT1, bo + (size_t)i * 512, Xc, Mo, 512, 512, Xc);
    ln_kernel<<<Mo, 256, 0, stream>>>(Xc, Ab, n2w + (size_t)i * 512, n2b + (size_t)i * 512,
                                      nullptr);
    // FFN: plain bf16 MFMA
    wtrans_kernel<<<dim3(2048 / 32, 512 / 32), 256, 0, stream>>>(
        W1 + (size_t)i * 512 * 2048, WT1, 2048, 512);
    wtrans_kernel<<<dim3(512 / 32, 2048 / 32), 256, 0, stream>>>(
        W2 + (size_t)i * 2048 * 512, WT2, 512, 2048);
    for (int off = 0; off < Mo; off += FFN_CHUNK) {
      int R = Mo - off;
      if (R > FFN_CHUNK) R = FFN_CHUNK;
      mfma_gemm_kernel<1, 0><<<dim3(16, (R + 127) / 128), 256, 0, stream>>>(
          Ab + (size_t)off * 512, WT1, b1 + (size_t)i * 2048, QKV, R, 2048, 512,
          nullptr);
      mfma_gemm_kernel<0, 1><<<dim3(4, (R + 127) / 128), 256, 0, stream>>>(
          QKV, WT2, b2 + (size_t)i * 512, Xc + (size_t)off * 512, R, 512, 2048,
          Xc + (size_t)off * 512);
    }
    t = tp;
  }
  head_kernel<<<8, 256, 0, stream>>>(Xc, enw, enb, fcw, fcb, (float*)d_out);
}

// Round 5
// 5729.025 us; speedup vs baseline: 1.7305x; 1.0491x over previous
//
#include <hip/hip_runtime.h>
#include <math.h>

// ---------------------------------------------------------------------------
// CompactVidTr forward.
//  - All GEMMs: 128x128 tile, BK=64 K-epochs (halved barrier count), 1-D grid
//    with bijective XCD-band swizzle: each XCD owns a contiguous m-band and
//    sweeps n fastest -> A-tiles hit the SAME per-XCD L2 (round-robin dispatch
//    had been spreading the 12 n-blocks of an m-row across 8 private L2s).
//  - Wt/conv GEMM: 3-term split-bf16 MFMA, pre-split A planes; LDS exactly
//    64 KB via XOR-granule swizzle (granule ^= row&7 on write AND read).
//  - Spatial attention: split-bf16 MFMA flash kernel.
//  - Class attention: two-phase flash split over L.
//  - Temporal attention + LN: fp32 vector.
// Layout: token matrices row-major [row = l*B + b][C]; l=0 is cls. B=8, C=512.
//
// Workspace (262.5 MB < 268.4 MB): X, Ab(split planes), QKV, CLS, IDX,
//   WT1/WT2 (2048*512 bf16 each), PART.
// ---------------------------------------------------------------------------

#define BB 8
#define CC 512
#define HH 8
#define HD 64
#define WHT 196
#define NCLS 157
#define CA_NCH 32

typedef short bf16x8 __attribute__((ext_vector_type(8)));
typedef float floatx4 __attribute__((ext_vector_type(4)));

__device__ __forceinline__ unsigned short f2bf(float f) {
  unsigned u = __float_as_uint(f);
  unsigned r = u + 0x7FFFu + ((u >> 16) & 1u);  // RNE
  return (unsigned short)(r >> 16);
}
__device__ __forceinline__ float bf2f(unsigned short h) {
  return __uint_as_float((unsigned)h << 16);
}
// truncation split: hi = top-16-bits, lo = RNE(residual); reconstruct ~2^-17
__device__ __forceinline__ void splitf(float x, unsigned short& h, unsigned short& l) {
  unsigned u = __float_as_uint(x);
  unsigned hs = u >> 16;
  float rem = x - __uint_as_float(hs << 16);
  h = (unsigned short)hs;
  l = f2bf(rem);
}

__device__ __forceinline__ float wave_reduce_sum(float v) {
#pragma unroll
  for (int o = 32; o > 0; o >>= 1) v += __shfl_down(v, o, 64);
  return v;
}
__device__ __forceinline__ float wave_reduce_max(float v) {
#pragma unroll
  for (int o = 32; o > 0; o >>= 1) v = fmaxf(v, __shfl_down(v, o, 64));
  return v;
}

// Bijective XCD-band decode (m204 variant): blocks with id%8==x run on XCD x;
// give each XCD a contiguous work range, n fastest within an m-row.
__device__ __forceinline__ void xcd_decode(int id, int G, int nt,
                                           int& m0, int& n0) {
  int q8 = G >> 3, r8 = G & 7;
  int xcd = id & 7, j = id >> 3;
  int w = (xcd < r8) ? xcd * (q8 + 1) + j : r8 * (q8 + 1) + (xcd - r8) * q8 + j;
  m0 = (w / nt) * 128;
  n0 = (w % nt) * 128;
}

// ---------------------------------------------------------------------------
// im2col + split: src [8][3][16][224][224] -> IMhi/IMlo [25088][768] bf16.
// ---------------------------------------------------------------------------
__global__ __launch_bounds__(256)
void im2col_split_kernel(const float* __restrict__ src,
                         unsigned short* __restrict__ IMhi,
                         unsigned short* __restrict__ IMlo) {
  int gid = blockIdx.x * 256 + threadIdx.x;
  int k4 = gid % 192;
  int u = gid / 192;
  if (u >= 25088) return;
  int b = u & 7;
  int s = u >> 3;
  int tt = s / WHT;
  int w2 = s % WHT;
  int ph = w2 / 14, pw = w2 % 14;
  int k = k4 * 4;
  int ci = k >> 8;
  int rem = k & 255;
  int py = rem >> 4, px = rem & 15;
  const float* sp = src + (size_t)b * (3 * 16 * 224 * 224) +
                    (size_t)ci * (16 * 224 * 224) + (size_t)tt * (224 * 224) +
                    (size_t)(ph * 16 + py) * 224 + pw * 16 + px;
  float4 v = *(const float4*)sp;
  ushort4 h, l;
  splitf(v.x, h.x, l.x);
  splitf(v.y, h.y, l.y);
  splitf(v.z, h.z, l.z);
  splitf(v.w, h.w, l.w);
  *(ushort4*)(IMhi + (size_t)u * 768 + k) = h;
  *(ushort4*)(IMlo + (size_t)u * 768 + k) = l;
}

__global__ __launch_bounds__(256)
void wsplit_flat_kernel(const float* __restrict__ W,
                        unsigned short* __restrict__ Whi,
                        unsigned short* __restrict__ Wlo, int total) {
  int i = blockIdx.x * 256 + threadIdx.x;
  if (i >= total) return;
  float w = W[i];
  unsigned short hi = f2bf(w);
  Whi[i] = hi;
  Wlo[i] = f2bf(w - bf2f(hi));
}

__global__ void cls_init_kernel(const float* __restrict__ clst, float* __restrict__ X) {
  X[(size_t)blockIdx.x * CC + threadIdx.x] = clst[threadIdx.x];
}

__global__ void copy_cls_kernel(const float* __restrict__ cls, float* __restrict__ A) {
  A[(size_t)blockIdx.x * CC + threadIdx.x] = cls[(size_t)blockIdx.x * CC + threadIdx.x];
}

// ---------------------------------------------------------------------------
// LayerNorm over C=512 (fp32 out); one block per row
// ---------------------------------------------------------------------------
__global__ __launch_bounds__(256)
void ln_kernel(const float* __restrict__ X, float* __restrict__ O,
               const float* __restrict__ w, const float* __restrict__ b,
               const float* __restrict__ pos) {
  __shared__ float red[8];
  const int row = blockIdx.x, tid = threadIdx.x;
  const float* x = X + (size_t)row * CC;
  float v0 = x[tid], v1 = x[tid + 256];
  float s = wave_reduce_sum(v0 + v1);
  if ((tid & 63) == 0) red[tid >> 6] = s;
  __syncthreads();
  float mean = (red[0] + red[1] + red[2] + red[3]) * (1.f / 512.f);
  float d0 = v0 - mean, d1 = v1 - mean;
  float vs = wave_reduce_sum(d0 * d0 + d1 * d1);
  if ((tid & 63) == 0) red[4 + (tid >> 6)] = vs;
  __syncthreads();
  float var = (red[4] + red[5] + red[6] + red[7]) * (1.f / 512.f);
  float inv = 1.0f / sqrtf(var + 1e-5f);
  float o0 = d0 * inv * w[tid] + b[tid];
  float o1 = d1 * inv * w[tid + 256] + b[tid + 256];
  if (pos) {
    const float* pr = pos + (size_t)(row >> 3) * CC;
    o0 += pr[tid];
    o1 += pr[tid + 256];
  }
  O[(size_t)row * CC + tid] = o0;
  O[(size_t)row * CC + tid + 256] = o1;
}

// ---------------------------------------------------------------------------
// LayerNorm + split-bf16 output (hi/lo planes) — feeds the Wt split GEMM.
// ---------------------------------------------------------------------------
__global__ __launch_bounds__(256)
void ln_split_kernel(const float* __restrict__ X,
                     unsigned short* __restrict__ Ahi,
                     unsigned short* __restrict__ Alo,
                     const float* __restrict__ w, const float* __restrict__ b,
                     const float* __restrict__ pos) {
  __shared__ float red[8];
  const int row = blockIdx.x, tid = threadIdx.x;
  const float* x = X + (size_t)row * CC;
  float v0 = x[tid], v1 = x[tid + 256];
  float s = wave_reduce_sum(v0 + v1);
  if ((tid & 63) == 0) red[tid >> 6] = s;
  __syncthreads();
  float mean = (red[0] + red[1] + red[2] + red[3]) * (1.f / 512.f);
  float d0 = v0 - mean, d1 = v1 - mean;
  float vs = wave_reduce_sum(d0 * d0 + d1 * d1);
  if ((tid & 63) == 0) red[4 + (tid >> 6)] = vs;
  __syncthreads();
  float var = (red[4] + red[5] + red[6] + red[7]) * (1.f / 512.f);
  float inv = 1.0f / sqrtf(var + 1e-5f);
  float o0 = d0 * inv * w[tid] + b[tid];
  float o1 = d1 * inv * w[tid + 256] + b[tid + 256];
  if (pos) {
    const float* pr = pos + (size_t)(row >> 3) * CC;
    o0 += pr[tid];
    o1 += pr[tid + 256];
  }
  unsigned short h, l;
  splitf(o0, h, l);
  Ahi[(size_t)row * CC + tid] = h;
  Alo[(size_t)row * CC + tid] = l;
  splitf(o1, h, l);
  Ahi[(size_t)row * CC + tid + 256] = h;
  Alo[(size_t)row * CC + tid + 256] = l;
}

// ---------------------------------------------------------------------------
// Weight transpose + fp32->bf16 (plain): W [K][N] -> WT [N][K]
// ---------------------------------------------------------------------------
__global__ __launch_bounds__(256)
void wtrans_kernel(const float* __restrict__ W, unsigned short* __restrict__ WT,
                   int N, int K) {
  __shared__ float tile[32][33];
  const int tid = threadIdx.x;
  const int tx = tid & 31, ty = tid >> 5;
  const int n0 = blockIdx.x * 32, k0 = blockIdx.y * 32;
#pragma unroll
  for (int r = 0; r < 4; r++) {
    int kk = ty + r * 8;
    tile[kk][tx] = W[(size_t)(k0 + kk) * N + n0 + tx];
  }
  __syncthreads();
#pragma unroll
  for (int r = 0; r < 4; r++) {
    int nn = ty + r * 8;
    WT[(size_t)(n0 + nn) * K + k0 + tx] = f2bf(tile[tx][nn]);
  }
}

// ---------------------------------------------------------------------------
// Weight transpose + split fp32 -> (hi, lo) bf16: W [K][N] -> WThi/WTlo [N][K]
// ---------------------------------------------------------------------------
__global__ __launch_bounds__(256)
void wtrans_split_kernel(const float* __restrict__ W,
                         unsigned short* __restrict__ WThi,
                         unsigned short* __restrict__ WTlo, int N, int K) {
  __shared__ float tile[32][33];
  const int tid = threadIdx.x;
  const int tx = tid & 31, ty = tid >> 5;
  const int n0 = blockIdx.x * 32, k0 = blockIdx.y * 32;
#pragma unroll
  for (int r = 0; r < 4; r++) {
    int kk = ty + r * 8;
    tile[kk][tx] = W[(size_t)(k0 + kk) * N + n0 + tx];
  }
  __syncthreads();
#pragma unroll
  for (int r = 0; r < 4; r++) {
    int nn = ty + r * 8;
    float w = tile[tx][nn];
    unsigned short hi = f2bf(w);
    unsigned short lo = f2bf(w - bf2f(hi));
    WThi[(size_t)(n0 + nn) * K + k0 + tx] = hi;
    WTlo[(size_t)(n0 + nn) * K + k0 + tx] = lo;
  }
}

// ---------------------------------------------------------------------------
// Plain bf16 MFMA GEMM: C = A(M,K) @ W(K,N) + bias [+relu] [+residual]
// BK=64 epochs; LDS rows padded to 68 shorts (stride 34 dwords -> no bank
// conflicts on ds_read_b128). 1-D grid + XCD-band decode.
// ---------------------------------------------------------------------------
template <int RELU, int RES>
__global__ __launch_bounds__(256)
void mfma_gemm_kernel(const float* __restrict__ A,
                      const unsigned short* __restrict__ WT,
                      const float* __restrict__ bias, float* __restrict__ Cout,
                      int M, int N, int K, const float* __restrict__ resid) {
  __shared__ unsigned short AsU[128 * 68];
  __shared__ unsigned short BsU[128 * 68];
  const int tid = threadIdx.x;
  const int wave = tid >> 6, lane = tid & 63;
  const int quad = lane >> 4, l16 = lane & 15;
  const int wrow = (wave >> 1) * 64, wcol = (wave & 1) * 64;
  int m0, n0;
  xcd_decode(blockIdx.x, gridDim.x, N >> 7, m0, n0);

  floatx4 acc[4][4];
#pragma unroll
  for (int i = 0; i < 4; i++)
#pragma unroll
    for (int j = 0; j < 4; j++) acc[i][j] = (floatx4){0.f, 0.f, 0.f, 0.f};

  for (int k0 = 0; k0 < K; k0 += 64) {
#pragma unroll
    for (int r = 0; r < 8; r++) {
      int row = (tid >> 4) + r * 16;
      int c4 = (tid & 15) * 4;
      int gm = m0 + row;
      float4 v = make_float4(0.f, 0.f, 0.f, 0.f);
      if (gm < M) v = *(const float4*)(A + (size_t)gm * K + k0 + c4);
      ushort4 o;
      o.x = f2bf(v.x); o.y = f2bf(v.y); o.z = f2bf(v.z); o.w = f2bf(v.w);
      *(ushort4*)&AsU[row * 68 + c4] = o;
    }
#pragma unroll
    for (int r = 0; r < 4; r++) {
      int n = (tid >> 3) + r * 32;
      int g = tid & 7;
      uint4 w = *(const uint4*)(WT + (size_t)(n0 + n) * K + k0 + g * 8);
      *(uint4*)&BsU[n * 68 + g * 8] = w;
    }
    __syncthreads();
#pragma unroll
    for (int st = 0; st < 2; st++) {
      bf16x8 af[4], bf[4];
#pragma unroll
      for (int i = 0; i < 4; i++)
        af[i] = *(const bf16x8*)&AsU[(wrow + i * 16 + l16) * 68 + st * 32 + quad * 8];
#pragma unroll
      for (int j = 0; j < 4; j++)
        bf[j] = *(const bf16x8*)&BsU[(wcol + j * 16 + l16) * 68 + st * 32 + quad * 8];
#pragma unroll
      for (int i = 0; i < 4; i++)
#pragma unroll
        for (int j = 0; j < 4; j++)
          acc[i][j] = __builtin_amdgcn_mfma_f32_16x16x32_bf16(af[i], bf[j],
                                                              acc[i][j], 0, 0, 0);
    }
    __syncthreads();
  }
#pragma unroll
  for (int i = 0; i < 4; i++) {
#pragma unroll
    for (int p = 0; p < 4; p++) {
      int gm = m0 + wrow + i * 16 + quad * 4 + p;
      if (gm >= M) continue;
#pragma unroll
      for (int j = 0; j < 4; j++) {
        int gn = n0 + wcol + j * 16 + l16;
        float v = acc[i][j][p] + bias[gn];
        if (RELU) v = fmaxf(v, 0.f);
        if (RES == 1) v += resid[(size_t)gm * N + gn];
        Cout[(size_t)gm * N + gn] = v;
      }
    }
  }
}

// ---------------------------------------------------------------------------
// Split-bf16 MFMA GEMM, pre-split A planes. BK=64; LDS = 4 x 16 KB = 64 KB
// exactly, bank-conflict-free via XOR-granule swizzle: 16-B granule g of row
// r is stored at g^(r&7) and read back at (st*4+quad)^(r&7).
// ---------------------------------------------------------------------------
__global__ __launch_bounds__(256)
void mfma_gemm3s_kernel(const unsigned short* __restrict__ Ahi,
                        const unsigned short* __restrict__ Alo,
                        const unsigned short* __restrict__ WThi,
                        const unsigned short* __restrict__ WTlo,
                        const float* __restrict__ bias, float* __restrict__ Cout,
                        int M, int N, int K) {
  __shared__ unsigned short AsHi[128 * 64];
  __shared__ unsigned short AsLo[128 * 64];
  __shared__ unsigned short BsHi[128 * 64];
  __shared__ unsigned short BsLo[128 * 64];
  const int tid = threadIdx.x;
  const int wave = tid >> 6, lane = tid & 63;
  const int quad = lane >> 4, l16 = lane & 15;
  const int wrow = (wave >> 1) * 64, wcol = (wave & 1) * 64;
  int m0, n0;
  xcd_decode(blockIdx.x, gridDim.x, N >> 7, m0, n0);

  floatx4 acc[4][4];
#pragma unroll
  for (int i = 0; i < 4; i++)
#pragma unroll
    for (int j = 0; j < 4; j++) acc[i][j] = (floatx4){0.f, 0.f, 0.f, 0.f};

  for (int k0 = 0; k0 < K; k0 += 64) {
#pragma unroll
    for (int r = 0; r < 4; r++) {
      int row = (tid >> 3) + r * 32;
      int g = tid & 7;
      int dst = row * 64 + ((g ^ (row & 7)) * 8);
      int gm = m0 + row;
      uint4 vh = make_uint4(0u, 0u, 0u, 0u), vl = make_uint4(0u, 0u, 0u, 0u);
      if (gm < M) {
        vh = *(const uint4*)(Ahi + (size_t)gm * K + k0 + g * 8);
        vl = *(const uint4*)(Alo + (size_t)gm * K + k0 + g * 8);
      }
      *(uint4*)&AsHi[dst] = vh;
      *(uint4*)&AsLo[dst] = vl;
      uint4 wh = *(const uint4*)(WThi + (size_t)(n0 + row) * K + k0 + g * 8);
      uint4 wl = *(const uint4*)(WTlo + (size_t)(n0 + row) * K + k0 + g * 8);
      *(uint4*)&BsHi[dst] = wh;
      *(uint4*)&BsLo[dst] = wl;
    }
    __syncthreads();
#pragma unroll
    for (int st = 0; st < 2; st++) {
      bf16x8 ah[4], al[4], bh[4], bl[4];
#pragma unroll
      for (int i = 0; i < 4; i++) {
        int ra = wrow + i * 16 + l16;
        int offa = ra * 64 + (((st * 4 + quad) ^ (ra & 7)) * 8);
        ah[i] = *(const bf16x8*)&AsHi[offa];
        al[i] = *(const bf16x8*)&AsLo[offa];
        int rb = wcol + i * 16 + l16;
        int offb = rb * 64 + (((st * 4 + quad) ^ (rb & 7)) * 8);
        bh[i] = *(const bf16x8*)&BsHi[offb];
        bl[i] = *(const bf16x8*)&BsLo[offb];
      }
#pragma unroll
      for (int i = 0; i < 4; i++)
#pragma unroll
        for (int j = 0; j < 4; j++) {
          acc[i][j] = __builtin_amdgcn_mfma_f32_16x16x32_bf16(ah[i], bh[j],
                                                              acc[i][j], 0, 0, 0);
          acc[i][j] = __builtin_amdgcn_mfma_f32_16x16x32_bf16(ah[i], bl[j],
                                                              acc[i][j], 0, 0, 0);
          acc[i][j] = __builtin_amdgcn_mfma_f32_16x16x32_bf16(al[i], bh[j],
                                                              acc[i][j], 0, 0, 0);
        }
    }
    __syncthreads();
  }
#pragma unroll
  for (int i = 0; i < 4; i++) {
#pragma unroll
    for (int p = 0; p < 4; p++) {
      int gm = m0 + wrow + i * 16 + quad * 4 + p;
      if (gm >= M) continue;
#pragma unroll
      for (int j = 0; j < 4; j++) {
        int gn = n0 + wcol + j * 16 + l16;
        Cout[(size_t)gm * N + gn] = acc[i][j][p] + bias[gn];
      }
    }
  }
}

// ---------------------------------------------------------------------------
// Class attention, phase 1: per-(h,b) x per-chunk partial flash softmax.
// ---------------------------------------------------------------------------
__global__ __launch_bounds__(256)
void class_attn_part_kernel(const float* __restrict__ qkv,
                            float* __restrict__ part, int L) {
  __shared__ float q[64];
  __shared__ float sc[128];
  __shared__ float red[8];
  __shared__ float pv[256];
  const int h = blockIdx.x & 7, b = blockIdx.x >> 3;
  const int chunk = blockIdx.y;
  const int tid = threadIdx.x;
  const int per = (L + CA_NCH - 1) / CA_NCH;
  const int l0 = chunk * per;
  const int nl = min(L - l0, per);
  if (tid < 64) q[tid] = qkv[(size_t)b * 1536 + h * 64 + tid] * 0.125f;
  __syncthreads();
  float lmax = -3.4e38f;
  for (int i = tid; i < nl; i += 256) {
    const float* kr = qkv + (size_t)((l0 + i) * 8 + b) * 1536 + 512 + h * 64;
    float s = 0;
#pragma unroll
    for (int d2 = 0; d2 < 64; d2 += 4) {
      float4 k4 = *(const float4*)(kr + d2);
      s += q[d2] * k4.x + q[d2 + 1] * k4.y + q[d2 + 2] * k4.z + q[d2 + 3] * k4.w;
    }
    sc[i] = s;
    lmax = fmaxf(lmax, s);
  }
  lmax = wave_reduce_max(lmax);
  if ((tid & 63) == 0) red[tid >> 6] = lmax;
  __syncthreads();
  float gmax = fmaxf(fmaxf(red[0], red[1]), fmaxf(red[2], red[3]));
  float lsum = 0;
  for (int i = tid; i < nl; i += 256) {
    float e = expf(sc[i] - gmax);
    sc[i] = e;
    lsum += e;
  }
  lsum = wave_reduce_sum(lsum);
  if ((tid & 63) == 0) red[4 + (tid >> 6)] = lsum;
  __syncthreads();
  float gsum = red[4] + red[5] + red[6] + red[7];
  const int g = tid >> 6, d = tid & 63;
  float acc = 0;
  for (int i = g; i < nl; i += 4)
    acc += sc[i] * qkv[(size_t)((l0 + i) * 8 + b) * 1536 + 1024 + h * 64 + d];
  pv[g * 64 + d] = acc;
  __syncthreads();
  float* rec = part + ((size_t)blockIdx.x * CA_NCH + chunk) * 68;
  if (tid == 0) {
    rec[0] = gmax;
    rec[1] = gsum;
  }
  if (g == 0) rec[2 + d] = pv[d] + pv[64 + d] + pv[128 + d] + pv[192 + d];
}

// ---------------------------------------------------------------------------
// Class attention, phase 2: combine CA_NCH partials per (h,b).
// ---------------------------------------------------------------------------
__global__ __launch_bounds__(64)
void class_attn_reduce_kernel(const float* __restrict__ part,
                              float* __restrict__ cls) {
  const int hb = blockIdx.x;  // (b<<3)|h
  const int tid = threadIdx.x;
  const float* prec = part + (size_t)hb * CA_NCH * 68;
  float M = -3.4e38f;
#pragma unroll
  for (int c = 0; c < CA_NCH; c++) M = fmaxf(M, prec[c * 68]);
  float total = 0.f, acc = 0.f;
#pragma unroll
  for (int c = 0; c < CA_NCH; c++) {
    float w = expf(prec[c * 68] - M);
    total += prec[c * 68 + 1] * w;
    acc += prec[c * 68 + 2 + tid] * w;
  }
  int h = hb & 7, b = hb >> 3;
  cls[b * CC + h * 64 + tid] = acc / total;
}

// ---------------------------------------------------------------------------
// Temporal attention + sigma top-k pooling (fp32 — rank-critical).
// ---------------------------------------------------------------------------
__global__ __launch_bounds__(256)
void temporal_attn_kernel(const float* __restrict__ qkv, float* __restrict__ Y,
                          int* __restrict__ idxbuf, int t, int tp, int pk) {
  __shared__ float qs[16 * 65], ks[16 * 65], vs[16 * 65];
  __shared__ float a[16 * 17];
  __shared__ float sig[16];
  __shared__ int keepf[16];
  __shared__ int klist[16];
  const int g = blockIdx.x;
  const int w = g % WHT;
  const int bb = (g / WHT) & 7;
  const int h = g / (WHT * 8);
  const int tid = threadIdx.x;
  const int td = t * 64;
  for (int e = tid; e < td; e += 256) {
    int tt = e >> 6, d = e & 63;
    size_t rb = (size_t)((1 + tt * WHT + w) * 8 + bb) * 1536 + h * 64 + d;
    qs[tt * 65 + d] = qkv[rb] * 0.125f;
    ks[tt * 65 + d] = qkv[rb + 512];
    vs[tt * 65 + d] = qkv[rb + 1024];
  }
  __syncthreads();
  if (tid < t * t) {
    int qi = tid / t, ki = tid % t;
    const float* qp = &qs[qi * 65];
    const float* kp = &ks[ki * 65];
    float s = 0;
#pragma unroll 8
    for (int d2 = 0; d2 < 64; d2++) s += qp[d2] * kp[d2];
    a[qi * 17 + ki] = s;
  }
  __syncthreads();
  if (tid < t) {
    float* row = &a[tid * 17];
    float m = row[0];
    for (int k2 = 1; k2 < t; k2++) m = fmaxf(m, row[k2]);
    float sum = 0;
    for (int k2 = 0; k2 < t; k2++) {
      float e2 = expf(row[k2] - m);
      row[k2] = e2;
      sum += e2;
    }
    float inv = 1.f / sum;
    for (int k2 = 0; k2 < t; k2++) row[k2] *= inv;
  }
  __syncthreads();
  if (pk > 0) {
    if (tid < t) {
      const float* row = &a[tid * 17];
      float mean = 0;
      for (int k2 = 0; k2 < t; k2++) mean += row[k2];
      mean /= (float)t;
      float var = 0;
      for (int k2 = 0; k2 < t; k2++) {
        float dl = row[k2] - mean;
        var += dl * dl;
      }
      var /= (float)(t - 1);
      sig[tid] = sqrtf(var);
    }
    __syncthreads();
    if (tid < t) {
      float sv = sig[tid];
      int r = 0;
      for (int q2 = 0; q2 < t; q2++) {
        float so = sig[q2];
        if (so > sv || (so == sv && q2 < tid)) r++;
      }
      keepf[tid] = (r < tp) ? 1 : 0;
    }
    __syncthreads();
    if (tid < t && keepf[tid]) {
      int ppos = 0;
      for (int q2 = 0; q2 < tid; q2++) ppos += keepf[q2];
      klist[ppos] = tid;
      idxbuf[((h * 8 + bb) * WHT + w) * 16 + ppos] = tid;
    }
  } else {
    if (tid < t) klist[tid] = tid;
  }
  __syncthreads();
  const int gq = tid >> 6, d = tid & 63;
  for (int qi = gq; qi < tp; qi += 4) {
    int qq = klist[qi];
    const float* arow = &a[qq * 17];
    float acc = 0;
    for (int k2 = 0; k2 < t; k2++) acc += arow[k2] * vs[k2 * 65 + d];
    Y[(size_t)((qi * WHT + w) * 8 + bb) * CC + h * 64 + d] = acc;
  }
}

// ---------------------------------------------------------------------------
// In-place temporal pooling of the residual stream X.
// ---------------------------------------------------------------------------
__global__ __launch_bounds__(256)
void pool_inplace_kernel(float* __restrict__ X, const int* __restrict__ idxbuf,
                         int tp) {
  const int b = blockIdx.x & 7;
  const int w = blockIdx.x >> 3;
  const int tid = threadIdx.x;
  const int c0 = tid, c1 = tid + 256;
  const int h0 = c0 >> 6, h1 = c1 >> 6;
  const int ib0 = ((h0 * 8 + b) * WHT + w) * 16;
  const int ib1 = ((h1 * 8 + b) * WHT + w) * 16;
  for (int q = 0; q < tp; q++) {
    int s0 = idxbuf[ib0 + q];
    int s1 = idxbuf[ib1 + q];
    size_t drow = (size_t)((1 + q * WHT + w) * 8 + b) * CC;
    if (s0 != q) {
      size_t srow = (size_t)((1 + s0 * WHT + w) * 8 + b) * CC;
      X[drow + c0] = X[srow + c0];
    }
    if (s1 != q) {
      size_t srow = (size_t)((1 + s1 * WHT + w) * 8 + b) * CC;
      X[drow + c1] = X[srow + c1];
    }
  }
}

// ---------------------------------------------------------------------------
// Spatial attention, split-bf16 MFMA flash kernel.
// ---------------------------------------------------------------------------
__global__ __launch_bounds__(256)
void spatial_mfma_kernel(const float* __restrict__ qkv, float* __restrict__ outA) {
  __shared__ unsigned short Khi[208 * 72];
  __shared__ unsigned short Klo[208 * 72];
  __shared__ unsigned short Vthi[64 * 200];
  __shared__ unsigned short Vtlo[64 * 200];
  __shared__ unsigned int Ps[4][16 * 196];
  const int blk = blockIdx.x;
  const int h = blk & 7;
  const int b = (blk >> 3) & 7;
  const int tq = blk >> 6;
  const int tid = threadIdx.x;
  const int wave = tid >> 6, lane = tid & 63;
  const int quad = lane >> 4, l16 = lane & 15;
  const size_t rowbase = (size_t)(tq * WHT) * 8 + b;  // qkv row for w=0

  union BF8 { bf16x8 v; unsigned short s[8]; unsigned int u[4]; };

  // ---- stage K (hi/lo) and V (transposed hi/lo) ----
  for (int r = tid >> 4; r < WHT; r += 16) {
    int c = (tid & 15) * 4;
    const float* gk = qkv + (rowbase + (size_t)r * 8) * 1536 + 512 + h * 64 + c;
    float4 kv = *(const float4*)gk;
    ushort4 khs, kls;
    splitf(kv.x, khs.x, kls.x);
    splitf(kv.y, khs.y, kls.y);
    splitf(kv.z, khs.z, kls.z);
    splitf(kv.w, khs.w, kls.w);
    *(ushort4*)&Khi[r * 72 + c] = khs;
    *(ushort4*)&Klo[r * 72 + c] = kls;
    const float* gv = qkv + (rowbase + (size_t)r * 8) * 1536 + 1024 + h * 64 + c;
    float4 vv = *(const float4*)gv;
    unsigned short vh, vl;
    splitf(vv.x, vh, vl); Vthi[(c + 0) * 200 + r] = vh; Vtlo[(c + 0) * 200 + r] = vl;
    splitf(vv.y, vh, vl); Vthi[(c + 1) * 200 + r] = vh; Vtlo[(c + 1) * 200 + r] = vl;
    splitf(vv.z, vh, vl); Vthi[(c + 2) * 200 + r] = vh; Vtlo[(c + 2) * 200 + r] = vl;
    splitf(vv.w, vh, vl); Vthi[(c + 3) * 200 + r] = vh; Vtlo[(c + 3) * 200 + r] = vl;
  }
  __syncthreads();

  unsigned int* myP = &Ps[wave][0];

  for (int strip = wave; strip < 13; strip += 4) {
    // ---- load Q fragments for rows strip*16 + l16 (A-operand layout) ----
    int qr = strip * 16 + l16;
    int qrc = min(qr, WHT - 1);
    const float* qp = qkv + (rowbase + (size_t)qrc * 8) * 1536 + h * 64 + quad * 8;
    BF8 qh[2], ql[2];
#pragma unroll
    for (int st = 0; st < 2; st++) {
      float4 a = *(const float4*)(qp + st * 32);
      float4 c = *(const float4*)(qp + st * 32 + 4);
      float vals[8] = {a.x, a.y, a.z, a.w, c.x, c.y, c.z, c.w};
#pragma unroll
      for (int i = 0; i < 8; i++) {
        float x = vals[i] * 0.125f;
        splitf(x, qh[st].s[i], ql[st].s[i]);
      }
    }

    // ---- S = Q K^T via split MFMA (13 key tiles x 2 k-steps x 3 terms) ----
    floatx4 acc_s[13];
#pragma unroll
    for (int j = 0; j < 13; j++) {
      floatx4 acc = (floatx4){0.f, 0.f, 0.f, 0.f};
#pragma unroll
      for (int st = 0; st < 2; st++) {
        bf16x8 bh = *(const bf16x8*)&Khi[(j * 16 + l16) * 72 + st * 32 + quad * 8];
        bf16x8 bl = *(const bf16x8*)&Klo[(j * 16 + l16) * 72 + st * 32 + quad * 8];
        acc = __builtin_amdgcn_mfma_f32_16x16x32_bf16(qh[st].v, bh, acc, 0, 0, 0);
        acc = __builtin_amdgcn_mfma_f32_16x16x32_bf16(ql[st].v, bh, acc, 0, 0, 0);
        acc = __builtin_amdgcn_mfma_f32_16x16x32_bf16(qh[st].v, bl, acc, 0, 0, 0);
      }
      acc_s[j] = acc;
    }
    // mask invalid key cols 196..207 (tile 12, l16 >= 4)
    if (l16 >= 4) acc_s[12] = (floatx4){-3.4e38f, -3.4e38f, -3.4e38f, -3.4e38f};

    // ---- softmax rows (row = quad*4+p): 13-reg local + 16-lane shfl reduce ----
    float inv4[4];
#pragma unroll
    for (int p = 0; p < 4; p++) {
      float m = acc_s[0][p];
#pragma unroll
      for (int j = 1; j < 13; j++) m = fmaxf(m, acc_s[j][p]);
#pragma unroll
      for (int o = 8; o >= 1; o >>= 1) m = fmaxf(m, __shfl_xor(m, o, 64));
      float s = 0.f;
#pragma unroll
      for (int j = 0; j < 13; j++) {
        float e = __expf(acc_s[j][p] - m);
        acc_s[j][p] = e;
        s += e;
      }
#pragma unroll
      for (int o = 8; o >= 1; o >>= 1) s += __shfl_xor(s, o, 64);
      inv4[p] = 1.f / s;
    }

    // ---- write P (tiles 0..11) to per-wave strip as packed hi|lo u32 ----
#pragma unroll
    for (int j = 0; j < 12; j++) {
#pragma unroll
      for (int p = 0; p < 4; p++) {
        float e = acc_s[j][p];
        unsigned u = __float_as_uint(e);
        unsigned hs = u >> 16;
        float rem = e - __uint_as_float(hs << 16);
        unsigned ls = f2bf(rem);
        myP[(quad * 4 + p) * 196 + j * 16 + l16] = hs | (ls << 16);
      }
    }

    // ---- O = P V via split MFMA (6 k-steps x 4 d-tiles x 3 terms) ----
    floatx4 acc_o[4];
#pragma unroll
    for (int jn = 0; jn < 4; jn++) acc_o[jn] = (floatx4){0.f, 0.f, 0.f, 0.f};
#pragma unroll
    for (int s = 0; s < 6; s++) {
      const unsigned int* pp = &myP[l16 * 196 + s * 32 + quad * 8];
      uint4 u0 = *(const uint4*)pp;
      uint4 u1 = *(const uint4*)(pp + 4);
      BF8 AH, AL;
      AH.u[0] = (u0.x & 0xffffu) | (u0.y << 16);
      AH.u[1] = (u0.z & 0xffffu) | (u0.w << 16);
      AH.u[2] = (u1.x & 0xffffu) | (u1.y << 16);
      AH.u[3] = (u1.z & 0xffffu) | (u1.w << 16);
      AL.u[0] = (u0.x >> 16) | (u0.y & 0xffff0000u);
      AL.u[1] = (u0.z >> 16) | (u0.w & 0xffff0000u);
      AL.u[2] = (u1.x >> 16) | (u1.y & 0xffff0000u);
      AL.u[3] = (u1.z >> 16) | (u1.w & 0xffff0000u);
#pragma unroll
      for (int jn = 0; jn < 4; jn++) {
        bf16x8 bh = *(const bf16x8*)&Vthi[(jn * 16 + l16) * 200 + s * 32 + quad * 8];
        bf16x8 bl = *(const bf16x8*)&Vtlo[(jn * 16 + l16) * 200 + s * 32 + quad * 8];
        acc_o[jn] = __builtin_amdgcn_mfma_f32_16x16x32_bf16(AH.v, bh, acc_o[jn], 0, 0, 0);
        acc_o[jn] = __builtin_amdgcn_mfma_f32_16x16x32_bf16(AL.v, bh, acc_o[jn], 0, 0, 0);
        acc_o[jn] = __builtin_amdgcn_mfma_f32_16x16x32_bf16(AH.v, bl, acc_o[jn], 0, 0, 0);
      }
    }
    // ---- tail keys 192..195: e still in acc_s[12], broadcast within quad ----
#pragma unroll
    for (int kk = 0; kk < 4; kk++) {
      int srcl = (lane & 48) + kk;
      float e0 = __shfl(acc_s[12][0], srcl, 64);
      float e1 = __shfl(acc_s[12][1], srcl, 64);
      float e2 = __shfl(acc_s[12][2], srcl, 64);
      float e3 = __shfl(acc_s[12][3], srcl, 64);
#pragma unroll
      for (int jn = 0; jn < 4; jn++) {
        int d = jn * 16 + l16;
        float v = bf2f(Vthi[d * 200 + 192 + kk]) + bf2f(Vtlo[d * 200 + 192 + kk]);
        acc_o[jn][0] += e0 * v;
        acc_o[jn][1] += e1 * v;
        acc_o[jn][2] += e2 * v;
        acc_o[jn][3] += e3 * v;
      }
    }

    // ---- store O (normalized) ----
#pragma unroll
    for (int jn = 0; jn < 4; jn++) {
#pragma unroll
      for (int p = 0; p < 4; p++) {
        int qrow = strip * 16 + quad * 4 + p;
        if (qrow < WHT)
          outA[((size_t)(1 + tq * WHT + qrow) * 8 + b) * CC + h * 64 + jn * 16 + l16] =
              acc_o[jn][p] * inv4[p];
      }
    }
  }
}

// ---------------------------------------------------------------------------
// Final LN (token 0 only) + classifier head
// ---------------------------------------------------------------------------
__global__ __launch_bounds__(256)
void head_kernel(const float* __restrict__ X, const float* __restrict__ enw,
                 const float* __restrict__ enb, const float* __restrict__ fcw,
                 const float* __restrict__ fcb, float* __restrict__ out) {
  __shared__ float nx[512];
  __shared__ float red[8];
  const int b = blockIdx.x, tid = threadIdx.x;
  const float* x = X + (size_t)b * CC;
  float v0 = x[tid], v1 = x[tid + 256];
  float s = wave_reduce_sum(v0 + v1);
  if ((tid & 63) == 0) red[tid >> 6] = s;
  __syncthreads();
  float mean = (red[0] + red[1] + red[2] + red[3]) * (1.f / 512.f);
  float d0 = v0 - mean, d1 = v1 - mean;
  float vs = wave_reduce_sum(d0 * d0 + d1 * d1);
  if ((tid & 63) == 0) red[4 + (tid >> 6)] = vs;
  __syncthreads();
  float var = (red[4] + red[5] + red[6] + red[7]) * (1.f / 512.f);
  float inv = 1.0f / sqrtf(var + 1e-5f);
  nx[tid] = d0 * inv * enw[tid] + enb[tid];
  nx[tid + 256] = d1 * inv * enw[tid + 256] + enb[tid + 256];
  __syncthreads();
  if (tid < NCLS) {
    float acc = fcb[tid];
    for (int c = 0; c < 512; c++) acc += nx[c] * fcw[c * NCLS + tid];
    out[b * NCLS + tid] = acc;
  }
}

// ---------------------------------------------------------------------------
extern "C" void kernel_launch(void* const* d_in, const int* in_sizes, int n_in,
                              void* d_out, int out_size, void* d_ws, size_t ws_size,
                              hipStream_t stream) {
  (void)in_sizes; (void)n_in; (void)out_size; (void)ws_size;
  const float* src  = (const float*)d_in[0];
  const float* cw   = (const float*)d_in[1];
  const float* cb   = (const float*)d_in[2];
  const float* clst = (const float*)d_in[3];
  const float* pos  = (const float*)d_in[4];
  const float* Wt   = (const float*)d_in[5];
  const float* bt   = (const float*)d_in[6];
  const float* Wsp  = (const float*)d_in[7];
  const float* bsp  = (const float*)d_in[8];
  const float* Wo   = (const float*)d_in[9];
  const float* bo   = (const float*)d_in[10];
  const float* n1w  = (const float*)d_in[11];
  const float* n1b  = (const float*)d_in[12];
  const float* n2w  = (const float*)d_in[13];
  const float* n2b  = (const float*)d_in[14];
  const float* W1   = (const float*)d_in[15];
  const float* b1   = (const float*)d_in[16];
  const float* W2   = (const float*)d_in[17];
  const float* b2   = (const float*)d_in[18];
  const float* enw  = (const float*)d_in[19];
  const float* enb  = (const float*)d_in[20];
  const float* fcw  = (const float*)d_in[21];
  const float* fcb  = (const float*)d_in[22];

  float* ws = (float*)d_ws;
  const size_t TOKR = (size_t)3137 * 8;
  float* X0  = ws;                              // TOKR*512
  float* Ab  = X0 + TOKR * 512;                 // TOKR*512
  float* QKV = Ab + TOKR * 512;                 // TOKR*1536 (also FFN mid / im2col)
  float* CLS = QKV + TOKR * 1536;               // 8*512
  int*   IDX = (int*)(CLS + 8 * 512);           // 8*8*196*16 ints
  unsigned short* WT1 = (unsigned short*)(IDX + 8 * 8 * WHT * 16);  // 2048*512
  unsigned short* WT2 = WT1 + 2048 * 512;                           // 2048*512
  float* PART = (float*)(WT2 + 2048 * 512);     // 64*CA_NCH*68

  // A-planes for split GEMMs (aliased into Ab / QKV; same total bytes).
  unsigned short* Ahi = (unsigned short*)Ab;
  unsigned short* Alo = Ahi + TOKR * 512;
  unsigned short* IMhi = (unsigned short*)QKV;
  unsigned short* IMlo = IMhi + (size_t)25088 * 768;

  // Patch embed as im2col(split) + split-bf16 MFMA GEMM (M=25088,N=512,K=768).
  wsplit_flat_kernel<<<(512 * 768 + 255) / 256, 256, 0, stream>>>(
      cw, WT1, WT2, 512 * 768);
  im2col_split_kernel<<<(25088 * 192) / 256, 256, 0, stream>>>(src, IMhi, IMlo);
  mfma_gemm3s_kernel<<<(25088 / 128) * 4, 256, 0, stream>>>(
      IMhi, IMlo, WT1, WT2, cb, X0 + 8 * CC, 25088, 512, 768);
  cls_init_kernel<<<8, 512, 0, stream>>>(clst, X0);

  float* Xc = X0;
  int t = 16;
  const int FFN_CHUNK = 16384;
  for (int i = 0; i < 6; i++) {
    const int pk = (i & 1) ? 2 : 0;
    const int tp = t - pk;
    const int L = 1 + t * WHT;
    const int Lo = 1 + tp * WHT;
    const int M = L * 8, Mo = Lo * 8, My = tp * WHT * 8;
    const int mtM = (M + 127) / 128, mtMo = (Mo + 127) / 128, mtMy = (My + 127) / 128;

    // LN1 with direct bf16 hi/lo split output (feeds only the Wt GEMM)
    ln_split_kernel<<<M, 256, 0, stream>>>(Xc, Ahi, Alo,
                                           n1w + (size_t)i * 512, n1b + (size_t)i * 512,
                                           (i == 0) ? pos : nullptr);
    // sigma-critical Wt: split-bf16 MFMA (hi/lo), fp32-class accuracy
    wtrans_split_kernel<<<dim3(1536 / 32, 512 / 32), 256, 0, stream>>>(
        Wt + (size_t)i * 512 * 1536, WT1, WT2, 1536, 512);
    mfma_gemm3s_kernel<<<mtM * 12, 256, 0, stream>>>(
        Ahi, Alo, WT1, WT2, bt + (size_t)i * 1536, QKV, M, 1536, 512);
    class_attn_part_kernel<<<dim3(64, CA_NCH), 256, 0, stream>>>(QKV, PART, L);
    class_attn_reduce_kernel<<<64, 64, 0, stream>>>(PART, CLS);
    temporal_attn_kernel<<<HH * BB * WHT, 256, 0, stream>>>(QKV, Ab, IDX, t, tp, pk);
    // Ws: plain bf16 MFMA
    wtrans_kernel<<<dim3(1536 / 32, 512 / 32), 256, 0, stream>>>(
        Wsp + (size_t)i * 512 * 1536, WT1, 1536, 512);
    mfma_gemm_kernel<0, 0><<<mtMy * 12, 256, 0, stream>>>(
        Ab, WT1, bsp + (size_t)i * 1536, QKV, My, 1536, 512, nullptr);
    copy_cls_kernel<<<8, 512, 0, stream>>>(CLS, Ab);
    spatial_mfma_kernel<<<64 * tp, 256, 0, stream>>>(QKV, Ab);
    if (pk > 0)
      pool_inplace_kernel<<<8 * WHT, 256, 0, stream>>>(Xc, IDX, tp);
    // Wo: plain bf16 MFMA + residual
    wtrans_kernel<<<dim3(512 / 32, 512 / 32), 256, 0, stream>>>(
        Wo + (size_t)i * 512 * 512, WT1, 512, 512);
    mfma_gemm_kernel<0, 1><<<mtMo * 4, 256, 0, stream>>>(
        Ab, WT1, bo + (size_t)i * 512, Xc, Mo, 512, 512, Xc);
    ln_kernel<<<Mo, 256, 0, stream>>>(Xc, Ab, n2w + (size_t)i * 512, n2b + (size_t)i * 512,
                                      nullptr);
    // FFN: plain bf16 MFMA
    wtrans_kernel<<<dim3(2048 / 32, 512 / 32), 256, 0, stream>>>(
        W1 + (size_t)i * 512 * 2048, WT1, 2048, 512);
    wtrans_kernel<<<dim3(512 / 32, 2048 / 32), 256, 0, stream>>>(
        W2 + (size_t)i * 2048 * 512, WT2, 512, 2048);
    for (int off = 0; off < Mo; off += FFN_CHUNK) {
      int R = Mo - off;
      if (R > FFN_CHUNK) R = FFN_CHUNK;
      int mtR = (R + 127) / 128;
      mfma_gemm_kernel<1, 0><<<mtR * 16, 256, 0, stream>>>(
          Ab + (size_t)off * 512, WT1, b1 + (size_t)i * 2048, QKV, R, 2048, 512,
          nullptr);
      mfma_gemm_kernel<0, 1><<<mtR * 4, 256, 0, stream>>>(
          QKV, WT2, b2 + (size_t)i * 512, Xc + (size_t)off * 512, R, 512, 2048,
          Xc + (size_t)off * 512);
    }
    t = tp;
  }
  head_kernel<<<8, 256, 0, stream>>>(Xc, enw, enb, fcw, fcb, (float*)d_out);
}

// Round 6
// 5529.509 us; speedup vs baseline: 1.7929x; 1.0361x over previous
//
#include <hip/hip_runtime.h>
#include <math.h>

// ---------------------------------------------------------------------------
// CompactVidTr forward.
//  - All GEMMs: 128x128 tile, 1-D grid with bijective XCD-band swizzle (each
//    XCD owns a contiguous m-band, n fastest -> A-tiles hit the same per-XCD
//    L2; FETCH for the Wt GEMM dropped 221->92 MB).
//  - Wt/conv GEMM (mfma_gemm3s): 3-term split-bf16 MFMA, pre-split A planes.
//    BK=32, LDS 32 KB total (4 planes x 8 KB), bank-conflict-free via XOR
//    granule swizzle  g ^= (row>>1)&3  on BOTH write and read. (BK=64/64 KB
//    variant cut occupancy 27->17% and lost 30 us/dispatch — m132 lesson.)
//  - Plain GEMMs (Ws/Wo/FFN): BK=64, 68-short padded rows (34 KB LDS).
//  - Spatial attention: split-bf16 MFMA flash kernel.
//  - Class attention: two-phase flash split over L.
//  - Temporal attention + LN: fp32 vector.
// Layout: token matrices row-major [row = l*B + b][C]; l=0 is cls. B=8, C=512.
//
// Workspace (262.5 MB < 268.4 MB): X, Ab(split planes), QKV, CLS, IDX,
//   WT1/WT2 (2048*512 bf16 each), PART.
// ---------------------------------------------------------------------------

#define BB 8
#define CC 512
#define HH 8
#define HD 64
#define WHT 196
#define NCLS 157
#define CA_NCH 32

typedef short bf16x8 __attribute__((ext_vector_type(8)));
typedef float floatx4 __attribute__((ext_vector_type(4)));

__device__ __forceinline__ unsigned short f2bf(float f) {
  unsigned u = __float_as_uint(f);
  unsigned r = u + 0x7FFFu + ((u >> 16) & 1u);  // RNE
  return (unsigned short)(r >> 16);
}
__device__ __forceinline__ float bf2f(unsigned short h) {
  return __uint_as_float((unsigned)h << 16);
}
// truncation split: hi = top-16-bits, lo = RNE(residual); reconstruct ~2^-17
__device__ __forceinline__ void splitf(float x, unsigned short& h, unsigned short& l) {
  unsigned u = __float_as_uint(x);
  unsigned hs = u >> 16;
  float rem = x - __uint_as_float(hs << 16);
  h = (unsigned short)hs;
  l = f2bf(rem);
}

__device__ __forceinline__ float wave_reduce_sum(float v) {
#pragma unroll
  for (int o = 32; o > 0; o >>= 1) v += __shfl_down(v, o, 64);
  return v;
}
__device__ __forceinline__ float wave_reduce_max(float v) {
#pragma unroll
  for (int o = 32; o > 0; o >>= 1) v = fmaxf(v, __shfl_down(v, o, 64));
  return v;
}

// Bijective XCD-band decode (m204 variant): blocks with id%8==x run on XCD x;
// give each XCD a contiguous work range, n fastest within an m-row.
__device__ __forceinline__ void xcd_decode(int id, int G, int nt,
                                           int& m0, int& n0) {
  int q8 = G >> 3, r8 = G & 7;
  int xcd = id & 7, j = id >> 3;
  int w = (xcd < r8) ? xcd * (q8 + 1) + j : r8 * (q8 + 1) + (xcd - r8) * q8 + j;
  m0 = (w / nt) * 128;
  n0 = (w % nt) * 128;
}

// ---------------------------------------------------------------------------
// im2col + split: src [8][3][16][224][224] -> IMhi/IMlo [25088][768] bf16.
// ---------------------------------------------------------------------------
__global__ __launch_bounds__(256)
void im2col_split_kernel(const float* __restrict__ src,
                         unsigned short* __restrict__ IMhi,
                         unsigned short* __restrict__ IMlo) {
  int gid = blockIdx.x * 256 + threadIdx.x;
  int k4 = gid % 192;
  int u = gid / 192;
  if (u >= 25088) return;
  int b = u & 7;
  int s = u >> 3;
  int tt = s / WHT;
  int w2 = s % WHT;
  int ph = w2 / 14, pw = w2 % 14;
  int k = k4 * 4;
  int ci = k >> 8;
  int rem = k & 255;
  int py = rem >> 4, px = rem & 15;
  const float* sp = src + (size_t)b * (3 * 16 * 224 * 224) +
                    (size_t)ci * (16 * 224 * 224) + (size_t)tt * (224 * 224) +
                    (size_t)(ph * 16 + py) * 224 + pw * 16 + px;
  float4 v = *(const float4*)sp;
  ushort4 h, l;
  splitf(v.x, h.x, l.x);
  splitf(v.y, h.y, l.y);
  splitf(v.z, h.z, l.z);
  splitf(v.w, h.w, l.w);
  *(ushort4*)(IMhi + (size_t)u * 768 + k) = h;
  *(ushort4*)(IMlo + (size_t)u * 768 + k) = l;
}

__global__ __launch_bounds__(256)
void wsplit_flat_kernel(const float* __restrict__ W,
                        unsigned short* __restrict__ Whi,
                        unsigned short* __restrict__ Wlo, int total) {
  int i = blockIdx.x * 256 + threadIdx.x;
  if (i >= total) return;
  float w = W[i];
  unsigned short hi = f2bf(w);
  Whi[i] = hi;
  Wlo[i] = f2bf(w - bf2f(hi));
}

__global__ void cls_init_kernel(const float* __restrict__ clst, float* __restrict__ X) {
  X[(size_t)blockIdx.x * CC + threadIdx.x] = clst[threadIdx.x];
}

__global__ void copy_cls_kernel(const float* __restrict__ cls, float* __restrict__ A) {
  A[(size_t)blockIdx.x * CC + threadIdx.x] = cls[(size_t)blockIdx.x * CC + threadIdx.x];
}

// ---------------------------------------------------------------------------
// LayerNorm over C=512 (fp32 out); one block per row
// ---------------------------------------------------------------------------
__global__ __launch_bounds__(256)
void ln_kernel(const float* __restrict__ X, float* __restrict__ O,
               const float* __restrict__ w, const float* __restrict__ b,
               const float* __restrict__ pos) {
  __shared__ float red[8];
  const int row = blockIdx.x, tid = threadIdx.x;
  const float* x = X + (size_t)row * CC;
  float v0 = x[tid], v1 = x[tid + 256];
  float s = wave_reduce_sum(v0 + v1);
  if ((tid & 63) == 0) red[tid >> 6] = s;
  __syncthreads();
  float mean = (red[0] + red[1] + red[2] + red[3]) * (1.f / 512.f);
  float d0 = v0 - mean, d1 = v1 - mean;
  float vs = wave_reduce_sum(d0 * d0 + d1 * d1);
  if ((tid & 63) == 0) red[4 + (tid >> 6)] = vs;
  __syncthreads();
  float var = (red[4] + red[5] + red[6] + red[7]) * (1.f / 512.f);
  float inv = 1.0f / sqrtf(var + 1e-5f);
  float o0 = d0 * inv * w[tid] + b[tid];
  float o1 = d1 * inv * w[tid + 256] + b[tid + 256];
  if (pos) {
    const float* pr = pos + (size_t)(row >> 3) * CC;
    o0 += pr[tid];
    o1 += pr[tid + 256];
  }
  O[(size_t)row * CC + tid] = o0;
  O[(size_t)row * CC + tid + 256] = o1;
}

// ---------------------------------------------------------------------------
// LayerNorm + split-bf16 output (hi/lo planes) — feeds the Wt split GEMM.
// ---------------------------------------------------------------------------
__global__ __launch_bounds__(256)
void ln_split_kernel(const float* __restrict__ X,
                     unsigned short* __restrict__ Ahi,
                     unsigned short* __restrict__ Alo,
                     const float* __restrict__ w, const float* __restrict__ b,
                     const float* __restrict__ pos) {
  __shared__ float red[8];
  const int row = blockIdx.x, tid = threadIdx.x;
  const float* x = X + (size_t)row * CC;
  float v0 = x[tid], v1 = x[tid + 256];
  float s = wave_reduce_sum(v0 + v1);
  if ((tid & 63) == 0) red[tid >> 6] = s;
  __syncthreads();
  float mean = (red[0] + red[1] + red[2] + red[3]) * (1.f / 512.f);
  float d0 = v0 - mean, d1 = v1 - mean;
  float vs = wave_reduce_sum(d0 * d0 + d1 * d1);
  if ((tid & 63) == 0) red[4 + (tid >> 6)] = vs;
  __syncthreads();
  float var = (red[4] + red[5] + red[6] + red[7]) * (1.f / 512.f);
  float inv = 1.0f / sqrtf(var + 1e-5f);
  float o0 = d0 * inv * w[tid] + b[tid];
  float o1 = d1 * inv * w[tid + 256] + b[tid + 256];
  if (pos) {
    const float* pr = pos + (size_t)(row >> 3) * CC;
    o0 += pr[tid];
    o1 += pr[tid + 256];
  }
  unsigned short h, l;
  splitf(o0, h, l);
  Ahi[(size_t)row * CC + tid] = h;
  Alo[(size_t)row * CC + tid] = l;
  splitf(o1, h, l);
  Ahi[(size_t)row * CC + tid + 256] = h;
  Alo[(size_t)row * CC + tid + 256] = l;
}

// ---------------------------------------------------------------------------
// Weight transpose + fp32->bf16 (plain): W [K][N] -> WT [N][K]
// ---------------------------------------------------------------------------
__global__ __launch_bounds__(256)
void wtrans_kernel(const float* __restrict__ W, unsigned short* __restrict__ WT,
                   int N, int K) {
  __shared__ float tile[32][33];
  const int tid = threadIdx.x;
  const int tx = tid & 31, ty = tid >> 5;
  const int n0 = blockIdx.x * 32, k0 = blockIdx.y * 32;
#pragma unroll
  for (int r = 0; r < 4; r++) {
    int kk = ty + r * 8;
    tile[kk][tx] = W[(size_t)(k0 + kk) * N + n0 + tx];
  }
  __syncthreads();
#pragma unroll
  for (int r = 0; r < 4; r++) {
    int nn = ty + r * 8;
    WT[(size_t)(n0 + nn) * K + k0 + tx] = f2bf(tile[tx][nn]);
  }
}

// ---------------------------------------------------------------------------
// Weight transpose + split fp32 -> (hi, lo) bf16: W [K][N] -> WThi/WTlo [N][K]
// ---------------------------------------------------------------------------
__global__ __launch_bounds__(256)
void wtrans_split_kernel(const float* __restrict__ W,
                         unsigned short* __restrict__ WThi,
                         unsigned short* __restrict__ WTlo, int N, int K) {
  __shared__ float tile[32][33];
  const int tid = threadIdx.x;
  const int tx = tid & 31, ty = tid >> 5;
  const int n0 = blockIdx.x * 32, k0 = blockIdx.y * 32;
#pragma unroll
  for (int r = 0; r < 4; r++) {
    int kk = ty + r * 8;
    tile[kk][tx] = W[(size_t)(k0 + kk) * N + n0 + tx];
  }
  __syncthreads();
#pragma unroll
  for (int r = 0; r < 4; r++) {
    int nn = ty + r * 8;
    float w = tile[tx][nn];
    unsigned short hi = f2bf(w);
    unsigned short lo = f2bf(w - bf2f(hi));
    WThi[(size_t)(n0 + nn) * K + k0 + tx] = hi;
    WTlo[(size_t)(n0 + nn) * K + k0 + tx] = lo;
  }
}

// ---------------------------------------------------------------------------
// Plain bf16 MFMA GEMM: C = A(M,K) @ W(K,N) + bias [+relu] [+residual]
// BK=64 epochs; LDS rows padded to 68 shorts (stride 34 dwords -> no bank
// conflicts on ds_read_b128). 1-D grid + XCD-band decode.
// ---------------------------------------------------------------------------
template <int RELU, int RES>
__global__ __launch_bounds__(256)
void mfma_gemm_kernel(const float* __restrict__ A,
                      const unsigned short* __restrict__ WT,
                      const float* __restrict__ bias, float* __restrict__ Cout,
                      int M, int N, int K, const float* __restrict__ resid) {
  __shared__ unsigned short AsU[128 * 68];
  __shared__ unsigned short BsU[128 * 68];
  const int tid = threadIdx.x;
  const int wave = tid >> 6, lane = tid & 63;
  const int quad = lane >> 4, l16 = lane & 15;
  const int wrow = (wave >> 1) * 64, wcol = (wave & 1) * 64;
  int m0, n0;
  xcd_decode(blockIdx.x, gridDim.x, N >> 7, m0, n0);

  floatx4 acc[4][4];
#pragma unroll
  for (int i = 0; i < 4; i++)
#pragma unroll
    for (int j = 0; j < 4; j++) acc[i][j] = (floatx4){0.f, 0.f, 0.f, 0.f};

  for (int k0 = 0; k0 < K; k0 += 64) {
#pragma unroll
    for (int r = 0; r < 8; r++) {
      int row = (tid >> 4) + r * 16;
      int c4 = (tid & 15) * 4;
      int gm = m0 + row;
      float4 v = make_float4(0.f, 0.f, 0.f, 0.f);
      if (gm < M) v = *(const float4*)(A + (size_t)gm * K + k0 + c4);
      ushort4 o;
      o.x = f2bf(v.x); o.y = f2bf(v.y); o.z = f2bf(v.z); o.w = f2bf(v.w);
      *(ushort4*)&AsU[row * 68 + c4] = o;
    }
#pragma unroll
    for (int r = 0; r < 4; r++) {
      int n = (tid >> 3) + r * 32;
      int g = tid & 7;
      uint4 w = *(const uint4*)(WT + (size_t)(n0 + n) * K + k0 + g * 8);
      *(uint4*)&BsU[n * 68 + g * 8] = w;
    }
    __syncthreads();
#pragma unroll
    for (int st = 0; st < 2; st++) {
      bf16x8 af[4], bf[4];
#pragma unroll
      for (int i = 0; i < 4; i++)
        af[i] = *(const bf16x8*)&AsU[(wrow + i * 16 + l16) * 68 + st * 32 + quad * 8];
#pragma unroll
      for (int j = 0; j < 4; j++)
        bf[j] = *(const bf16x8*)&BsU[(wcol + j * 16 + l16) * 68 + st * 32 + quad * 8];
#pragma unroll
      for (int i = 0; i < 4; i++)
#pragma unroll
        for (int j = 0; j < 4; j++)
          acc[i][j] = __builtin_amdgcn_mfma_f32_16x16x32_bf16(af[i], bf[j],
                                                              acc[i][j], 0, 0, 0);
    }
    __syncthreads();
  }
#pragma unroll
  for (int i = 0; i < 4; i++) {
#pragma unroll
    for (int p = 0; p < 4; p++) {
      int gm = m0 + wrow + i * 16 + quad * 4 + p;
      if (gm >= M) continue;
#pragma unroll
      for (int j = 0; j < 4; j++) {
        int gn = n0 + wcol + j * 16 + l16;
        float v = acc[i][j][p] + bias[gn];
        if (RELU) v = fmaxf(v, 0.f);
        if (RES == 1) v += resid[(size_t)gm * N + gn];
        Cout[(size_t)gm * N + gn] = v;
      }
    }
  }
}

// ---------------------------------------------------------------------------
// Split-bf16 MFMA GEMM, pre-split A planes. BK=32; LDS = 4 x 8 KB = 32 KB,
// bank-conflict-free XOR-granule swizzle: 16-B granule g of row r stored at
// g ^ ((r>>1)&3) and read back at quad ^ ((r>>1)&3).  ((r>>1), not r: bank
// base alternates with row parity, so rows {0,4,8,12} would 4-way collide
// under g^(r&3); (r>>1)&3 leaves only the free 2-way alias.)
// ---------------------------------------------------------------------------
__global__ __launch_bounds__(256)
void mfma_gemm3s_kernel(const unsigned short* __restrict__ Ahi,
                        const unsigned short* __restrict__ Alo,
                        const unsigned short* __restrict__ WThi,
                        const unsigned short* __restrict__ WTlo,
                        const float* __restrict__ bias, float* __restrict__ Cout,
                        int M, int N, int K) {
  __shared__ unsigned short AsHi[128 * 32];
  __shared__ unsigned short AsLo[128 * 32];
  __shared__ unsigned short BsHi[128 * 32];
  __shared__ unsigned short BsLo[128 * 32];
  const int tid = threadIdx.x;
  const int wave = tid >> 6, lane = tid & 63;
  const int quad = lane >> 4, l16 = lane & 15;
  const int wrow = (wave >> 1) * 64, wcol = (wave & 1) * 64;
  int m0, n0;
  xcd_decode(blockIdx.x, gridDim.x, N >> 7, m0, n0);

  floatx4 acc[4][4];
#pragma unroll
  for (int i = 0; i < 4; i++)
#pragma unroll
    for (int j = 0; j < 4; j++) acc[i][j] = (floatx4){0.f, 0.f, 0.f, 0.f};

  for (int k0 = 0; k0 < K; k0 += 32) {
#pragma unroll
    for (int r = 0; r < 2; r++) {
      int row = (tid >> 2) + r * 64;
      int g = tid & 3;
      int dst = row * 32 + ((g ^ ((row >> 1) & 3)) * 8);
      int gm = m0 + row;
      uint4 vh = make_uint4(0u, 0u, 0u, 0u), vl = make_uint4(0u, 0u, 0u, 0u);
      if (gm < M) {
        vh = *(const uint4*)(Ahi + (size_t)gm * K + k0 + g * 8);
        vl = *(const uint4*)(Alo + (size_t)gm * K + k0 + g * 8);
      }
      *(uint4*)&AsHi[dst] = vh;
      *(uint4*)&AsLo[dst] = vl;
      uint4 wh = *(const uint4*)(WThi + (size_t)(n0 + row) * K + k0 + g * 8);
      uint4 wl = *(const uint4*)(WTlo + (size_t)(n0 + row) * K + k0 + g * 8);
      *(uint4*)&BsHi[dst] = wh;
      *(uint4*)&BsLo[dst] = wl;
    }
    __syncthreads();
    bf16x8 ah[4], al[4], bh[4], bl[4];
#pragma unroll
    for (int i = 0; i < 4; i++) {
      int ra = wrow + i * 16 + l16;
      int offa = ra * 32 + ((quad ^ ((ra >> 1) & 3)) * 8);
      ah[i] = *(const bf16x8*)&AsHi[offa];
      al[i] = *(const bf16x8*)&AsLo[offa];
      int rb = wcol + i * 16 + l16;
      int offb = rb * 32 + ((quad ^ ((rb >> 1) & 3)) * 8);
      bh[i] = *(const bf16x8*)&BsHi[offb];
      bl[i] = *(const bf16x8*)&BsLo[offb];
    }
#pragma unroll
    for (int i = 0; i < 4; i++)
#pragma unroll
      for (int j = 0; j < 4; j++) {
        acc[i][j] = __builtin_amdgcn_mfma_f32_16x16x32_bf16(ah[i], bh[j],
                                                            acc[i][j], 0, 0, 0);
        acc[i][j] = __builtin_amdgcn_mfma_f32_16x16x32_bf16(ah[i], bl[j],
                                                            acc[i][j], 0, 0, 0);
        acc[i][j] = __builtin_amdgcn_mfma_f32_16x16x32_bf16(al[i], bh[j],
                                                            acc[i][j], 0, 0, 0);
      }
    __syncthreads();
  }
#pragma unroll
  for (int i = 0; i < 4; i++) {
#pragma unroll
    for (int p = 0; p < 4; p++) {
      int gm = m0 + wrow + i * 16 + quad * 4 + p;
      if (gm >= M) continue;
#pragma unroll
      for (int j = 0; j < 4; j++) {
        int gn = n0 + wcol + j * 16 + l16;
        Cout[(size_t)gm * N + gn] = acc[i][j][p] + bias[gn];
      }
    }
  }
}

// ---------------------------------------------------------------------------
// Class attention, phase 1: per-(h,b) x per-chunk partial flash softmax.
// ---------------------------------------------------------------------------
__global__ __launch_bounds__(256)
void class_attn_part_kernel(const float* __restrict__ qkv,
                            float* __restrict__ part, int L) {
  __shared__ float q[64];
  __shared__ float sc[128];
  __shared__ float red[8];
  __shared__ float pv[256];
  const int h = blockIdx.x & 7, b = blockIdx.x >> 3;
  const int chunk = blockIdx.y;
  const int tid = threadIdx.x;
  const int per = (L + CA_NCH - 1) / CA_NCH;
  const int l0 = chunk * per;
  const int nl = min(L - l0, per);
  if (tid < 64) q[tid] = qkv[(size_t)b * 1536 + h * 64 + tid] * 0.125f;
  __syncthreads();
  float lmax = -3.4e38f;
  for (int i = tid; i < nl; i += 256) {
    const float* kr = qkv + (size_t)((l0 + i) * 8 + b) * 1536 + 512 + h * 64;
    float s = 0;
#pragma unroll
    for (int d2 = 0; d2 < 64; d2 += 4) {
      float4 k4 = *(const float4*)(kr + d2);
      s += q[d2] * k4.x + q[d2 + 1] * k4.y + q[d2 + 2] * k4.z + q[d2 + 3] * k4.w;
    }
    sc[i] = s;
    lmax = fmaxf(lmax, s);
  }
  lmax = wave_reduce_max(lmax);
  if ((tid & 63) == 0) red[tid >> 6] = lmax;
  __syncthreads();
  float gmax = fmaxf(fmaxf(red[0], red[1]), fmaxf(red[2], red[3]));
  float lsum = 0;
  for (int i = tid; i < nl; i += 256) {
    float e = expf(sc[i] - gmax);
    sc[i] = e;
    lsum += e;
  }
  lsum = wave_reduce_sum(lsum);
  if ((tid & 63) == 0) red[4 + (tid >> 6)] = lsum;
  __syncthreads();
  float gsum = red[4] + red[5] + red[6] + red[7];
  const int g = tid >> 6, d = tid & 63;
  float acc = 0;
  for (int i = g; i < nl; i += 4)
    acc += sc[i] * qkv[(size_t)((l0 + i) * 8 + b) * 1536 + 1024 + h * 64 + d];
  pv[g * 64 + d] = acc;
  __syncthreads();
  float* rec = part + ((size_t)blockIdx.x * CA_NCH + chunk) * 68;
  if (tid == 0) {
    rec[0] = gmax;
    rec[1] = gsum;
  }
  if (g == 0) rec[2 + d] = pv[d] + pv[64 + d] + pv[128 + d] + pv[192 + d];
}

// ---------------------------------------------------------------------------
// Class attention, phase 2: combine CA_NCH partials per (h,b).
// ---------------------------------------------------------------------------
__global__ __launch_bounds__(64)
void class_attn_reduce_kernel(const float* __restrict__ part,
                              float* __restrict__ cls) {
  const int hb = blockIdx.x;  // (b<<3)|h
  const int tid = threadIdx.x;
  const float* prec = part + (size_t)hb * CA_NCH * 68;
  float M = -3.4e38f;
#pragma unroll
  for (int c = 0; c < CA_NCH; c++) M = fmaxf(M, prec[c * 68]);
  float total = 0.f, acc = 0.f;
#pragma unroll
  for (int c = 0; c < CA_NCH; c++) {
    float w = expf(prec[c * 68] - M);
    total += prec[c * 68 + 1] * w;
    acc += prec[c * 68 + 2 + tid] * w;
  }
  int h = hb & 7, b = hb >> 3;
  cls[b * CC + h * 64 + tid] = acc / total;
}

// ---------------------------------------------------------------------------
// Temporal attention + sigma top-k pooling (fp32 — rank-critical).
// ---------------------------------------------------------------------------
__global__ __launch_bounds__(256)
void temporal_attn_kernel(const float* __restrict__ qkv, float* __restrict__ Y,
                          int* __restrict__ idxbuf, int t, int tp, int pk) {
  __shared__ float qs[16 * 65], ks[16 * 65], vs[16 * 65];
  __shared__ float a[16 * 17];
  __shared__ float sig[16];
  __shared__ int keepf[16];
  __shared__ int klist[16];
  const int g = blockIdx.x;
  const int w = g % WHT;
  const int bb = (g / WHT) & 7;
  const int h = g / (WHT * 8);
  const int tid = threadIdx.x;
  const int td = t * 64;
  for (int e = tid; e < td; e += 256) {
    int tt = e >> 6, d = e & 63;
    size_t rb = (size_t)((1 + tt * WHT + w) * 8 + bb) * 1536 + h * 64 + d;
    qs[tt * 65 + d] = qkv[rb] * 0.125f;
    ks[tt * 65 + d] = qkv[rb + 512];
    vs[tt * 65 + d] = qkv[rb + 1024];
  }
  __syncthreads();
  if (tid < t * t) {
    int qi = tid / t, ki = tid % t;
    const float* qp = &qs[qi * 65];
    const float* kp = &ks[ki * 65];
    float s = 0;
#pragma unroll 8
    for (int d2 = 0; d2 < 64; d2++) s += qp[d2] * kp[d2];
    a[qi * 17 + ki] = s;
  }
  __syncthreads();
  if (tid < t) {
    float* row = &a[tid * 17];
    float m = row[0];
    for (int k2 = 1; k2 < t; k2++) m = fmaxf(m, row[k2]);
    float sum = 0;
    for (int k2 = 0; k2 < t; k2++) {
      float e2 = expf(row[k2] - m);
      row[k2] = e2;
      sum += e2;
    }
    float inv = 1.f / sum;
    for (int k2 = 0; k2 < t; k2++) row[k2] *= inv;
  }
  __syncthreads();
  if (pk > 0) {
    if (tid < t) {
      const float* row = &a[tid * 17];
      float mean = 0;
      for (int k2 = 0; k2 < t; k2++) mean += row[k2];
      mean /= (float)t;
      float var = 0;
      for (int k2 = 0; k2 < t; k2++) {
        float dl = row[k2] - mean;
        var += dl * dl;
      }
      var /= (float)(t - 1);
      sig[tid] = sqrtf(var);
    }
    __syncthreads();
    if (tid < t) {
      float sv = sig[tid];
      int r = 0;
      for (int q2 = 0; q2 < t; q2++) {
        float so = sig[q2];
        if (so > sv || (so == sv && q2 < tid)) r++;
      }
      keepf[tid] = (r < tp) ? 1 : 0;
    }
    __syncthreads();
    if (tid < t && keepf[tid]) {
      int ppos = 0;
      for (int q2 = 0; q2 < tid; q2++) ppos += keepf[q2];
      klist[ppos] = tid;
      idxbuf[((h * 8 + bb) * WHT + w) * 16 + ppos] = tid;
    }
  } else {
    if (tid < t) klist[tid] = tid;
  }
  __syncthreads();
  const int gq = tid >> 6, d = tid & 63;
  for (int qi = gq; qi < tp; qi += 4) {
    int qq = klist[qi];
    const float* arow = &a[qq * 17];
    float acc = 0;
    for (int k2 = 0; k2 < t; k2++) acc += arow[k2] * vs[k2 * 65 + d];
    Y[(size_t)((qi * WHT + w) * 8 + bb) * CC + h * 64 + d] = acc;
  }
}

// ---------------------------------------------------------------------------
// In-place temporal pooling of the residual stream X.
// ---------------------------------------------------------------------------
__global__ __launch_bounds__(256)
void pool_inplace_kernel(float* __restrict__ X, const int* __restrict__ idxbuf,
                         int tp) {
  const int b = blockIdx.x & 7;
  const int w = blockIdx.x >> 3;
  const int tid = threadIdx.x;
  const int c0 = tid, c1 = tid + 256;
  const int h0 = c0 >> 6, h1 = c1 >> 6;
  const int ib0 = ((h0 * 8 + b) * WHT + w) * 16;
  const int ib1 = ((h1 * 8 + b) * WHT + w) * 16;
  for (int q = 0; q < tp; q++) {
    int s0 = idxbuf[ib0 + q];
    int s1 = idxbuf[ib1 + q];
    size_t drow = (size_t)((1 + q * WHT + w) * 8 + b) * CC;
    if (s0 != q) {
      size_t srow = (size_t)((1 + s0 * WHT + w) * 8 + b) * CC;
      X[drow + c0] = X[srow + c0];
    }
    if (s1 != q) {
      size_t srow = (size_t)((1 + s1 * WHT + w) * 8 + b) * CC;
      X[drow + c1] = X[srow + c1];
    }
  }
}

// ---------------------------------------------------------------------------
// Spatial attention, split-bf16 MFMA flash kernel.
// ---------------------------------------------------------------------------
__global__ __launch_bounds__(256)
void spatial_mfma_kernel(const float* __restrict__ qkv, float* __restrict__ outA) {
  __shared__ unsigned short Khi[208 * 72];
  __shared__ unsigned short Klo[208 * 72];
  __shared__ unsigned short Vthi[64 * 200];
  __shared__ unsigned short Vtlo[64 * 200];
  __shared__ unsigned int Ps[4][16 * 196];
  const int blk = blockIdx.x;
  const int h = blk & 7;
  const int b = (blk >> 3) & 7;
  const int tq = blk >> 6;
  const int tid = threadIdx.x;
  const int wave = tid >> 6, lane = tid & 63;
  const int quad = lane >> 4, l16 = lane & 15;
  const size_t rowbase = (size_t)(tq * WHT) * 8 + b;  // qkv row for w=0

  union BF8 { bf16x8 v; unsigned short s[8]; unsigned int u[4]; };

  // ---- stage K (hi/lo) and V (transposed hi/lo) ----
  for (int r = tid >> 4; r < WHT; r += 16) {
    int c = (tid & 15) * 4;
    const float* gk = qkv + (rowbase + (size_t)r * 8) * 1536 + 512 + h * 64 + c;
    float4 kv = *(const float4*)gk;
    ushort4 khs, kls;
    splitf(kv.x, khs.x, kls.x);
    splitf(kv.y, khs.y, kls.y);
    splitf(kv.z, khs.z, kls.z);
    splitf(kv.w, khs.w, kls.w);
    *(ushort4*)&Khi[r * 72 + c] = khs;
    *(ushort4*)&Klo[r * 72 + c] = kls;
    const float* gv = qkv + (rowbase + (size_t)r * 8) * 1536 + 1024 + h * 64 + c;
    float4 vv = *(const float4*)gv;
    unsigned short vh, vl;
    splitf(vv.x, vh, vl); Vthi[(c + 0) * 200 + r] = vh; Vtlo[(c + 0) * 200 + r] = vl;
    splitf(vv.y, vh, vl); Vthi[(c + 1) * 200 + r] = vh; Vtlo[(c + 1) * 200 + r] = vl;
    splitf(vv.z, vh, vl); Vthi[(c + 2) * 200 + r] = vh; Vtlo[(c + 2) * 200 + r] = vl;
    splitf(vv.w, vh, vl); Vthi[(c + 3) * 200 + r] = vh; Vtlo[(c + 3) * 200 + r] = vl;
  }
  __syncthreads();

  unsigned int* myP = &Ps[wave][0];

  for (int strip = wave; strip < 13; strip += 4) {
    // ---- load Q fragments for rows strip*16 + l16 (A-operand layout) ----
    int qr = strip * 16 + l16;
    int qrc = min(qr, WHT - 1);
    const float* qp = qkv + (rowbase + (size_t)qrc * 8) * 1536 + h * 64 + quad * 8;
    BF8 qh[2], ql[2];
#pragma unroll
    for (int st = 0; st < 2; st++) {
      float4 a = *(const float4*)(qp + st * 32);
      float4 c = *(const float4*)(qp + st * 32 + 4);
      float vals[8] = {a.x, a.y, a.z, a.w, c.x, c.y, c.z, c.w};
#pragma unroll
      for (int i = 0; i < 8; i++) {
        float x = vals[i] * 0.125f;
        splitf(x, qh[st].s[i], ql[st].s[i]);
      }
    }

    // ---- S = Q K^T via split MFMA (13 key tiles x 2 k-steps x 3 terms) ----
    floatx4 acc_s[13];
#pragma unroll
    for (int j = 0; j < 13; j++) {
      floatx4 acc = (floatx4){0.f, 0.f, 0.f, 0.f};
#pragma unroll
      for (int st = 0; st < 2; st++) {
        bf16x8 bh = *(const bf16x8*)&Khi[(j * 16 + l16) * 72 + st * 32 + quad * 8];
        bf16x8 bl = *(const bf16x8*)&Klo[(j * 16 + l16) * 72 + st * 32 + quad * 8];
        acc = __builtin_amdgcn_mfma_f32_16x16x32_bf16(qh[st].v, bh, acc, 0, 0, 0);
        acc = __builtin_amdgcn_mfma_f32_16x16x32_bf16(ql[st].v, bh, acc, 0, 0, 0);
        acc = __builtin_amdgcn_mfma_f32_16x16x32_bf16(qh[st].v, bl, acc, 0, 0, 0);
      }
      acc_s[j] = acc;
    }
    // mask invalid key cols 196..207 (tile 12, l16 >= 4)
    if (l16 >= 4) acc_s[12] = (floatx4){-3.4e38f, -3.4e38f, -3.4e38f, -3.4e38f};

    // ---- softmax rows (row = quad*4+p): 13-reg local + 16-lane shfl reduce ----
    float inv4[4];
#pragma unroll
    for (int p = 0; p < 4; p++) {
      float m = acc_s[0][p];
#pragma unroll
      for (int j = 1; j < 13; j++) m = fmaxf(m, acc_s[j][p]);
#pragma unroll
      for (int o = 8; o >= 1; o >>= 1) m = fmaxf(m, __shfl_xor(m, o, 64));
      float s = 0.f;
#pragma unroll
      for (int j = 0; j < 13; j++) {
        float e = __expf(acc_s[j][p] - m);
        acc_s[j][p] = e;
        s += e;
      }
#pragma unroll
      for (int o = 8; o >= 1; o >>= 1) s += __shfl_xor(s, o, 64);
      inv4[p] = 1.f / s;
    }

    // ---- write P (tiles 0..11) to per-wave strip as packed hi|lo u32 ----
#pragma unroll
    for (int j = 0; j < 12; j++) {
#pragma unroll
      for (int p = 0; p < 4; p++) {
        float e = acc_s[j][p];
        unsigned u = __float_as_uint(e);
        unsigned hs = u >> 16;
        float rem = e - __uint_as_float(hs << 16);
        unsigned ls = f2bf(rem);
        myP[(quad * 4 + p) * 196 + j * 16 + l16] = hs | (ls << 16);
      }
    }

    // ---- O = P V via split MFMA (6 k-steps x 4 d-tiles x 3 terms) ----
    floatx4 acc_o[4];
#pragma unroll
    for (int jn = 0; jn < 4; jn++) acc_o[jn] = (floatx4){0.f, 0.f, 0.f, 0.f};
#pragma unroll
    for (int s = 0; s < 6; s++) {
      const unsigned int* pp = &myP[l16 * 196 + s * 32 + quad * 8];
      uint4 u0 = *(const uint4*)pp;
      uint4 u1 = *(const uint4*)(pp + 4);
      BF8 AH, AL;
      AH.u[0] = (u0.x & 0xffffu) | (u0.y << 16);
      AH.u[1] = (u0.z & 0xffffu) | (u0.w << 16);
      AH.u[2] = (u1.x & 0xffffu) | (u1.y << 16);
      AH.u[3] = (u1.z & 0xffffu) | (u1.w << 16);
      AL.u[0] = (u0.x >> 16) | (u0.y & 0xffff0000u);
      AL.u[1] = (u0.z >> 16) | (u0.w & 0xffff0000u);
      AL.u[2] = (u1.x >> 16) | (u1.y & 0xffff0000u);
      AL.u[3] = (u1.z >> 16) | (u1.w & 0xffff0000u);
#pragma unroll
      for (int jn = 0; jn < 4; jn++) {
        bf16x8 bh = *(const bf16x8*)&Vthi[(jn * 16 + l16) * 200 + s * 32 + quad * 8];
        bf16x8 bl = *(const bf16x8*)&Vtlo[(jn * 16 + l16) * 200 + s * 32 + quad * 8];
        acc_o[jn] = __builtin_amdgcn_mfma_f32_16x16x32_bf16(AH.v, bh, acc_o[jn], 0, 0, 0);
        acc_o[jn] = __builtin_amdgcn_mfma_f32_16x16x32_bf16(AL.v, bh, acc_o[jn], 0, 0, 0);
        acc_o[jn] = __builtin_amdgcn_mfma_f32_16x16x32_bf16(AH.v, bl, acc_o[jn], 0, 0, 0);
      }
    }
    // ---- tail keys 192..195: e still in acc_s[12], broadcast within quad ----
#pragma unroll
    for (int kk = 0; kk < 4; kk++) {
      int srcl = (lane & 48) + kk;
      float e0 = __shfl(acc_s[12][0], srcl, 64);
      float e1 = __shfl(acc_s[12][1], srcl, 64);
      float e2 = __shfl(acc_s[12][2], srcl, 64);
      float e3 = __shfl(acc_s[12][3], srcl, 64);
#pragma unroll
      for (int jn = 0; jn < 4; jn++) {
        int d = jn * 16 + l16;
        float v = bf2f(Vthi[d * 200 + 192 + kk]) + bf2f(Vtlo[d * 200 + 192 + kk]);
        acc_o[jn][0] += e0 * v;
        acc_o[jn][1] += e1 * v;
        acc_o[jn][2] += e2 * v;
        acc_o[jn][3] += e3 * v;
      }
    }

    // ---- store O (normalized) ----
#pragma unroll
    for (int jn = 0; jn < 4; jn++) {
#pragma unroll
      for (int p = 0; p < 4; p++) {
        int qrow = strip * 16 + quad * 4 + p;
        if (qrow < WHT)
          outA[((size_t)(1 + tq * WHT + qrow) * 8 + b) * CC + h * 64 + jn * 16 + l16] =
              acc_o[jn][p] * inv4[p];
      }
    }
  }
}

// ---------------------------------------------------------------------------
// Final LN (token 0 only) + classifier head
// ---------------------------------------------------------------------------
__global__ __launch_bounds__(256)
void head_kernel(const float* __restrict__ X, const float* __restrict__ enw,
                 const float* __restrict__ enb, const float* __restrict__ fcw,
                 const float* __restrict__ fcb, float* __restrict__ out) {
  __shared__ float nx[512];
  __shared__ float red[8];
  const int b = blockIdx.x, tid = threadIdx.x;
  const float* x = X + (size_t)b * CC;
  float v0 = x[tid], v1 = x[tid + 256];
  float s = wave_reduce_sum(v0 + v1);
  if ((tid & 63) == 0) red[tid >> 6] = s;
  __syncthreads();
  float mean = (red[0] + red[1] + red[2] + red[3]) * (1.f / 512.f);
  float d0 = v0 - mean, d1 = v1 - mean;
  float vs = wave_reduce_sum(d0 * d0 + d1 * d1);
  if ((tid & 63) == 0) red[4 + (tid >> 6)] = vs;
  __syncthreads();
  float var = (red[4] + red[5] + red[6] + red[7]) * (1.f / 512.f);
  float inv = 1.0f / sqrtf(var + 1e-5f);
  nx[tid] = d0 * inv * enw[tid] + enb[tid];
  nx[tid + 256] = d1 * inv * enw[tid + 256] + enb[tid + 256];
  __syncthreads();
  if (tid < NCLS) {
    float acc = fcb[tid];
    for (int c = 0; c < 512; c++) acc += nx[c] * fcw[c * NCLS + tid];
    out[b * NCLS + tid] = acc;
  }
}

// ---------------------------------------------------------------------------
extern "C" void kernel_launch(void* const* d_in, const int* in_sizes, int n_in,
                              void* d_out, int out_size, void* d_ws, size_t ws_size,
                              hipStream_t stream) {
  (void)in_sizes; (void)n_in; (void)out_size; (void)ws_size;
  const float* src  = (const float*)d_in[0];
  const float* cw   = (const float*)d_in[1];
  const float* cb   = (const float*)d_in[2];
  const float* clst = (const float*)d_in[3];
  const float* pos  = (const float*)d_in[4];
  const float* Wt   = (const float*)d_in[5];
  const float* bt   = (const float*)d_in[6];
  const float* Wsp  = (const float*)d_in[7];
  const float* bsp  = (const float*)d_in[8];
  const float* Wo   = (const float*)d_in[9];
  const float* bo   = (const float*)d_in[10];
  const float* n1w  = (const float*)d_in[11];
  const float* n1b  = (const float*)d_in[12];
  const float* n2w  = (const float*)d_in[13];
  const float* n2b  = (const float*)d_in[14];
  const float* W1   = (const float*)d_in[15];
  const float* b1   = (const float*)d_in[16];
  const float* W2   = (const float*)d_in[17];
  const float* b2   = (const float*)d_in[18];
  const float* enw  = (const float*)d_in[19];
  const float* enb  = (const float*)d_in[20];
  const float* fcw  = (const float*)d_in[21];
  const float* fcb  = (const float*)d_in[22];

  float* ws = (float*)d_ws;
  const size_t TOKR = (size_t)3137 * 8;
  float* X0  = ws;                              // TOKR*512
  float* Ab  = X0 + TOKR * 512;                 // TOKR*512
  float* QKV = Ab + TOKR * 512;                 // TOKR*1536 (also FFN mid / im2col)
  float* CLS = QKV + TOKR * 1536;               // 8*512
  int*   IDX = (int*)(CLS + 8 * 512);           // 8*8*196*16 ints
  unsigned short* WT1 = (unsigned short*)(IDX + 8 * 8 * WHT * 16);  // 2048*512
  unsigned short* WT2 = WT1 + 2048 * 512;                           // 2048*512
  float* PART = (float*)(WT2 + 2048 * 512);     // 64*CA_NCH*68

  // A-planes for split GEMMs (aliased into Ab / QKV; same total bytes).
  unsigned short* Ahi = (unsigned short*)Ab;
  unsigned short* Alo = Ahi + TOKR * 512;
  unsigned short* IMhi = (unsigned short*)QKV;
  unsigned short* IMlo = IMhi + (size_t)25088 * 768;

  // Patch embed as im2col(split) + split-bf16 MFMA GEMM (M=25088,N=512,K=768).
  wsplit_flat_kernel<<<(512 * 768 + 255) / 256, 256, 0, stream>>>(
      cw, WT1, WT2, 512 * 768);
  im2col_split_kernel<<<(25088 * 192) / 256, 256, 0, stream>>>(src, IMhi, IMlo);
  mfma_gemm3s_kernel<<<(25088 / 128) * 4, 256, 0, stream>>>(
      IMhi, IMlo, WT1, WT2, cb, X0 + 8 * CC, 25088, 512, 768);
  cls_init_kernel<<<8, 512, 0, stream>>>(clst, X0);

  float* Xc = X0;
  int t = 16;
  const int FFN_CHUNK = 16384;
  for (int i = 0; i < 6; i++) {
    const int pk = (i & 1) ? 2 : 0;
    const int tp = t - pk;
    const int L = 1 + t * WHT;
    const int Lo = 1 + tp * WHT;
    const int M = L * 8, Mo = Lo * 8, My = tp * WHT * 8;
    const int mtM = (M + 127) / 128, mtMo = (Mo + 127) / 128, mtMy = (My + 127) / 128;

    // LN1 with direct bf16 hi/lo split output (feeds only the Wt GEMM)
    ln_split_kernel<<<M, 256, 0, stream>>>(Xc, Ahi, Alo,
                                           n1w + (size_t)i * 512, n1b + (size_t)i * 512,
                                           (i == 0) ? pos : nullptr);
    // sigma-critical Wt: split-bf16 MFMA (hi/lo), fp32-class accuracy
    wtrans_split_kernel<<<dim3(1536 / 32, 512 / 32), 256, 0, stream>>>(
        Wt + (size_t)i * 512 * 1536, WT1, WT2, 1536, 512);
    mfma_gemm3s_kernel<<<mtM * 12, 256, 0, stream>>>(
        Ahi, Alo, WT1, WT2, bt + (size_t)i * 1536, QKV, M, 1536, 512);
    class_attn_part_kernel<<<dim3(64, CA_NCH), 256, 0, stream>>>(QKV, PART, L);
    class_attn_reduce_kernel<<<64, 64, 0, stream>>>(PART, CLS);
    temporal_attn_kernel<<<HH * BB * WHT, 256, 0, stream>>>(QKV, Ab, IDX, t, tp, pk);
    // Ws: plain bf16 MFMA
    wtrans_kernel<<<dim3(1536 / 32, 512 / 32), 256, 0, stream>>>(
        Wsp + (size_t)i * 512 * 1536, WT1, 1536, 512);
    mfma_gemm_kernel<0, 0><<<mtMy * 12, 256, 0, stream>>>(
        Ab, WT1, bsp + (size_t)i * 1536, QKV, My, 1536, 512, nullptr);
    copy_cls_kernel<<<8, 512, 0, stream>>>(CLS, Ab);
    spatial_mfma_kernel<<<64 * tp, 256, 0, stream>>>(QKV, Ab);
    if (pk > 0)
      pool_inplace_kernel<<<8 * WHT, 256, 0, stream>>>(Xc, IDX, tp);
    // Wo: plain bf16 MFMA + residual
    wtrans_kernel<<<dim3(512 / 32, 512 / 32), 256, 0, stream>>>(
        Wo + (size_t)i * 512 * 512, WT1, 512, 512);
    mfma_gemm_kernel<0, 1><<<mtMo * 4, 256, 0, stream>>>(
        Ab, WT1, bo + (size_t)i * 512, Xc, Mo, 512, 512, Xc);
    ln_kernel<<<Mo, 256, 0, stream>>>(Xc, Ab, n2w + (size_t)i * 512, n2b + (size_t)i * 512,
                                      nullptr);
    // FFN: plain bf16 MFMA
    wtrans_kernel<<<dim3(2048 / 32, 512 / 32), 256, 0, stream>>>(
        W1 + (size_t)i * 512 * 2048, WT1, 2048, 512);
    wtrans_kernel<<<dim3(512 / 32, 2048 / 32), 256, 0, stream>>>(
        W2 + (size_t)i * 2048 * 512, WT2, 512, 2048);
    for (int off = 0; off < Mo; off += FFN_CHUNK) {
      int R = Mo - off;
      if (R > FFN_CHUNK) R = FFN_CHUNK;
      int mtR = (R + 127) / 128;
      mfma_gemm_kernel<1, 0><<<mtR * 16, 256, 0, stream>>>(
          Ab + (size_t)off * 512, WT1, b1 + (size_t)i * 2048, QKV, R, 2048, 512,
          nullptr);
      mfma_gemm_kernel<0, 1><<<mtR * 4, 256, 0, stream>>>(
          QKV, WT2, b2 + (size_t)i * 512, Xc + (size_t)off * 512, R, 512, 2048,
          Xc + (size_t)off * 512);
    }
    t = tp;
  }
  head_kernel<<<8, 256, 0, stream>>>(Xc, enw, enb, fcw, fcb, (float*)d_out);
}

// Round 7
// 4000.733 us; speedup vs baseline: 2.4781x; 1.3821x over previous
//
#include <hip/hip_runtime.h>
#include <math.h>

// ---------------------------------------------------------------------------
// CompactVidTr forward.
//  - All GEMMs: 128x128 tile, 1-D grid + bijective XCD-band swizzle; staging
//    via __builtin_amdgcn_global_load_lds width=16 (no VGPR round-trip).
//    LDS dest is LINEAR (glds writes base+lane*16); the bank-conflict XOR
//    swizzle is applied to the per-lane GLOBAL source granule index and
//    mirrored on the read side (rule #21: inverse-swz source + swz read).
//  - Wt/conv GEMM (mfma_gemm3s): 3-term split-bf16, pre-split A planes,
//    BK=32, 32 KB LDS, swizzle g^((r>>1)&3).
//  - Plain GEMMs (Ws/Wo/FFN): A is bf16 (producers emit f2bf directly —
//    bit-identical to the old staging conversion), BK=64, 32 KB LDS,
//    swizzle g^(r&7).
//  - Spatial attention: split-bf16 MFMA flash kernel (bf16 out -> Wo GEMM).
//  - Class attention: two-phase flash split over L.
//  - Temporal attention (fp32 math, bf16 Y out) + LN.
// Layout: token matrices row-major [row = l*B + b][C]; l=0 is cls. B=8, C=512.
// ---------------------------------------------------------------------------

#define BB 8
#define CC 512
#define HH 8
#define HD 64
#define WHT 196
#define NCLS 157
#define CA_NCH 32

typedef short bf16x8 __attribute__((ext_vector_type(8)));
typedef float floatx4 __attribute__((ext_vector_type(4)));

__device__ __forceinline__ unsigned short f2bf(float f) {
  unsigned u = __float_as_uint(f);
  unsigned r = u + 0x7FFFu + ((u >> 16) & 1u);  // RNE
  return (unsigned short)(r >> 16);
}
__device__ __forceinline__ float bf2f(unsigned short h) {
  return __uint_as_float((unsigned)h << 16);
}
// truncation split: hi = top-16-bits, lo = RNE(residual); reconstruct ~2^-17
__device__ __forceinline__ void splitf(float x, unsigned short& h, unsigned short& l) {
  unsigned u = __float_as_uint(x);
  unsigned hs = u >> 16;
  float rem = x - __uint_as_float(hs << 16);
  h = (unsigned short)hs;
  l = f2bf(rem);
}

// async global->LDS, 16B per lane; LDS dest = wave-uniform base + lane*16.
__device__ __forceinline__ void glds16(const unsigned short* g, unsigned short* l) {
  __builtin_amdgcn_global_load_lds(
      (const __attribute__((address_space(1))) void*)g,
      (__attribute__((address_space(3))) void*)l, 16, 0, 0);
}

__device__ __forceinline__ float wave_reduce_sum(float v) {
#pragma unroll
  for (int o = 32; o > 0; o >>= 1) v += __shfl_down(v, o, 64);
  return v;
}
__device__ __forceinline__ float wave_reduce_max(float v) {
#pragma unroll
  for (int o = 32; o > 0; o >>= 1) v = fmaxf(v, __shfl_down(v, o, 64));
  return v;
}

// Bijective XCD-band decode: blocks with id%8==x run on XCD x; each XCD owns
// a contiguous work range, n fastest within an m-row.
__device__ __forceinline__ void xcd_decode(int id, int G, int nt,
                                           int& m0, int& n0) {
  int q8 = G >> 3, r8 = G & 7;
  int xcd = id & 7, j = id >> 3;
  int w = (xcd < r8) ? xcd * (q8 + 1) + j : r8 * (q8 + 1) + (xcd - r8) * q8 + j;
  m0 = (w / nt) * 128;
  n0 = (w % nt) * 128;
}

// ---------------------------------------------------------------------------
// im2col + split: src [8][3][16][224][224] -> IMhi/IMlo [25088][768] bf16.
// ---------------------------------------------------------------------------
__global__ __launch_bounds__(256)
void im2col_split_kernel(const float* __restrict__ src,
                         unsigned short* __restrict__ IMhi,
                         unsigned short* __restrict__ IMlo) {
  int gid = blockIdx.x * 256 + threadIdx.x;
  int k4 = gid % 192;
  int u = gid / 192;
  if (u >= 25088) return;
  int b = u & 7;
  int s = u >> 3;
  int tt = s / WHT;
  int w2 = s % WHT;
  int ph = w2 / 14, pw = w2 % 14;
  int k = k4 * 4;
  int ci = k >> 8;
  int rem = k & 255;
  int py = rem >> 4, px = rem & 15;
  const float* sp = src + (size_t)b * (3 * 16 * 224 * 224) +
                    (size_t)ci * (16 * 224 * 224) + (size_t)tt * (224 * 224) +
                    (size_t)(ph * 16 + py) * 224 + pw * 16 + px;
  float4 v = *(const float4*)sp;
  ushort4 h, l;
  splitf(v.x, h.x, l.x);
  splitf(v.y, h.y, l.y);
  splitf(v.z, h.z, l.z);
  splitf(v.w, h.w, l.w);
  *(ushort4*)(IMhi + (size_t)u * 768 + k) = h;
  *(ushort4*)(IMlo + (size_t)u * 768 + k) = l;
}

__global__ __launch_bounds__(256)
void wsplit_flat_kernel(const float* __restrict__ W,
                        unsigned short* __restrict__ Whi,
                        unsigned short* __restrict__ Wlo, int total) {
  int i = blockIdx.x * 256 + threadIdx.x;
  if (i >= total) return;
  float w = W[i];
  unsigned short hi = f2bf(w);
  Whi[i] = hi;
  Wlo[i] = f2bf(w - bf2f(hi));
}

__global__ void cls_init_kernel(const float* __restrict__ clst, float* __restrict__ X) {
  X[(size_t)blockIdx.x * CC + threadIdx.x] = clst[threadIdx.x];
}

// CLS fp32 -> row 0 of the bf16 A buffer (same rounding staging used to do).
__global__ void copy_cls_kernel(const float* __restrict__ cls,
                                unsigned short* __restrict__ A) {
  A[(size_t)blockIdx.x * CC + threadIdx.x] =
      f2bf(cls[(size_t)blockIdx.x * CC + threadIdx.x]);
}

// ---------------------------------------------------------------------------
// LayerNorm over C=512, bf16 out (feeds plain GEMMs); one block per row.
// ---------------------------------------------------------------------------
__global__ __launch_bounds__(256)
void ln_bf16_kernel(const float* __restrict__ X, unsigned short* __restrict__ O,
                    const float* __restrict__ w, const float* __restrict__ b) {
  __shared__ float red[8];
  const int row = blockIdx.x, tid = threadIdx.x;
  const float* x = X + (size_t)row * CC;
  float v0 = x[tid], v1 = x[tid + 256];
  float s = wave_reduce_sum(v0 + v1);
  if ((tid & 63) == 0) red[tid >> 6] = s;
  __syncthreads();
  float mean = (red[0] + red[1] + red[2] + red[3]) * (1.f / 512.f);
  float d0 = v0 - mean, d1 = v1 - mean;
  float vs = wave_reduce_sum(d0 * d0 + d1 * d1);
  if ((tid & 63) == 0) red[4 + (tid >> 6)] = vs;
  __syncthreads();
  float var = (red[4] + red[5] + red[6] + red[7]) * (1.f / 512.f);
  float inv = 1.0f / sqrtf(var + 1e-5f);
  O[(size_t)row * CC + tid] = f2bf(d0 * inv * w[tid] + b[tid]);
  O[(size_t)row * CC + tid + 256] = f2bf(d1 * inv * w[tid + 256] + b[tid + 256]);
}

// ---------------------------------------------------------------------------
// LayerNorm + split-bf16 output (hi/lo planes) — feeds the Wt split GEMM.
// ---------------------------------------------------------------------------
__global__ __launch_bounds__(256)
void ln_split_kernel(const float* __restrict__ X,
                     unsigned short* __restrict__ Ahi,
                     unsigned short* __restrict__ Alo,
                     const float* __restrict__ w, const float* __restrict__ b,
                     const float* __restrict__ pos) {
  __shared__ float red[8];
  const int row = blockIdx.x, tid = threadIdx.x;
  const float* x = X + (size_t)row * CC;
  float v0 = x[tid], v1 = x[tid + 256];
  float s = wave_reduce_sum(v0 + v1);
  if ((tid & 63) == 0) red[tid >> 6] = s;
  __syncthreads();
  float mean = (red[0] + red[1] + red[2] + red[3]) * (1.f / 512.f);
  float d0 = v0 - mean, d1 = v1 - mean;
  float vs = wave_reduce_sum(d0 * d0 + d1 * d1);
  if ((tid & 63) == 0) red[4 + (tid >> 6)] = vs;
  __syncthreads();
  float var = (red[4] + red[5] + red[6] + red[7]) * (1.f / 512.f);
  float inv = 1.0f / sqrtf(var + 1e-5f);
  float o0 = d0 * inv * w[tid] + b[tid];
  float o1 = d1 * inv * w[tid + 256] + b[tid + 256];
  if (pos) {
    const float* pr = pos + (size_t)(row >> 3) * CC;
    o0 += pr[tid];
    o1 += pr[tid + 256];
  }
  unsigned short h, l;
  splitf(o0, h, l);
  Ahi[(size_t)row * CC + tid] = h;
  Alo[(size_t)row * CC + tid] = l;
  splitf(o1, h, l);
  Ahi[(size_t)row * CC + tid + 256] = h;
  Alo[(size_t)row * CC + tid + 256] = l;
}

// ---------------------------------------------------------------------------
// Weight transpose + fp32->bf16 (plain): W [K][N] -> WT [N][K]
// ---------------------------------------------------------------------------
__global__ __launch_bounds__(256)
void wtrans_kernel(const float* __restrict__ W, unsigned short* __restrict__ WT,
                   int N, int K) {
  __shared__ float tile[32][33];
  const int tid = threadIdx.x;
  const int tx = tid & 31, ty = tid >> 5;
  const int n0 = blockIdx.x * 32, k0 = blockIdx.y * 32;
#pragma unroll
  for (int r = 0; r < 4; r++) {
    int kk = ty + r * 8;
    tile[kk][tx] = W[(size_t)(k0 + kk) * N + n0 + tx];
  }
  __syncthreads();
#pragma unroll
  for (int r = 0; r < 4; r++) {
    int nn = ty + r * 8;
    WT[(size_t)(n0 + nn) * K + k0 + tx] = f2bf(tile[tx][nn]);
  }
}

// ---------------------------------------------------------------------------
// Weight transpose + split fp32 -> (hi, lo) bf16: W [K][N] -> WThi/WTlo [N][K]
// ---------------------------------------------------------------------------
__global__ __launch_bounds__(256)
void wtrans_split_kernel(const float* __restrict__ W,
                         unsigned short* __restrict__ WThi,
                         unsigned short* __restrict__ WTlo, int N, int K) {
  __shared__ float tile[32][33];
  const int tid = threadIdx.x;
  const int tx = tid & 31, ty = tid >> 5;
  const int n0 = blockIdx.x * 32, k0 = blockIdx.y * 32;
#pragma unroll
  for (int r = 0; r < 4; r++) {
    int kk = ty + r * 8;
    tile[kk][tx] = W[(size_t)(k0 + kk) * N + n0 + tx];
  }
  __syncthreads();
#pragma unroll
  for (int r = 0; r < 4; r++) {
    int nn = ty + r * 8;
    float w = tile[tx][nn];
    unsigned short hi = f2bf(w);
    unsigned short lo = f2bf(w - bf2f(hi));
    WThi[(size_t)(n0 + nn) * K + k0 + tx] = hi;
    WTlo[(size_t)(n0 + nn) * K + k0 + tx] = lo;
  }
}

// ---------------------------------------------------------------------------
// Plain bf16 MFMA GEMM: C = A(M,K,bf16) @ W(K,N) + bias [+relu] [+residual]
// BK=64, LDS 2x16KB linear rows of 64 shorts; glds staging with source-side
// XOR swizzle g^(r&7); reads mirror the swizzle. OBF=1 -> bf16 output.
// ---------------------------------------------------------------------------
template <int RELU, int RES, int OBF>
__global__ __launch_bounds__(256)
void mfma_gemm_kernel(const unsigned short* __restrict__ A,
                      const unsigned short* __restrict__ WT,
                      const float* __restrict__ bias, void* __restrict__ Cout,
                      int M, int N, int K, const float* __restrict__ resid) {
  __shared__ __attribute__((aligned(16))) unsigned short As[128 * 64];
  __shared__ __attribute__((aligned(16))) unsigned short Bs[128 * 64];
  const int tid = threadIdx.x;
  const int wave = tid >> 6, lane = tid & 63;
  const int quad = lane >> 4, l16 = lane & 15;
  const int wrow = (wave >> 1) * 64, wcol = (wave & 1) * 64;
  int m0, n0;
  xcd_decode(blockIdx.x, gridDim.x, N >> 7, m0, n0);

  floatx4 acc[4][4];
#pragma unroll
  for (int i = 0; i < 4; i++)
#pragma unroll
    for (int j = 0; j < 4; j++) acc[i][j] = (floatx4){0.f, 0.f, 0.f, 0.f};

  for (int k0 = 0; k0 < K; k0 += 64) {
#pragma unroll
    for (int t = 0; t < 4; t++) {
      int rl = wave * 32 + t * 8 + (lane >> 3);
      int g = (lane & 7) ^ (rl & 7);
      glds16(A + (size_t)(m0 + rl) * K + k0 + g * 8, &As[(wave * 32 + t * 8) * 64]);
      glds16(WT + (size_t)(n0 + rl) * K + k0 + g * 8, &Bs[(wave * 32 + t * 8) * 64]);
    }
    __syncthreads();
#pragma unroll
    for (int st = 0; st < 2; st++) {
      bf16x8 af[4], bf[4];
#pragma unroll
      for (int i = 0; i < 4; i++) {
        int ra = wrow + i * 16 + l16;
        af[i] = *(const bf16x8*)&As[ra * 64 + (((st * 4 + quad) ^ (ra & 7)) * 8)];
        int rb = wcol + i * 16 + l16;
        bf[i] = *(const bf16x8*)&Bs[rb * 64 + (((st * 4 + quad) ^ (rb & 7)) * 8)];
      }
#pragma unroll
      for (int i = 0; i < 4; i++)
#pragma unroll
        for (int j = 0; j < 4; j++)
          acc[i][j] = __builtin_amdgcn_mfma_f32_16x16x32_bf16(af[i], bf[j],
                                                              acc[i][j], 0, 0, 0);
    }
    __syncthreads();
  }
#pragma unroll
  for (int i = 0; i < 4; i++) {
#pragma unroll
    for (int p = 0; p < 4; p++) {
      int gm = m0 + wrow + i * 16 + quad * 4 + p;
      if (gm >= M) continue;
#pragma unroll
      for (int j = 0; j < 4; j++) {
        int gn = n0 + wcol + j * 16 + l16;
        float v = acc[i][j][p] + bias[gn];
        if (RELU) v = fmaxf(v, 0.f);
        if (RES == 1) v += resid[(size_t)gm * N + gn];
        if (OBF)
          ((unsigned short*)Cout)[(size_t)gm * N + gn] = f2bf(v);
        else
          ((float*)Cout)[(size_t)gm * N + gn] = v;
      }
    }
  }
}

// ---------------------------------------------------------------------------
// Split-bf16 MFMA GEMM, pre-split A planes. BK=32; LDS 4x8KB linear rows of
// 32 shorts; glds staging with source-side swizzle g^((r>>1)&3); reads mirror.
// ---------------------------------------------------------------------------
__global__ __launch_bounds__(256)
void mfma_gemm3s_kernel(const unsigned short* __restrict__ Ahi,
                        const unsigned short* __restrict__ Alo,
                        const unsigned short* __restrict__ WThi,
                        const unsigned short* __restrict__ WTlo,
                        const float* __restrict__ bias, float* __restrict__ Cout,
                        int M, int N, int K) {
  __shared__ __attribute__((aligned(16))) unsigned short AsHi[128 * 32];
  __shared__ __attribute__((aligned(16))) unsigned short AsLo[128 * 32];
  __shared__ __attribute__((aligned(16))) unsigned short BsHi[128 * 32];
  __shared__ __attribute__((aligned(16))) unsigned short BsLo[128 * 32];
  const int tid = threadIdx.x;
  const int wave = tid >> 6, lane = tid & 63;
  const int quad = lane >> 4, l16 = lane & 15;
  const int wrow = (wave >> 1) * 64, wcol = (wave & 1) * 64;
  int m0, n0;
  xcd_decode(blockIdx.x, gridDim.x, N >> 7, m0, n0);

  floatx4 acc[4][4];
#pragma unroll
  for (int i = 0; i < 4; i++)
#pragma unroll
    for (int j = 0; j < 4; j++) acc[i][j] = (floatx4){0.f, 0.f, 0.f, 0.f};

  for (int k0 = 0; k0 < K; k0 += 32) {
#pragma unroll
    for (int t = 0; t < 2; t++) {
      int rl = wave * 32 + t * 16 + (lane >> 2);
      int g = (lane & 3) ^ ((rl >> 1) & 3);
      size_t soff = (size_t)(m0 + rl) * K + k0 + g * 8;
      size_t boff = (size_t)(n0 + rl) * K + k0 + g * 8;
      unsigned short* lb = (unsigned short*)0 + (wave * 32 + t * 16) * 32;
      glds16(Ahi + soff, &AsHi[(wave * 32 + t * 16) * 32]);
      glds16(Alo + soff, &AsLo[(wave * 32 + t * 16) * 32]);
      glds16(WThi + boff, &BsHi[(wave * 32 + t * 16) * 32]);
      glds16(WTlo + boff, &BsLo[(wave * 32 + t * 16) * 32]);
      (void)lb;
    }
    __syncthreads();
    bf16x8 ah[4], al[4], bh[4], bl[4];
#pragma unroll
    for (int i = 0; i < 4; i++) {
      int ra = wrow + i * 16 + l16;
      int offa = ra * 32 + ((quad ^ ((ra >> 1) & 3)) * 8);
      ah[i] = *(const bf16x8*)&AsHi[offa];
      al[i] = *(const bf16x8*)&AsLo[offa];
      int rb = wcol + i * 16 + l16;
      int offb = rb * 32 + ((quad ^ ((rb >> 1) & 3)) * 8);
      bh[i] = *(const bf16x8*)&BsHi[offb];
      bl[i] = *(const bf16x8*)&BsLo[offb];
    }
#pragma unroll
    for (int i = 0; i < 4; i++)
#pragma unroll
      for (int j = 0; j < 4; j++) {
        acc[i][j] = __builtin_amdgcn_mfma_f32_16x16x32_bf16(ah[i], bh[j],
                                                            acc[i][j], 0, 0, 0);
        acc[i][j] = __builtin_amdgcn_mfma_f32_16x16x32_bf16(ah[i], bl[j],
                                                            acc[i][j], 0, 0, 0);
        acc[i][j] = __builtin_amdgcn_mfma_f32_16x16x32_bf16(al[i], bh[j],
                                                            acc[i][j], 0, 0, 0);
      }
    __syncthreads();
  }
#pragma unroll
  for (int i = 0; i < 4; i++) {
#pragma unroll
    for (int p = 0; p < 4; p++) {
      int gm = m0 + wrow + i * 16 + quad * 4 + p;
      if (gm >= M) continue;
#pragma unroll
      for (int j = 0; j < 4; j++) {
        int gn = n0 + wcol + j * 16 + l16;
        Cout[(size_t)gm * N + gn] = acc[i][j][p] + bias[gn];
      }
    }
  }
}

// ---------------------------------------------------------------------------
// Class attention, phase 1: per-(h,b) x per-chunk partial flash softmax.
// ---------------------------------------------------------------------------
__global__ __launch_bounds__(256)
void class_attn_part_kernel(const float* __restrict__ qkv,
                            float* __restrict__ part, int L) {
  __shared__ float q[64];
  __shared__ float sc[128];
  __shared__ float red[8];
  __shared__ float pv[256];
  const int h = blockIdx.x & 7, b = blockIdx.x >> 3;
  const int chunk = blockIdx.y;
  const int tid = threadIdx.x;
  const int per = (L + CA_NCH - 1) / CA_NCH;
  const int l0 = chunk * per;
  const int nl = min(L - l0, per);
  if (tid < 64) q[tid] = qkv[(size_t)b * 1536 + h * 64 + tid] * 0.125f;
  __syncthreads();
  float lmax = -3.4e38f;
  for (int i = tid; i < nl; i += 256) {
    const float* kr = qkv + (size_t)((l0 + i) * 8 + b) * 1536 + 512 + h * 64;
    float s = 0;
#pragma unroll
    for (int d2 = 0; d2 < 64; d2 += 4) {
      float4 k4 = *(const float4*)(kr + d2);
      s += q[d2] * k4.x + q[d2 + 1] * k4.y + q[d2 + 2] * k4.z + q[d2 + 3] * k4.w;
    }
    sc[i] = s;
    lmax = fmaxf(lmax, s);
  }
  lmax = wave_reduce_max(lmax);
  if ((tid & 63) == 0) red[tid >> 6] = lmax;
  __syncthreads();
  float gmax = fmaxf(fmaxf(red[0], red[1]), fmaxf(red[2], red[3]));
  float lsum = 0;
  for (int i = tid; i < nl; i += 256) {
    float e = expf(sc[i] - gmax);
    sc[i] = e;
    lsum += e;
  }
  lsum = wave_reduce_sum(lsum);
  if ((tid & 63) == 0) red[4 + (tid >> 6)] = lsum;
  __syncthreads();
  float gsum = red[4] + red[5] + red[6] + red[7];
  const int g = tid >> 6, d = tid & 63;
  float acc = 0;
  for (int i = g; i < nl; i += 4)
    acc += sc[i] * qkv[(size_t)((l0 + i) * 8 + b) * 1536 + 1024 + h * 64 + d];
  pv[g * 64 + d] = acc;
  __syncthreads();
  float* rec = part + ((size_t)blockIdx.x * CA_NCH + chunk) * 68;
  if (tid == 0) {
    rec[0] = gmax;
    rec[1] = gsum;
  }
  if (g == 0) rec[2 + d] = pv[d] + pv[64 + d] + pv[128 + d] + pv[192 + d];
}

// ---------------------------------------------------------------------------
// Class attention, phase 2: combine CA_NCH partials per (h,b).
// ---------------------------------------------------------------------------
__global__ __launch_bounds__(64)
void class_attn_reduce_kernel(const float* __restrict__ part,
                              float* __restrict__ cls) {
  const int hb = blockIdx.x;  // (b<<3)|h
  const int tid = threadIdx.x;
  const float* prec = part + (size_t)hb * CA_NCH * 68;
  float M = -3.4e38f;
#pragma unroll
  for (int c = 0; c < CA_NCH; c++) M = fmaxf(M, prec[c * 68]);
  float total = 0.f, acc = 0.f;
#pragma unroll
  for (int c = 0; c < CA_NCH; c++) {
    float w = expf(prec[c * 68] - M);
    total += prec[c * 68 + 1] * w;
    acc += prec[c * 68 + 2 + tid] * w;
  }
  int h = hb & 7, b = hb >> 3;
  cls[b * CC + h * 64 + tid] = acc / total;
}

// ---------------------------------------------------------------------------
// Temporal attention + sigma top-k pooling (fp32 math — rank-critical).
// Y emitted as bf16 (same rounding the Ws GEMM staging used to apply).
// ---------------------------------------------------------------------------
__global__ __launch_bounds__(256)
void temporal_attn_kernel(const float* __restrict__ qkv,
                          unsigned short* __restrict__ Y,
                          int* __restrict__ idxbuf, int t, int tp, int pk) {
  __shared__ float qs[16 * 65], ks[16 * 65], vs[16 * 65];
  __shared__ float a[16 * 17];
  __shared__ float sig[16];
  __shared__ int keepf[16];
  __shared__ int klist[16];
  const int g = blockIdx.x;
  const int w = g % WHT;
  const int bb = (g / WHT) & 7;
  const int h = g / (WHT * 8);
  const int tid = threadIdx.x;
  const int td = t * 64;
  for (int e = tid; e < td; e += 256) {
    int tt = e >> 6, d = e & 63;
    size_t rb = (size_t)((1 + tt * WHT + w) * 8 + bb) * 1536 + h * 64 + d;
    qs[tt * 65 + d] = qkv[rb] * 0.125f;
    ks[tt * 65 + d] = qkv[rb + 512];
    vs[tt * 65 + d] = qkv[rb + 1024];
  }
  __syncthreads();
  if (tid < t * t) {
    int qi = tid / t, ki = tid % t;
    const float* qp = &qs[qi * 65];
    const float* kp = &ks[ki * 65];
    float s = 0;
#pragma unroll 8
    for (int d2 = 0; d2 < 64; d2++) s += qp[d2] * kp[d2];
    a[qi * 17 + ki] = s;
  }
  __syncthreads();
  if (tid < t) {
    float* row = &a[tid * 17];
    float m = row[0];
    for (int k2 = 1; k2 < t; k2++) m = fmaxf(m, row[k2]);
    float sum = 0;
    for (int k2 = 0; k2 < t; k2++) {
      float e2 = expf(row[k2] - m);
      row[k2] = e2;
      sum += e2;
    }
    float inv = 1.f / sum;
    for (int k2 = 0; k2 < t; k2++) row[k2] *= inv;
  }
  __syncthreads();
  if (pk > 0) {
    if (tid < t) {
      const float* row = &a[tid * 17];
      float mean = 0;
      for (int k2 = 0; k2 < t; k2++) mean += row[k2];
      mean /= (float)t;
      float var = 0;
      for (int k2 = 0; k2 < t; k2++) {
        float dl = row[k2] - mean;
        var += dl * dl;
      }
      var /= (float)(t - 1);
      sig[tid] = sqrtf(var);
    }
    __syncthreads();
    if (tid < t) {
      float sv = sig[tid];
      int r = 0;
      for (int q2 = 0; q2 < t; q2++) {
        float so = sig[q2];
        if (so > sv || (so == sv && q2 < tid)) r++;
      }
      keepf[tid] = (r < tp) ? 1 : 0;
    }
    __syncthreads();
    if (tid < t && keepf[tid]) {
      int ppos = 0;
      for (int q2 = 0; q2 < tid; q2++) ppos += keepf[q2];
      klist[ppos] = tid;
      idxbuf[((h * 8 + bb) * WHT + w) * 16 + ppos] = tid;
    }
  } else {
    if (tid < t) klist[tid] = tid;
  }
  __syncthreads();
  const int gq = tid >> 6, d = tid & 63;
  for (int qi = gq; qi < tp; qi += 4) {
    int qq = klist[qi];
    const float* arow = &a[qq * 17];
    float acc = 0;
    for (int k2 = 0; k2 < t; k2++) acc += arow[k2] * vs[k2 * 65 + d];
    Y[(size_t)((qi * WHT + w) * 8 + bb) * CC + h * 64 + d] = f2bf(acc);
  }
}

// ---------------------------------------------------------------------------
// In-place temporal pooling of the residual stream X.
// ---------------------------------------------------------------------------
__global__ __launch_bounds__(256)
void pool_inplace_kernel(float* __restrict__ X, const int* __restrict__ idxbuf,
                         int tp) {
  const int b = blockIdx.x & 7;
  const int w = blockIdx.x >> 3;
  const int tid = threadIdx.x;
  const int c0 = tid, c1 = tid + 256;
  const int h0 = c0 >> 6, h1 = c1 >> 6;
  const int ib0 = ((h0 * 8 + b) * WHT + w) * 16;
  const int ib1 = ((h1 * 8 + b) * WHT + w) * 16;
  for (int q = 0; q < tp; q++) {
    int s0 = idxbuf[ib0 + q];
    int s1 = idxbuf[ib1 + q];
    size_t drow = (size_t)((1 + q * WHT + w) * 8 + b) * CC;
    if (s0 != q) {
      size_t srow = (size_t)((1 + s0 * WHT + w) * 8 + b) * CC;
      X[drow + c0] = X[srow + c0];
    }
    if (s1 != q) {
      size_t srow = (size_t)((1 + s1 * WHT + w) * 8 + b) * CC;
      X[drow + c1] = X[srow + c1];
    }
  }
}

// ---------------------------------------------------------------------------
// Spatial attention, split-bf16 MFMA flash kernel. Output bf16 (-> Wo GEMM).
// ---------------------------------------------------------------------------
__global__ __launch_bounds__(256)
void spatial_mfma_kernel(const float* __restrict__ qkv,
                         unsigned short* __restrict__ outA) {
  __shared__ unsigned short Khi[208 * 72];
  __shared__ unsigned short Klo[208 * 72];
  __shared__ unsigned short Vthi[64 * 200];
  __shared__ unsigned short Vtlo[64 * 200];
  __shared__ unsigned int Ps[4][16 * 196];
  const int blk = blockIdx.x;
  const int h = blk & 7;
  const int b = (blk >> 3) & 7;
  const int tq = blk >> 6;
  const int tid = threadIdx.x;
  const int wave = tid >> 6, lane = tid & 63;
  const int quad = lane >> 4, l16 = lane & 15;
  const size_t rowbase = (size_t)(tq * WHT) * 8 + b;  // qkv row for w=0

  union BF8 { bf16x8 v; unsigned short s[8]; unsigned int u[4]; };

  // ---- stage K (hi/lo) and V (transposed hi/lo) ----
  for (int r = tid >> 4; r < WHT; r += 16) {
    int c = (tid & 15) * 4;
    const float* gk = qkv + (rowbase + (size_t)r * 8) * 1536 + 512 + h * 64 + c;
    float4 kv = *(const float4*)gk;
    ushort4 khs, kls;
    splitf(kv.x, khs.x, kls.x);
    splitf(kv.y, khs.y, kls.y);
    splitf(kv.z, khs.z, kls.z);
    splitf(kv.w, khs.w, kls.w);
    *(ushort4*)&Khi[r * 72 + c] = khs;
    *(ushort4*)&Klo[r * 72 + c] = kls;
    const float* gv = qkv + (rowbase + (size_t)r * 8) * 1536 + 1024 + h * 64 + c;
    float4 vv = *(const float4*)gv;
    unsigned short vh, vl;
    splitf(vv.x, vh, vl); Vthi[(c + 0) * 200 + r] = vh; Vtlo[(c + 0) * 200 + r] = vl;
    splitf(vv.y, vh, vl); Vthi[(c + 1) * 200 + r] = vh; Vtlo[(c + 1) * 200 + r] = vl;
    splitf(vv.z, vh, vl); Vthi[(c + 2) * 200 + r] = vh; Vtlo[(c + 2) * 200 + r] = vl;
    splitf(vv.w, vh, vl); Vthi[(c + 3) * 200 + r] = vh; Vtlo[(c + 3) * 200 + r] = vl;
  }
  __syncthreads();

  unsigned int* myP = &Ps[wave][0];

  for (int strip = wave; strip < 13; strip += 4) {
    // ---- load Q fragments for rows strip*16 + l16 (A-operand layout) ----
    int qr = strip * 16 + l16;
    int qrc = min(qr, WHT - 1);
    const float* qp = qkv + (rowbase + (size_t)qrc * 8) * 1536 + h * 64 + quad * 8;
    BF8 qh[2], ql[2];
#pragma unroll
    for (int st = 0; st < 2; st++) {
      float4 a = *(const float4*)(qp + st * 32);
      float4 c = *(const float4*)(qp + st * 32 + 4);
      float vals[8] = {a.x, a.y, a.z, a.w, c.x, c.y, c.z, c.w};
#pragma unroll
      for (int i = 0; i < 8; i++) {
        float x = vals[i] * 0.125f;
        splitf(x, qh[st].s[i], ql[st].s[i]);
      }
    }

    // ---- S = Q K^T via split MFMA (13 key tiles x 2 k-steps x 3 terms) ----
    floatx4 acc_s[13];
#pragma unroll
    for (int j = 0; j < 13; j++) {
      floatx4 acc = (floatx4){0.f, 0.f, 0.f, 0.f};
#pragma unroll
      for (int st = 0; st < 2; st++) {
        bf16x8 bh = *(const bf16x8*)&Khi[(j * 16 + l16) * 72 + st * 32 + quad * 8];
        bf16x8 bl = *(const bf16x8*)&Klo[(j * 16 + l16) * 72 + st * 32 + quad * 8];
        acc = __builtin_amdgcn_mfma_f32_16x16x32_bf16(qh[st].v, bh, acc, 0, 0, 0);
        acc = __builtin_amdgcn_mfma_f32_16x16x32_bf16(ql[st].v, bh, acc, 0, 0, 0);
        acc = __builtin_amdgcn_mfma_f32_16x16x32_bf16(qh[st].v, bl, acc, 0, 0, 0);
      }
      acc_s[j] = acc;
    }
    // mask invalid key cols 196..207 (tile 12, l16 >= 4)
    if (l16 >= 4) acc_s[12] = (floatx4){-3.4e38f, -3.4e38f, -3.4e38f, -3.4e38f};

    // ---- softmax rows (row = quad*4+p): 13-reg local + 16-lane shfl reduce ----
    float inv4[4];
#pragma unroll
    for (int p = 0; p < 4; p++) {
      float m = acc_s[0][p];
#pragma unroll
      for (int j = 1; j < 13; j++) m = fmaxf(m, acc_s[j][p]);
#pragma unroll
      for (int o = 8; o >= 1; o >>= 1) m = fmaxf(m, __shfl_xor(m, o, 64));
      float s = 0.f;
#pragma unroll
      for (int j = 0; j < 13; j++) {
        float e = __expf(acc_s[j][p] - m);
        acc_s[j][p] = e;
        s += e;
      }
#pragma unroll
      for (int o = 8; o >= 1; o >>= 1) s += __shfl_xor(s, o, 64);
      inv4[p] = 1.f / s;
    }

    // ---- write P (tiles 0..11) to per-wave strip as packed hi|lo u32 ----
#pragma unroll
    for (int j = 0; j < 12; j++) {
#pragma unroll
      for (int p = 0; p < 4; p++) {
        float e = acc_s[j][p];
        unsigned u = __float_as_uint(e);
        unsigned hs = u >> 16;
        float rem = e - __uint_as_float(hs << 16);
        unsigned ls = f2bf(rem);
        myP[(quad * 4 + p) * 196 + j * 16 + l16] = hs | (ls << 16);
      }
    }

    // ---- O = P V via split MFMA (6 k-steps x 4 d-tiles x 3 terms) ----
    floatx4 acc_o[4];
#pragma unroll
    for (int jn = 0; jn < 4; jn++) acc_o[jn] = (floatx4){0.f, 0.f, 0.f, 0.f};
#pragma unroll
    for (int s = 0; s < 6; s++) {
      const unsigned int* pp = &myP[l16 * 196 + s * 32 + quad * 8];
      uint4 u0 = *(const uint4*)pp;
      uint4 u1 = *(const uint4*)(pp + 4);
      BF8 AH, AL;
      AH.u[0] = (u0.x & 0xffffu) | (u0.y << 16);
      AH.u[1] = (u0.z & 0xffffu) | (u0.w << 16);
      AH.u[2] = (u1.x & 0xffffu) | (u1.y << 16);
      AH.u[3] = (u1.z & 0xffffu) | (u1.w << 16);
      AL.u[0] = (u0.x >> 16) | (u0.y & 0xffff0000u);
      AL.u[1] = (u0.z >> 16) | (u0.w & 0xffff0000u);
      AL.u[2] = (u1.x >> 16) | (u1.y & 0xffff0000u);
      AL.u[3] = (u1.z >> 16) | (u1.w & 0xffff0000u);
#pragma unroll
      for (int jn = 0; jn < 4; jn++) {
        bf16x8 bh = *(const bf16x8*)&Vthi[(jn * 16 + l16) * 200 + s * 32 + quad * 8];
        bf16x8 bl = *(const bf16x8*)&Vtlo[(jn * 16 + l16) * 200 + s * 32 + quad * 8];
        acc_o[jn] = __builtin_amdgcn_mfma_f32_16x16x32_bf16(AH.v, bh, acc_o[jn], 0, 0, 0);
        acc_o[jn] = __builtin_amdgcn_mfma_f32_16x16x32_bf16(AL.v, bh, acc_o[jn], 0, 0, 0);
        acc_o[jn] = __builtin_amdgcn_mfma_f32_16x16x32_bf16(AH.v, bl, acc_o[jn], 0, 0, 0);
      }
    }
    // ---- tail keys 192..195: e still in acc_s[12], broadcast within quad ----
#pragma unroll
    for (int kk = 0; kk < 4; kk++) {
      int srcl = (lane & 48) + kk;
      float e0 = __shfl(acc_s[12][0], srcl, 64);
      float e1 = __shfl(acc_s[12][1], srcl, 64);
      float e2 = __shfl(acc_s[12][2], srcl, 64);
      float e3 = __shfl(acc_s[12][3], srcl, 64);
#pragma unroll
      for (int jn = 0; jn < 4; jn++) {
        int d = jn * 16 + l16;
        float v = bf2f(Vthi[d * 200 + 192 + kk]) + bf2f(Vtlo[d * 200 + 192 + kk]);
        acc_o[jn][0] += e0 * v;
        acc_o[jn][1] += e1 * v;
        acc_o[jn][2] += e2 * v;
        acc_o[jn][3] += e3 * v;
      }
    }

    // ---- store O (normalized, bf16) ----
#pragma unroll
    for (int jn = 0; jn < 4; jn++) {
#pragma unroll
      for (int p = 0; p < 4; p++) {
        int qrow = strip * 16 + quad * 4 + p;
        if (qrow < WHT)
          outA[((size_t)(1 + tq * WHT + qrow) * 8 + b) * CC + h * 64 + jn * 16 + l16] =
              f2bf(acc_o[jn][p] * inv4[p]);
      }
    }
  }
}

// ---------------------------------------------------------------------------
// Final LN (token 0 only) + classifier head
// ---------------------------------------------------------------------------
__global__ __launch_bounds__(256)
void head_kernel(const float* __restrict__ X, const float* __restrict__ enw,
                 const float* __restrict__ enb, const float* __restrict__ fcw,
                 const float* __restrict__ fcb, float* __restrict__ out) {
  __shared__ float nx[512];
  __shared__ float red[8];
  const int b = blockIdx.x, tid = threadIdx.x;
  const float* x = X + (size_t)b * CC;
  float v0 = x[tid], v1 = x[tid + 256];
  float s = wave_reduce_sum(v0 + v1);
  if ((tid & 63) == 0) red[tid >> 6] = s;
  __syncthreads();
  float mean = (red[0] + red[1] + red[2] + red[3]) * (1.f / 512.f);
  float d0 = v0 - mean, d1 = v1 - mean;
  float vs = wave_reduce_sum(d0 * d0 + d1 * d1);
  if ((tid & 63) == 0) red[4 + (tid >> 6)] = vs;
  __syncthreads();
  float var = (red[4] + red[5] + red[6] + red[7]) * (1.f / 512.f);
  float inv = 1.0f / sqrtf(var + 1e-5f);
  nx[tid] = d0 * inv * enw[tid] + enb[tid];
  nx[tid + 256] = d1 * inv * enw[tid + 256] + enb[tid + 256];
  __syncthreads();
  if (tid < NCLS) {
    float acc = fcb[tid];
    for (int c = 0; c < 512; c++) acc += nx[c] * fcw[c * NCLS + tid];
    out[b * NCLS + tid] = acc;
  }
}

// ---------------------------------------------------------------------------
extern "C" void kernel_launch(void* const* d_in, const int* in_sizes, int n_in,
                              void* d_out, int out_size, void* d_ws, size_t ws_size,
                              hipStream_t stream) {
  (void)in_sizes; (void)n_in; (void)out_size; (void)ws_size;
  const float* src  = (const float*)d_in[0];
  const float* cw   = (const float*)d_in[1];
  const float* cb   = (const float*)d_in[2];
  const float* clst = (const float*)d_in[3];
  const float* pos  = (const float*)d_in[4];
  const float* Wt   = (const float*)d_in[5];
  const float* bt   = (const float*)d_in[6];
  const float* Wsp  = (const float*)d_in[7];
  const float* bsp  = (const float*)d_in[8];
  const float* Wo   = (const float*)d_in[9];
  const float* bo   = (const float*)d_in[10];
  const float* n1w  = (const float*)d_in[11];
  const float* n1b  = (const float*)d_in[12];
  const float* n2w  = (const float*)d_in[13];
  const float* n2b  = (const float*)d_in[14];
  const float* W1   = (const float*)d_in[15];
  const float* b1   = (const float*)d_in[16];
  const float* W2   = (const float*)d_in[17];
  const float* b2   = (const float*)d_in[18];
  const float* enw  = (const float*)d_in[19];
  const float* enb  = (const float*)d_in[20];
  const float* fcw  = (const float*)d_in[21];
  const float* fcb  = (const float*)d_in[22];

  float* ws = (float*)d_ws;
  const size_t TOKR = (size_t)3137 * 8;
  float* X0  = ws;                              // TOKR*512
  float* Ab  = X0 + TOKR * 512;                 // TOKR*512
  float* QKV = Ab + TOKR * 512;                 // TOKR*1536 (also FFN mid / im2col)
  float* CLS = QKV + TOKR * 1536;               // 8*512
  int*   IDX = (int*)(CLS + 8 * 512);           // 8*8*196*16 ints
  unsigned short* WT1 = (unsigned short*)(IDX + 8 * 8 * WHT * 16);  // 2048*512
  unsigned short* WT2 = WT1 + 2048 * 512;                           // 2048*512
  float* PART = (float*)(WT2 + 2048 * 512);     // 64*CA_NCH*68

  // bf16 views aliased into Ab / QKV.
  unsigned short* Ahi = (unsigned short*)Ab;            // split plane (Wt GEMM)
  unsigned short* Alo = Ahi + TOKR * 512;
  unsigned short* Abf = (unsigned short*)Ab;            // plain-GEMM A (bf16)
  unsigned short* MIDb = (unsigned short*)QKV;          // FFN mid (bf16)
  unsigned short* IMhi = (unsigned short*)QKV;
  unsigned short* IMlo = IMhi + (size_t)25088 * 768;

  // Patch embed as im2col(split) + split-bf16 MFMA GEMM (M=25088,N=512,K=768).
  wsplit_flat_kernel<<<(512 * 768 + 255) / 256, 256, 0, stream>>>(
      cw, WT1, WT2, 512 * 768);
  im2col_split_kernel<<<(25088 * 192) / 256, 256, 0, stream>>>(src, IMhi, IMlo);
  mfma_gemm3s_kernel<<<(25088 / 128) * 4, 256, 0, stream>>>(
      IMhi, IMlo, WT1, WT2, cb, X0 + 8 * CC, 25088, 512, 768);
  cls_init_kernel<<<8, 512, 0, stream>>>(clst, X0);

  float* Xc = X0;
  int t = 16;
  const int FFN_CHUNK = 16384;
  for (int i = 0; i < 6; i++) {
    const int pk = (i & 1) ? 2 : 0;
    const int tp = t - pk;
    const int L = 1 + t * WHT;
    const int Lo = 1 + tp * WHT;
    const int M = L * 8, Mo = Lo * 8, My = tp * WHT * 8;
    const int mtM = (M + 127) / 128, mtMo = (Mo + 127) / 128, mtMy = (My + 127) / 128;

    // LN1 with direct bf16 hi/lo split output (feeds only the Wt GEMM)
    ln_split_kernel<<<M, 256, 0, stream>>>(Xc, Ahi, Alo,
                                           n1w + (size_t)i * 512, n1b + (size_t)i * 512,
                                           (i == 0) ? pos : nullptr);
    // sigma-critical Wt: split-bf16 MFMA (hi/lo), fp32-class accuracy
    wtrans_split_kernel<<<dim3(1536 / 32, 512 / 32), 256, 0, stream>>>(
        Wt + (size_t)i * 512 * 1536, WT1, WT2, 1536, 512);
    mfma_gemm3s_kernel<<<mtM * 12, 256, 0, stream>>>(
        Ahi, Alo, WT1, WT2, bt + (size_t)i * 1536, QKV, M, 1536, 512);
    class_attn_part_kernel<<<dim3(64, CA_NCH), 256, 0, stream>>>(QKV, PART, L);
    class_attn_reduce_kernel<<<64, 64, 0, stream>>>(PART, CLS);
    // temporal writes Y (bf16) over the Ahi plane — consumed by Ws GEMM
    temporal_attn_kernel<<<HH * BB * WHT, 256, 0, stream>>>(QKV, Abf, IDX, t, tp, pk);
    // Ws: plain bf16 MFMA
    wtrans_kernel<<<dim3(1536 / 32, 512 / 32), 256, 0, stream>>>(
        Wsp + (size_t)i * 512 * 1536, WT1, 1536, 512);
    mfma_gemm_kernel<0, 0, 0><<<mtMy * 12, 256, 0, stream>>>(
        Abf, WT1, bsp + (size_t)i * 1536, QKV, My, 1536, 512, nullptr);
    copy_cls_kernel<<<8, 512, 0, stream>>>(CLS, Abf);
    spatial_mfma_kernel<<<64 * tp, 256, 0, stream>>>(QKV, Abf);
    if (pk > 0)
      pool_inplace_kernel<<<8 * WHT, 256, 0, stream>>>(Xc, IDX, tp);
    // Wo: plain bf16 MFMA + residual
    wtrans_kernel<<<dim3(512 / 32, 512 / 32), 256, 0, stream>>>(
        Wo + (size_t)i * 512 * 512, WT1, 512, 512);
    mfma_gemm_kernel<0, 1, 0><<<mtMo * 4, 256, 0, stream>>>(
        Abf, WT1, bo + (size_t)i * 512, Xc, Mo, 512, 512, Xc);
    // LN2 -> bf16 (feeds FFN1)
    ln_bf16_kernel<<<Mo, 256, 0, stream>>>(Xc, Abf, n2w + (size_t)i * 512,
                                           n2b + (size_t)i * 512);
    // FFN: plain bf16 MFMA; FFN1 emits bf16 mid (same rounding staging did)
    wtrans_kernel<<<dim3(2048 / 32, 512 / 32), 256, 0, stream>>>(
        W1 + (size_t)i * 512 * 2048, WT1, 2048, 512);
    wtrans_kernel<<<dim3(512 / 32, 2048 / 32), 256, 0, stream>>>(
        W2 + (size_t)i * 2048 * 512, WT2, 512, 2048);
    for (int off = 0; off < Mo; off += FFN_CHUNK) {
      int R = Mo - off;
      if (R > FFN_CHUNK) R = FFN_CHUNK;
      int mtR = (R + 127) / 128;
      mfma_gemm_kernel<1, 0, 1><<<mtR * 16, 256, 0, stream>>>(
          Abf + (size_t)off * 512, WT1, b1 + (size_t)i * 2048,
          MIDb + (size_t)off * 2048, R, 2048, 512, nullptr);
      mfma_gemm_kernel<0, 1, 0><<<mtR * 4, 256, 0, stream>>>(
          MIDb + (size_t)off * 2048, WT2, b2 + (size_t)i * 512,
          Xc + (size_t)off * 512, R, 512, 2048, Xc + (size_t)off * 512);
    }
    t = tp;
  }
  head_kernel<<<8, 256, 0, stream>>>(Xc, enw, enb, fcw, fcb, (float*)d_out);
}